// Round 1
// baseline (2497.643 us; speedup 1.0000x reference)
//
#include <hip/hip_runtime.h>

// ---------------------------------------------------------------------------
// LocallyConnectedNN: x[16384,256] -> conv3x3(1->16)+BN+ReLU -> conv2x2(16->32)
// +BN+ReLU -> conv1x1(32->64)+BN+ReLU -> FC(10816->10).
// Training-mode BN forces 3 global stat syncs; intermediates are recomputed
// from x (16MB, cache-resident) instead of materialized (205-709MB).
// ws usage: 1024-block partial sums + scale/shift params = ~918KB.
// ---------------------------------------------------------------------------

#define NPART 1024
#define P1_OFF 0          // [1024][32]  (16 sums | 16 sumsq)
#define P2_OFF 32768      // [1024][64]
#define P3_OFF 98304      // [1024][128]
#define ST_OFF 229376     // s1[16] t1[16] s2[32] t2[32] s3[64] t3[64]
#define ST1 ST_OFF
#define ST2 (ST_OFF + 32)
#define ST3 (ST_OFF + 96)

__device__ __forceinline__ unsigned int f2bf(float f) {
  unsigned int u = __float_as_uint(f);
  return (u + 0x7fffu + ((u >> 16) & 1u)) >> 16;   // RTNE bf16 bits
}

// conv1 (3x3, 1->16) + bn1 + relu for output rows i and i+1 of one image.
// Lane split: k=lane&15 (channel), rk=lane>>4: s=rk>>1 (row), cg=rk&1 (7 cols).
__device__ __forceinline__ void conv1_two_rows(
    const float* sx_img,            // [256] = 16x16 image
    float* a1w,                     // [2][16][18] wave-private
    int i, int lane, const float* w1r, float rs1, float rt1)
{
  const int k  = lane & 15;
  const int rk = lane >> 4;
  const int s  = rk >> 1;
  const int cg = rk & 1;
  const float* px = sx_img + (i + s) * 16 + cg * 7;
  float v[3][9];
#pragma unroll
  for (int di = 0; di < 3; ++di)
#pragma unroll
    for (int m = 0; m < 9; ++m)
      v[di][m] = px[di * 16 + m];
  float* pa = a1w + (s * 16 + k) * 18 + cg * 7;
#pragma unroll
  for (int q = 0; q < 7; ++q) {
    float y = 0.f;
#pragma unroll
    for (int di = 0; di < 3; ++di)
#pragma unroll
      for (int dj = 0; dj < 3; ++dj)
        y += w1r[di * 3 + dj] * v[di][q + dj];
    y = rs1 * y + rt1;
    pa[q] = y > 0.f ? y : 0.f;
  }
}

// conv2 (2x2, 16->32) raw output row i. Lane split: c=lane&31, hf=lane>>5.
// hf=0 computes j=0..6 (j=6 redundant), hf=1 computes j=6..12. acc[q]=y2 at
// j = hf*6+q.  Register-sliding over 4x float2 LDS loads (2-addr merge).
__device__ __forceinline__ void conv2_row(
    const float* a1w,               // [2][16][18]
    const float* w2i,               // [16][2][32][2]  (k,di,c,dj)
    int c, int hf, float* acc)
{
#pragma unroll
  for (int q = 0; q < 7; ++q) acc[q] = 0.f;
  const int jb = hf * 6;
#pragma unroll 4
  for (int k = 0; k < 16; ++k) {
#pragma unroll
    for (int di = 0; di < 2; ++di) {
      const float* pr = a1w + (di * 16 + k) * 18 + jb;
      float2 p0 = *(const float2*)(pr + 0);
      float2 p1 = *(const float2*)(pr + 2);
      float2 p2 = *(const float2*)(pr + 4);
      float2 p3 = *(const float2*)(pr + 6);
      float2 wv = *(const float2*)(w2i + ((k * 2 + di) * 32 + c) * 2);
      acc[0] += wv.x * p0.x + wv.y * p0.y;
      acc[1] += wv.x * p0.y + wv.y * p1.x;
      acc[2] += wv.x * p1.x + wv.y * p1.y;
      acc[3] += wv.x * p1.y + wv.y * p2.x;
      acc[4] += wv.x * p2.x + wv.y * p2.y;
      acc[5] += wv.x * p2.y + wv.y * p3.x;
      acc[6] += wv.x * p3.x + wv.y * p3.y;
    }
  }
}

// conv3 (1x1, 32->64) raw output row. Lane owns channel c=lane, all 13 j.
__device__ __forceinline__ void conv3_row(
    const float* a2r,               // [32][18]
    const float* w3t,               // [32][64]  (k,c)
    int c, float* y3)
{
#pragma unroll
  for (int j = 0; j < 13; ++j) y3[j] = 0.f;
#pragma unroll 8
  for (int k = 0; k < 32; ++k) {
    const float* pr = a2r + k * 18;
    float2 q0 = *(const float2*)(pr + 0);
    float2 q1 = *(const float2*)(pr + 2);
    float2 q2 = *(const float2*)(pr + 4);
    float2 q3 = *(const float2*)(pr + 6);
    float2 q4 = *(const float2*)(pr + 8);
    float2 q5 = *(const float2*)(pr + 10);
    float  vc = pr[12];
    float  wv = w3t[k * 64 + c];
    y3[0]  += wv * q0.x;  y3[1]  += wv * q0.y;
    y3[2]  += wv * q1.x;  y3[3]  += wv * q1.y;
    y3[4]  += wv * q2.x;  y3[5]  += wv * q2.y;
    y3[6]  += wv * q3.x;  y3[7]  += wv * q3.y;
    y3[8]  += wv * q4.x;  y3[9]  += wv * q4.y;
    y3[10] += wv * q5.x;  y3[11] += wv * q5.y;
    y3[12] += wv * vc;
  }
}

// K1: per-channel sum/sumsq of raw conv1 output. Wave-per-image, 4 img/wave.
__global__ __launch_bounds__(256) void k1_conv1_stats(
    const float* __restrict__ x, const float* __restrict__ w1,
    float* __restrict__ ws)
{
  __shared__ float sx[4][256];
  __shared__ float red[4][32];
  const int tid = threadIdx.x, w = tid >> 6, lane = tid & 63;
  const int k = lane & 15, pg = lane >> 4;
  float w1r[9];
#pragma unroll
  for (int q = 0; q < 9; ++q) w1r[q] = w1[k * 9 + q];
  float fsum = 0.f, fsq = 0.f;
  const int wid = blockIdx.x * 4 + w;
  for (int t = 0; t < 4; ++t) {
    const int b = wid * 4 + t;
    ((float4*)sx[w])[lane] = ((const float4*)x)[b * 64 + lane];
    __builtin_amdgcn_wave_barrier();
    for (int q = 0; q < 49; ++q) {
      int p = pg * 49 + q;
      int i = p / 14, j = p - i * 14;
      const float* r0 = &sx[w][i * 16 + j];
      float y = 0.f;
#pragma unroll
      for (int di = 0; di < 3; ++di)
#pragma unroll
        for (int dj = 0; dj < 3; ++dj)
          y += w1r[di * 3 + dj] * r0[di * 16 + dj];
      fsum += y; fsq += y * y;
    }
    __builtin_amdgcn_wave_barrier();
  }
  fsum += __shfl_xor(fsum, 16); fsum += __shfl_xor(fsum, 32);
  fsq  += __shfl_xor(fsq, 16);  fsq  += __shfl_xor(fsq, 32);
  if (lane < 16) { red[w][lane] = fsum; red[w][16 + lane] = fsq; }
  __syncthreads();
  if (tid < 32)
    ws[P1_OFF + blockIdx.x * 32 + tid] =
        red[0][tid] + red[1][tid] + red[2][tid] + red[3][tid];
}

// Generic stats finalize: sum 1024 partials, emit s=g*rsqrt(var+eps), t=b-mean*s
__global__ __launch_bounds__(64) void k_stats(
    const float* __restrict__ gamma, const float* __restrict__ beta,
    float* __restrict__ ws, int nch, int part_off, int st_off, float inv_n)
{
  int c = threadIdx.x;
  if (c >= nch) return;
  float s = 0.f, q = 0.f;
  for (int i = 0; i < NPART; ++i) {
    s += ws[part_off + i * 2 * nch + c];
    q += ws[part_off + i * 2 * nch + nch + c];
  }
  float mean = s * inv_n;
  float var  = q * inv_n - mean * mean;
  float sv   = gamma[c] * rsqrtf(var + 1e-5f);
  ws[st_off + c]       = sv;
  ws[st_off + nch + c] = beta[c] - mean * sv;
}

// K3: per-channel sum/sumsq of raw conv2 output (recompute conv1+bn1+relu).
__global__ __launch_bounds__(256) void k3_conv2_stats(
    const float* __restrict__ x, const float* __restrict__ w1,
    const float* __restrict__ w2, float* __restrict__ ws)
{
  __shared__ float sx[4][256];
  __shared__ float a1w_s[4][2 * 16 * 18];
  __shared__ float w2i[2048];
  __shared__ float red[4][64];
  const int tid = threadIdx.x, w = tid >> 6, lane = tid & 63;
  for (int q = tid; q < 2048; q += 256) {
    int k = q >> 7, di = (q >> 6) & 1, c = (q >> 1) & 31, dj = q & 1;
    w2i[q] = w2[c * 64 + k * 4 + di * 2 + dj];
  }
  const int k1 = lane & 15;
  float w1r[9];
#pragma unroll
  for (int q = 0; q < 9; ++q) w1r[q] = w1[k1 * 9 + q];
  const float rs1 = ws[ST1 + k1], rt1 = ws[ST1 + 16 + k1];
  const int c2 = lane & 31, hf = lane >> 5;
  __syncthreads();
  float fsum = 0.f, fsq = 0.f;
  const int wid = blockIdx.x * 4 + w;
  float* a1w = a1w_s[w];
  for (int t = 0; t < 4; ++t) {
    const int b = wid * 4 + t;
    ((float4*)sx[w])[lane] = ((const float4*)x)[b * 64 + lane];
    __builtin_amdgcn_wave_barrier();
    for (int i = 0; i < 13; ++i) {
      conv1_two_rows(sx[w], a1w, i, lane, w1r, rs1, rt1);
      __builtin_amdgcn_wave_barrier();
      float acc[7];
      conv2_row(a1w, w2i, c2, hf, acc);
#pragma unroll
      for (int q = 0; q < 7; ++q) {
        bool valid = hf ? true : (q < 6);   // j=6 owned by hf=1
        float y = acc[q];
        fsum += valid ? y : 0.f;
        fsq  += valid ? y * y : 0.f;
      }
      __builtin_amdgcn_wave_barrier();
    }
  }
  fsum += __shfl_xor(fsum, 32);
  fsq  += __shfl_xor(fsq, 32);
  if (lane < 32) { red[w][c2] = fsum; red[w][32 + c2] = fsq; }
  __syncthreads();
  if (tid < 64)
    ws[P2_OFF + blockIdx.x * 64 + tid] =
        red[0][tid] + red[1][tid] + red[2][tid] + red[3][tid];
}

// K5: per-channel sum/sumsq of raw conv3 output (recompute chain through a2).
__global__ __launch_bounds__(256) void k5_conv3_stats(
    const float* __restrict__ x, const float* __restrict__ w1,
    const float* __restrict__ w2, const float* __restrict__ w3,
    float* __restrict__ ws)
{
  __shared__ float sx[4][256];
  __shared__ float a1w_s[4][2 * 16 * 18];
  __shared__ float a2r_s[4][32 * 18];
  __shared__ float w2i[2048];
  __shared__ float w3t[2048];
  __shared__ float red[4][128];
  const int tid = threadIdx.x, w = tid >> 6, lane = tid & 63;
  for (int q = tid; q < 2048; q += 256) {
    int k = q >> 7, di = (q >> 6) & 1, c = (q >> 1) & 31, dj = q & 1;
    w2i[q] = w2[c * 64 + k * 4 + di * 2 + dj];
  }
  for (int q = tid; q < 2048; q += 256) {
    int k = q >> 6, c = q & 63;
    w3t[q] = w3[c * 32 + k];
  }
  const int k1 = lane & 15;
  float w1r[9];
#pragma unroll
  for (int q = 0; q < 9; ++q) w1r[q] = w1[k1 * 9 + q];
  const float rs1 = ws[ST1 + k1], rt1 = ws[ST1 + 16 + k1];
  const int c2 = lane & 31, hf = lane >> 5;
  const float rs2 = ws[ST2 + c2], rt2 = ws[ST2 + 32 + c2];
  __syncthreads();
  float fsum = 0.f, fsq = 0.f;
  const int wid = blockIdx.x * 4 + w;
  float* a1w = a1w_s[w];
  float* a2r = a2r_s[w];
  for (int t = 0; t < 4; ++t) {
    const int b = wid * 4 + t;
    ((float4*)sx[w])[lane] = ((const float4*)x)[b * 64 + lane];
    __builtin_amdgcn_wave_barrier();
    for (int i = 0; i < 13; ++i) {
      conv1_two_rows(sx[w], a1w, i, lane, w1r, rs1, rt1);
      __builtin_amdgcn_wave_barrier();
      float acc[7];
      conv2_row(a1w, w2i, c2, hf, acc);
      float* pa2 = a2r + c2 * 18 + hf * 6;
#pragma unroll
      for (int q = 0; q < 7; ++q) {
        float v = rs2 * acc[q] + rt2;
        pa2[q] = v > 0.f ? v : 0.f;     // j=6 double-written identically
      }
      __builtin_amdgcn_wave_barrier();
      float y3[13];
      conv3_row(a2r, w3t, lane, y3);
#pragma unroll
      for (int j = 0; j < 13; ++j) { fsum += y3[j]; fsq += y3[j] * y3[j]; }
      __builtin_amdgcn_wave_barrier();
    }
  }
  red[w][lane] = fsum; red[w][64 + lane] = fsq;
  __syncthreads();
  if (tid < 128)
    ws[P3_OFF + blockIdx.x * 128 + tid] =
        red[0][tid] + red[1][tid] + red[2][tid] + red[3][tid];
}

// K7: full chain + FC. 8 images/block, row-streaming; per-row fc_w slice
// staged to LDS as packed bf16 pairs, amortized over the 8 images.
__global__ __launch_bounds__(256) void k7_final(
    const float* __restrict__ x, const float* __restrict__ w1,
    const float* __restrict__ w2, const float* __restrict__ w3,
    const float* __restrict__ fcw, const float* __restrict__ fcb,
    const float* __restrict__ ws, float* __restrict__ out)
{
  __shared__ float sx[8 * 256];            // 8KB
  __shared__ float a1w_s[4][2 * 16 * 18];  // 9.2KB
  __shared__ float a2r_s[4][32 * 18];      // 9.2KB
  __shared__ float w2i[2048];              // 8KB
  __shared__ float w3t[2048];              // 8KB
  __shared__ unsigned int fcp[10 * 64 * 7];// 17.9KB packed bf16 pairs
  const int tid = threadIdx.x, w = tid >> 6, lane = tid & 63;
  for (int q = tid; q < 2048; q += 256) sx[q] = x[blockIdx.x * 2048 + q];
  for (int q = tid; q < 2048; q += 256) {
    int k = q >> 7, di = (q >> 6) & 1, c = (q >> 1) & 31, dj = q & 1;
    w2i[q] = w2[c * 64 + k * 4 + di * 2 + dj];
  }
  for (int q = tid; q < 2048; q += 256) {
    int k = q >> 6, c = q & 63;
    w3t[q] = w3[c * 32 + k];
  }
  const int k1 = lane & 15;
  float w1r[9];
#pragma unroll
  for (int q = 0; q < 9; ++q) w1r[q] = w1[k1 * 9 + q];
  const float rs1 = ws[ST1 + k1], rt1 = ws[ST1 + 16 + k1];
  const int c2 = lane & 31, hf = lane >> 5;
  const float rs2 = ws[ST2 + c2], rt2 = ws[ST2 + 32 + c2];
  const float rs3 = ws[ST3 + lane], rt3 = ws[ST3 + 64 + lane];
  float pacc[2][10];
#pragma unroll
  for (int t = 0; t < 2; ++t)
#pragma unroll
    for (int jj = 0; jj < 10; ++jj) pacc[t][jj] = 0.f;
  __syncthreads();

  for (int i = 0; i < 13; ++i) {
    // stage this row's FC weight slice: fcp[jj][c][jp] = bf16(w_j0)|bf16(w_j1)<<16
    for (int q = tid; q < 4480; q += 256) {
      int jj = q / 448, r = q - jj * 448, c = r / 7, jp = r - c * 7;
      const float* pw = fcw + jj * 10816 + c * 169 + i * 13;
      float w0 = pw[2 * jp];
      float w1v = (2 * jp + 1 < 13) ? pw[2 * jp + 1] : 0.f;
      fcp[q] = f2bf(w0) | (f2bf(w1v) << 16);
    }
    __syncthreads();
#pragma unroll
    for (int t = 0; t < 2; ++t) {
      const int g = w * 2 + t;
      conv1_two_rows(sx + g * 256, a1w_s[w], i, lane, w1r, rs1, rt1);
      __builtin_amdgcn_wave_barrier();
      float acc[7];
      conv2_row(a1w_s[w], w2i, c2, hf, acc);
      float* pa2 = a2r_s[w] + c2 * 18 + hf * 6;
#pragma unroll
      for (int q = 0; q < 7; ++q) {
        float v = rs2 * acc[q] + rt2;
        pa2[q] = v > 0.f ? v : 0.f;
      }
      __builtin_amdgcn_wave_barrier();
      float y3[13];
      conv3_row(a2r_s[w], w3t, lane, y3);
      float a3[13];
#pragma unroll
      for (int j = 0; j < 13; ++j) {
        float v = rs3 * y3[j] + rt3;
        a3[j] = v > 0.f ? v : 0.f;
      }
#pragma unroll
      for (int jj = 0; jj < 10; ++jj) {
        const unsigned int* pf = fcp + jj * 448 + lane * 7;
        float s = 0.f;
#pragma unroll
        for (int jp = 0; jp < 7; ++jp) {
          unsigned int u = pf[jp];
          s += __uint_as_float(u << 16) * a3[2 * jp];
          if (jp < 6) s += __uint_as_float(u & 0xffff0000u) * a3[2 * jp + 1];
        }
        pacc[t][jj] += s;
      }
      __builtin_amdgcn_wave_barrier();
    }
    __syncthreads();   // all waves done with fcp before next row restage
  }

#pragma unroll
  for (int t = 0; t < 2; ++t) {
    const int b = blockIdx.x * 8 + w * 2 + t;
    float res = 0.f;
#pragma unroll
    for (int jj = 0; jj < 10; ++jj) {
      float v = pacc[t][jj];
      v += __shfl_xor(v, 1);  v += __shfl_xor(v, 2);  v += __shfl_xor(v, 4);
      v += __shfl_xor(v, 8);  v += __shfl_xor(v, 16); v += __shfl_xor(v, 32);
      if (lane == jj) res = v;
    }
    if (lane < 10) out[b * 10 + lane] = res + fcb[lane];
  }
}

extern "C" void kernel_launch(void* const* d_in, const int* in_sizes, int n_in,
                              void* d_out, int out_size, void* d_ws, size_t ws_size,
                              hipStream_t stream) {
  (void)in_sizes; (void)n_in; (void)out_size; (void)ws_size;
  const float* x   = (const float*)d_in[0];
  const float* w1  = (const float*)d_in[1];
  const float* w2  = (const float*)d_in[2];
  const float* w3  = (const float*)d_in[3];
  const float* g1  = (const float*)d_in[4];
  const float* b1  = (const float*)d_in[5];
  const float* g2  = (const float*)d_in[6];
  const float* b2  = (const float*)d_in[7];
  const float* g3  = (const float*)d_in[8];
  const float* b3  = (const float*)d_in[9];
  const float* fcw = (const float*)d_in[10];
  const float* fcb = (const float*)d_in[11];
  float* out = (float*)d_out;
  float* ws  = (float*)d_ws;

  k1_conv1_stats<<<1024, 256, 0, stream>>>(x, w1, ws);
  k_stats<<<1, 64, 0, stream>>>(g1, b1, ws, 16, P1_OFF, ST1,
                                1.0f / (16384.0f * 196.0f));
  k3_conv2_stats<<<1024, 256, 0, stream>>>(x, w1, w2, ws);
  k_stats<<<1, 64, 0, stream>>>(g2, b2, ws, 32, P2_OFF, ST2,
                                1.0f / (16384.0f * 169.0f));
  k5_conv3_stats<<<1024, 256, 0, stream>>>(x, w1, w2, w3, ws);
  k_stats<<<1, 64, 0, stream>>>(g3, b3, ws, 64, P3_OFF, ST3,
                                1.0f / (16384.0f * 169.0f));
  k7_final<<<2048, 256, 0, stream>>>(x, w1, w2, w3, fcw, fcb, ws, out);
}

// Round 2
// 1306.063 us; speedup vs baseline: 1.9123x; 1.9123x over previous
//
#include <hip/hip_runtime.h>

// ---------------------------------------------------------------------------
// LocallyConnectedNN: x[16384,256] -> conv3x3(1->16)+BN+ReLU -> conv2x2(16->32)
// +BN+ReLU -> conv1x1(32->64)+BN+ReLU -> FC(10816->10).
// Round 2: conv2/conv3 on MFMA 16x16x32 bf16 (split-precision), channel-last
// LDS layouts, FC weights pre-transposed into ws for coalesced staging.
// ws: P1/P2/P3 block partials + scale/shift; fcwT reuses [0,68640) after
// stats1/2 are consumed (launch order guarantees no overlap in time).
// ---------------------------------------------------------------------------

#define NPART 1024
#define P1_OFF 0          // [1024][32]  (16 sums | 16 sumsq)
#define P2_OFF 32768      // [1024][64]
#define P3_OFF 98304      // [1024][128]
#define ST_OFF 229376     // s1[16] t1[16] s2[32] t2[32] s3[64] t3[64]
#define ST1 ST_OFF
#define ST2 (ST_OFF + 32)
#define ST3 (ST_OFF + 96)
#define FCT_N (13 * 5280) // fcwT packed u32 at ws[0..68640), reused region

typedef __attribute__((ext_vector_type(8))) short bf16x8;
typedef __attribute__((ext_vector_type(4))) float f32x4;

__device__ __forceinline__ unsigned int f2bf(float f) {
  unsigned int u = __float_as_uint(f);
  return (u + 0x7fffu + ((u >> 16) & 1u)) >> 16;   // RTNE bf16 bits
}
__device__ __forceinline__ float bf2f(unsigned int hb) {
  return __uint_as_float(hb << 16);
}

// conv1 (3x3, 1->16) + bn1 + relu, one output row r, channel-last split bf16.
// lane: b = lane&15 (channel), jg = lane>>4 (4-col group).
__device__ __forceinline__ void conv1_row(
    const float* __restrict__ sxi,   // [256] one 16x16 image
    short* ph_buf, short* pl_buf,    // [2 bufs][16 j][16 k]
    int r, int b, int jg, const float* w1r, float rs1, float rt1)
{
  short* ph = ph_buf + (r & 1) * 256;
  short* pl = pl_buf + (r & 1) * 256;
#pragma unroll
  for (int jq = 0; jq < 4; ++jq) {
    int j = jg * 4 + jq;
    if (j < 14) {
      float y = 0.f;
#pragma unroll
      for (int di = 0; di < 3; ++di)
#pragma unroll
        for (int dj = 0; dj < 3; ++dj)
          y += w1r[di * 3 + dj] * sxi[(r + di) * 16 + j + dj];
      y = rs1 * y + rt1;
      y = y > 0.f ? y : 0.f;
      unsigned hi = f2bf(y);
      ph[j * 16 + b] = (short)hi;
      pl[j * 16 + b] = (short)f2bf(y - bf2f(hi));
    }
  }
}

// K1: per-channel sum/sumsq of raw conv1 output (unchanged from round 1).
__global__ __launch_bounds__(256) void k1_conv1_stats(
    const float* __restrict__ x, const float* __restrict__ w1,
    float* __restrict__ ws)
{
  __shared__ float sx[4][256];
  __shared__ float red[4][32];
  const int tid = threadIdx.x, w = tid >> 6, lane = tid & 63;
  const int k = lane & 15, pg = lane >> 4;
  float w1r[9];
#pragma unroll
  for (int q = 0; q < 9; ++q) w1r[q] = w1[k * 9 + q];
  float fsum = 0.f, fsq = 0.f;
  const int wid = blockIdx.x * 4 + w;
  for (int t = 0; t < 4; ++t) {
    const int b = wid * 4 + t;
    ((float4*)sx[w])[lane] = ((const float4*)x)[b * 64 + lane];
    __builtin_amdgcn_wave_barrier();
    for (int q = 0; q < 49; ++q) {
      int p = pg * 49 + q;
      int i = p / 14, j = p - i * 14;
      const float* r0 = &sx[w][i * 16 + j];
      float y = 0.f;
#pragma unroll
      for (int di = 0; di < 3; ++di)
#pragma unroll
        for (int dj = 0; dj < 3; ++dj)
          y += w1r[di * 3 + dj] * r0[di * 16 + dj];
      fsum += y; fsq += y * y;
    }
    __builtin_amdgcn_wave_barrier();
  }
  fsum += __shfl_xor(fsum, 16); fsum += __shfl_xor(fsum, 32);
  fsq  += __shfl_xor(fsq, 16);  fsq  += __shfl_xor(fsq, 32);
  if (lane < 16) { red[w][lane] = fsum; red[w][16 + lane] = fsq; }
  __syncthreads();
  if (tid < 32)
    ws[P1_OFF + blockIdx.x * 32 + tid] =
        red[0][tid] + red[1][tid] + red[2][tid] + red[3][tid];
}

// Stats finalize: sum 1024 partials, emit s=g*rsqrt(var+eps), t=b-mean*s
__global__ __launch_bounds__(64) void k_stats(
    const float* __restrict__ gamma, const float* __restrict__ beta,
    float* __restrict__ ws, int nch, int part_off, int st_off, float inv_n)
{
  int c = threadIdx.x;
  if (c >= nch) return;
  float s = 0.f, q = 0.f;
  for (int i = 0; i < NPART; ++i) {
    s += ws[part_off + i * 2 * nch + c];
    q += ws[part_off + i * 2 * nch + nch + c];
  }
  float mean = s * inv_n;
  float var  = q * inv_n - mean * mean;
  float sv   = gamma[c] * rsqrtf(var + 1e-5f);
  ws[st_off + c]       = sv;
  ws[st_off + nch + c] = beta[c] - mean * sv;
}

// K0: transpose+pack fc_w into ws as u32: fcT[i][jj][j(16)][p(33)] =
// bf16(w[jj][p][i][j]) | bf16(w[jj][p+32][i][j])<<16  (zeros for pads)
__global__ __launch_bounds__(256) void k0_fcT(
    const float* __restrict__ fcw, unsigned int* __restrict__ fcT)
{
  int e = blockIdx.x * 256 + threadIdx.x;
  if (e >= FCT_N) return;
  int i = e / 5280, rem = e - i * 5280;
  int jj = rem / 528, rem2 = rem - jj * 528;
  int j = rem2 / 33, p = rem2 - j * 33;
  unsigned int v = 0;
  if (p < 32 && j < 13) {
    float w0 = fcw[jj * 10816 + p * 169 + i * 13 + j];
    float w1v = fcw[jj * 10816 + (p + 32) * 169 + i * 13 + j];
    v = f2bf(w0) | (f2bf(w1v) << 16);
  }
  fcT[e] = v;
}

// Main MFMA pipeline. STAGE: 3 = conv2 stats, 5 = conv3 stats, 7 = final+FC.
// MFMA 16x16x32 bf16 layouts (verified, guide §3):
//   A: m=lane&15, k=8*(lane>>4)+j   B: n=lane&15, k=8*(lane>>4)+j
//   D: n=lane&15, m=4*(lane>>4)+reg
// M-tile = 13-pixel output row padded to 16 (garbage rows masked).
template <int STAGE>
__global__ __launch_bounds__(256, 3) void k_pipe(
    const float* __restrict__ x, const float* __restrict__ w1,
    const float* __restrict__ w2, const float* __restrict__ w3,
    const float* __restrict__ fcb, float* __restrict__ ws,
    float* __restrict__ out)
{
  constexpr int NIW = (STAGE == 7) ? 2 : 4;    // images per wave
  constexpr int NWIN = (STAGE == 7) ? 2 : 1;   // live a1 windows per wave
  constexpr int NIB = NIW * 4;                 // images per block

  __shared__ float sx[NIB * 256];
  __shared__ alignas(16) short a1h[4 * NWIN * 512];  // [w][win][buf2][j16][k16]
  __shared__ alignas(16) short a1l[4 * NWIN * 512];
  __shared__ alignas(16) short a2s[(STAGE >= 5) ? 4 * 640 : 8]; // [w][pix16][40]
  __shared__ unsigned int fcp[(STAGE == 7) ? 5280 : 1];         // [jj][j16][33]
  __shared__ float red[(STAGE == 3) ? 256 : ((STAGE == 5) ? 512 : 1)];

  const int tid = threadIdx.x, w = tid >> 6, lane = tid & 63;
  const int b = lane & 15, q = lane >> 4;

  // stage x (coalesced float4)
  {
    const float4* xs = (const float4*)(x + (size_t)blockIdx.x * (NIB * 256));
    float4* sd = (float4*)sx;
    for (int e = tid; e < NIB * 64; e += 256) sd[e] = xs[e];
  }

  // conv1 weights + bn1 (lane channel = b)
  float w1r[9];
#pragma unroll
  for (int t = 0; t < 9; ++t) w1r[t] = w1[b * 9 + t];
  const float rs1 = ws[ST1 + b], rt1 = ws[ST1 + 16 + b];

  // conv2 weight B-frags, split hi/lo. K = ks*32 + dj*16 + kk (di=ks).
  bf16x8 b2h[4], b2l[4];
#pragma unroll
  for (int ks = 0; ks < 2; ++ks)
#pragma unroll
    for (int nt = 0; nt < 2; ++nt) {
      bf16x8 vh, vl;
#pragma unroll
      for (int j = 0; j < 8; ++j) {
        int kk = 8 * (q & 1) + j, dj = q >> 1;
        float wv = w2[(nt * 16 + b) * 64 + kk * 4 + ks * 2 + dj];
        unsigned hi = f2bf(wv);
        vh[j] = (short)hi;
        vl[j] = (short)f2bf(wv - bf2f(hi));
      }
      b2h[ks * 2 + nt] = vh;
      b2l[ks * 2 + nt] = vl;
    }

  bf16x8 b3h[4], b3l[4];
  float rs2v[2], rt2v[2], rs3v[4], rt3v[4];
  if constexpr (STAGE >= 5) {
#pragma unroll
    for (int nt = 0; nt < 4; ++nt) {
      bf16x8 vh, vl;
#pragma unroll
      for (int j = 0; j < 8; ++j) {
        float wv = w3[(nt * 16 + b) * 32 + 8 * q + j];
        unsigned hi = f2bf(wv);
        vh[j] = (short)hi;
        vl[j] = (short)f2bf(wv - bf2f(hi));
      }
      b3h[nt] = vh; b3l[nt] = vl;
    }
#pragma unroll
    for (int nt = 0; nt < 2; ++nt) {
      rs2v[nt] = ws[ST2 + nt * 16 + b];
      rt2v[nt] = ws[ST2 + 32 + nt * 16 + b];
    }
  }
  if constexpr (STAGE == 7) {
#pragma unroll
    for (int nt = 0; nt < 4; ++nt) {
      rs3v[nt] = ws[ST3 + nt * 16 + b];
      rt3v[nt] = ws[ST3 + 64 + nt * 16 + b];
    }
  }

  // per-lane A-frag offsets (shorts). conv2: m=b pixel, col=min(b+dj,15).
  const int colA = b + (q >> 1);
  const int offA = (colA < 15 ? colA : 15) * 16 + 8 * (q & 1);
  const int offA3 = b * 40 + 8 * q;
  short* a2w = a2s + w * 640;

  __syncthreads();

  if constexpr (STAGE != 7) {
    float s2[2] = {0.f, 0.f}, q2[2] = {0.f, 0.f};
    float s3[4] = {0.f, 0.f, 0.f, 0.f}, q3[4] = {0.f, 0.f, 0.f, 0.f};
    short* ph = a1h + w * 512;
    short* pl = a1l + w * 512;
#pragma unroll 1
    for (int t = 0; t < NIW; ++t) {
      const float* sxi = sx + (w * NIW + t) * 256;
      conv1_row(sxi, ph, pl, 0, b, q, w1r, rs1, rt1);
      __builtin_amdgcn_wave_barrier();
#pragma unroll 1
      for (int i = 0; i < 13; ++i) {
        conv1_row(sxi, ph, pl, i + 1, b, q, w1r, rs1, rt1);
        __builtin_amdgcn_wave_barrier();
        f32x4 acc2[2] = {{0.f,0.f,0.f,0.f},{0.f,0.f,0.f,0.f}};
#pragma unroll
        for (int ks = 0; ks < 2; ++ks) {
          int par = (i + ks) & 1;
          bf16x8 ah = *(const bf16x8*)(ph + par * 256 + offA);
          bf16x8 al = *(const bf16x8*)(pl + par * 256 + offA);
#pragma unroll
          for (int nt = 0; nt < 2; ++nt) {
            acc2[nt] = __builtin_amdgcn_mfma_f32_16x16x32_bf16(ah, b2h[ks*2+nt], acc2[nt], 0, 0, 0);
            acc2[nt] = __builtin_amdgcn_mfma_f32_16x16x32_bf16(al, b2h[ks*2+nt], acc2[nt], 0, 0, 0);
            acc2[nt] = __builtin_amdgcn_mfma_f32_16x16x32_bf16(ah, b2l[ks*2+nt], acc2[nt], 0, 0, 0);
          }
        }
        if constexpr (STAGE == 3) {
#pragma unroll
          for (int nt = 0; nt < 2; ++nt)
#pragma unroll
            for (int r = 0; r < 4; ++r) {
              bool vd = (4 * q + r) < 13;
              float y = acc2[nt][r];
              s2[nt] += vd ? y : 0.f;
              q2[nt] += vd ? y * y : 0.f;
            }
        } else {
#pragma unroll
          for (int nt = 0; nt < 2; ++nt)
#pragma unroll
            for (int r = 0; r < 4; ++r) {
              float v = rs2v[nt] * acc2[nt][r] + rt2v[nt];
              v = v > 0.f ? v : 0.f;          // kills NaN garbage rows too
              a2w[(4 * q + r) * 40 + nt * 16 + b] = (short)f2bf(v);
            }
          __builtin_amdgcn_wave_barrier();
          bf16x8 a2f = *(const bf16x8*)(a2w + offA3);
#pragma unroll
          for (int nt = 0; nt < 4; ++nt) {
            f32x4 acc3 = {0.f, 0.f, 0.f, 0.f};
            acc3 = __builtin_amdgcn_mfma_f32_16x16x32_bf16(a2f, b3h[nt], acc3, 0, 0, 0);
            acc3 = __builtin_amdgcn_mfma_f32_16x16x32_bf16(a2f, b3l[nt], acc3, 0, 0, 0);
#pragma unroll
            for (int r = 0; r < 4; ++r) {
              bool vd = (4 * q + r) < 13;
              float y = acc3[r];
              s3[nt] += vd ? y : 0.f;
              q3[nt] += vd ? y * y : 0.f;
            }
          }
        }
        __builtin_amdgcn_wave_barrier();
      }
    }
    if constexpr (STAGE == 3) {
#pragma unroll
      for (int nt = 0; nt < 2; ++nt) {
        s2[nt] += __shfl_xor(s2[nt], 16); s2[nt] += __shfl_xor(s2[nt], 32);
        q2[nt] += __shfl_xor(q2[nt], 16); q2[nt] += __shfl_xor(q2[nt], 32);
      }
      if (lane < 16) {
        red[w * 64 + b]      = s2[0];
        red[w * 64 + 16 + b] = s2[1];
        red[w * 64 + 32 + b] = q2[0];
        red[w * 64 + 48 + b] = q2[1];
      }
      __syncthreads();
      if (tid < 64)
        ws[P2_OFF + blockIdx.x * 64 + tid] =
            red[tid] + red[64 + tid] + red[128 + tid] + red[192 + tid];
    } else {
#pragma unroll
      for (int nt = 0; nt < 4; ++nt) {
        s3[nt] += __shfl_xor(s3[nt], 16); s3[nt] += __shfl_xor(s3[nt], 32);
        q3[nt] += __shfl_xor(q3[nt], 16); q3[nt] += __shfl_xor(q3[nt], 32);
      }
      if (lane < 16) {
#pragma unroll
        for (int nt = 0; nt < 4; ++nt) {
          red[w * 128 + nt * 16 + b]      = s3[nt];
          red[w * 128 + 64 + nt * 16 + b] = q3[nt];
        }
      }
      __syncthreads();
      if (tid < 128)
        ws[P3_OFF + blockIdx.x * 128 + tid] =
            red[tid] + red[128 + tid] + red[256 + tid] + red[384 + tid];
    }
  }

  if constexpr (STAGE == 7) {
    const unsigned int* fcT = (const unsigned int*)ws;
    float pacc[2][10];
#pragma unroll
    for (int t = 0; t < 2; ++t)
#pragma unroll
      for (int jj = 0; jj < 10; ++jj) pacc[t][jj] = 0.f;

#pragma unroll
    for (int t = 0; t < 2; ++t)
      conv1_row(sx + (w * 2 + t) * 256, a1h + (w * 2 + t) * 512,
                a1l + (w * 2 + t) * 512, 0, b, q, w1r, rs1, rt1);

#pragma unroll 1
    for (int i = 0; i < 13; ++i) {
      for (int e = tid; e < 5280; e += 256) fcp[e] = fcT[i * 5280 + e];
      __syncthreads();
#pragma unroll
      for (int t = 0; t < 2; ++t) {
        const float* sxi = sx + (w * 2 + t) * 256;
        short* ph = a1h + (w * 2 + t) * 512;
        short* pl = a1l + (w * 2 + t) * 512;
        conv1_row(sxi, ph, pl, i + 1, b, q, w1r, rs1, rt1);
        __builtin_amdgcn_wave_barrier();
        f32x4 acc2[2] = {{0.f,0.f,0.f,0.f},{0.f,0.f,0.f,0.f}};
#pragma unroll
        for (int ks = 0; ks < 2; ++ks) {
          int par = (i + ks) & 1;
          bf16x8 ah = *(const bf16x8*)(ph + par * 256 + offA);
          bf16x8 al = *(const bf16x8*)(pl + par * 256 + offA);
#pragma unroll
          for (int nt = 0; nt < 2; ++nt) {
            acc2[nt] = __builtin_amdgcn_mfma_f32_16x16x32_bf16(ah, b2h[ks*2+nt], acc2[nt], 0, 0, 0);
            acc2[nt] = __builtin_amdgcn_mfma_f32_16x16x32_bf16(al, b2h[ks*2+nt], acc2[nt], 0, 0, 0);
            acc2[nt] = __builtin_amdgcn_mfma_f32_16x16x32_bf16(ah, b2l[ks*2+nt], acc2[nt], 0, 0, 0);
          }
        }
#pragma unroll
        for (int nt = 0; nt < 2; ++nt)
#pragma unroll
          for (int r = 0; r < 4; ++r) {
            float v = rs2v[nt] * acc2[nt][r] + rt2v[nt];
            v = v > 0.f ? v : 0.f;
            a2w[(4 * q + r) * 40 + nt * 16 + b] = (short)f2bf(v);
          }
        __builtin_amdgcn_wave_barrier();
        bf16x8 a2f = *(const bf16x8*)(a2w + offA3);
        float a3v[4][4];
#pragma unroll
        for (int nt = 0; nt < 4; ++nt) {
          f32x4 acc3 = {0.f, 0.f, 0.f, 0.f};
          acc3 = __builtin_amdgcn_mfma_f32_16x16x32_bf16(a2f, b3h[nt], acc3, 0, 0, 0);
          acc3 = __builtin_amdgcn_mfma_f32_16x16x32_bf16(a2f, b3l[nt], acc3, 0, 0, 0);
#pragma unroll
          for (int r = 0; r < 4; ++r) {
            float v = rs3v[nt] * acc3[r] + rt3v[nt];
            v = v > 0.f ? v : 0.f;
            a3v[nt][r] = (4 * q + r) < 13 ? v : 0.f;
          }
        }
#pragma unroll
        for (int jj = 0; jj < 10; ++jj) {
          float s = 0.f;
#pragma unroll
          for (int r = 0; r < 4; ++r) {
            int jrow = 4 * q + r;
            unsigned u0 = fcp[(jj * 16 + jrow) * 33 + b];
            unsigned u1 = fcp[(jj * 16 + jrow) * 33 + b + 16];
            s += bf2f(u0 & 0xffffu) * a3v[0][r];
            s += __uint_as_float(u0 & 0xffff0000u) * a3v[2][r];
            s += bf2f(u1 & 0xffffu) * a3v[1][r];
            s += __uint_as_float(u1 & 0xffff0000u) * a3v[3][r];
          }
          pacc[t][jj] += s;
        }
        __builtin_amdgcn_wave_barrier();
      }
      __syncthreads();
    }

#pragma unroll
    for (int t = 0; t < 2; ++t) {
      const int bi = blockIdx.x * 8 + w * 2 + t;
      float res = 0.f;
#pragma unroll
      for (int jj = 0; jj < 10; ++jj) {
        float v = pacc[t][jj];
        v += __shfl_xor(v, 1);  v += __shfl_xor(v, 2);  v += __shfl_xor(v, 4);
        v += __shfl_xor(v, 8);  v += __shfl_xor(v, 16); v += __shfl_xor(v, 32);
        if (lane == jj) res = v;
      }
      if (lane < 10) out[bi * 10 + lane] = res + fcb[lane];
    }
  }
}

extern "C" void kernel_launch(void* const* d_in, const int* in_sizes, int n_in,
                              void* d_out, int out_size, void* d_ws, size_t ws_size,
                              hipStream_t stream) {
  (void)in_sizes; (void)n_in; (void)out_size; (void)ws_size;
  const float* x   = (const float*)d_in[0];
  const float* w1  = (const float*)d_in[1];
  const float* w2  = (const float*)d_in[2];
  const float* w3  = (const float*)d_in[3];
  const float* g1  = (const float*)d_in[4];
  const float* b1  = (const float*)d_in[5];
  const float* g2  = (const float*)d_in[6];
  const float* b2  = (const float*)d_in[7];
  const float* g3  = (const float*)d_in[8];
  const float* b3  = (const float*)d_in[9];
  const float* fcw = (const float*)d_in[10];
  const float* fcb = (const float*)d_in[11];
  float* out = (float*)d_out;
  float* ws  = (float*)d_ws;

  k1_conv1_stats<<<1024, 256, 0, stream>>>(x, w1, ws);
  k_stats<<<1, 64, 0, stream>>>(g1, b1, ws, 16, P1_OFF, ST1,
                                1.0f / (16384.0f * 196.0f));
  k_pipe<3><<<1024, 256, 0, stream>>>(x, w1, w2, w3, fcb, ws, out);
  k_stats<<<1, 64, 0, stream>>>(g2, b2, ws, 32, P2_OFF, ST2,
                                1.0f / (16384.0f * 169.0f));
  k_pipe<5><<<1024, 256, 0, stream>>>(x, w1, w2, w3, fcb, ws, out);
  k_stats<<<1, 64, 0, stream>>>(g3, b3, ws, 64, P3_OFF, ST3,
                                1.0f / (16384.0f * 169.0f));
  k0_fcT<<<(FCT_N + 255) / 256, 256, 0, stream>>>(fcw, (unsigned int*)ws);
  k_pipe<7><<<2048, 256, 0, stream>>>(x, w1, w2, w3, fcb, ws, out);
}

// Round 3
// 608.715 us; speedup vs baseline: 4.1031x; 2.1456x over previous
//
#include <hip/hip_runtime.h>

// ---------------------------------------------------------------------------
// LocallyConnectedNN: x[16384,256] -> conv3x3(1->16)+BN+ReLU -> conv2x2(16->32)
// +BN+ReLU -> conv1x1(32->64)+BN+ReLU -> FC(10816->10).
// Round 3: single-bf16 precision throughout (lo-planes dropped: round-2
// counters showed 1.76GB/214MB scratch-spill traffic from 64 VGPRs of weight
// fragments under launch_bounds(256,3)). launch_bounds relaxed to (256).
// Stats finalize parallelized to grid=nch blocks.
// ---------------------------------------------------------------------------

#define NPART 1024
#define P1_OFF 0          // [1024][32]  (16 sums | 16 sumsq)
#define P2_OFF 32768      // [1024][64]
#define P3_OFF 98304      // [1024][128]
#define ST_OFF 229376     // s1[16] t1[16] s2[32] t2[32] s3[64] t3[64]
#define ST1 ST_OFF
#define ST2 (ST_OFF + 32)
#define ST3 (ST_OFF + 96)
#define FCT_N (13 * 5280) // fcwT packed u32 at ws[0..68640), reused region

typedef __attribute__((ext_vector_type(8))) short bf16x8;
typedef __attribute__((ext_vector_type(4))) float f32x4;

__device__ __forceinline__ unsigned int f2bf(float f) {
  unsigned int u = __float_as_uint(f);
  return (u + 0x7fffu + ((u >> 16) & 1u)) >> 16;   // RTNE bf16 bits
}
__device__ __forceinline__ float bf2f(unsigned int hb) {
  return __uint_as_float(hb << 16);
}

// conv1 (3x3, 1->16) + bn1 + relu, one output row r, channel-last bf16.
// lane: b = lane&15 (channel), jg = lane>>4 (4-col group).
__device__ __forceinline__ void conv1_row(
    const float* __restrict__ sxi,   // [256] one 16x16 image
    short* ph_buf,                   // [2 bufs][16 j][16 k]
    int r, int b, int jg, const float* w1r, float rs1, float rt1)
{
  short* ph = ph_buf + (r & 1) * 256;
#pragma unroll
  for (int jq = 0; jq < 4; ++jq) {
    int j = jg * 4 + jq;
    if (j < 14) {
      float y = 0.f;
#pragma unroll
      for (int di = 0; di < 3; ++di)
#pragma unroll
        for (int dj = 0; dj < 3; ++dj)
          y += w1r[di * 3 + dj] * sxi[(r + di) * 16 + j + dj];
      y = rs1 * y + rt1;
      y = y > 0.f ? y : 0.f;
      ph[j * 16 + b] = (short)f2bf(y);
    }
  }
}

// K1: per-channel sum/sumsq of raw conv1 output.
__global__ __launch_bounds__(256) void k1_conv1_stats(
    const float* __restrict__ x, const float* __restrict__ w1,
    float* __restrict__ ws)
{
  __shared__ float sx[4][256];
  __shared__ float red[4][32];
  const int tid = threadIdx.x, w = tid >> 6, lane = tid & 63;
  const int k = lane & 15, pg = lane >> 4;
  float w1r[9];
#pragma unroll
  for (int q = 0; q < 9; ++q) w1r[q] = w1[k * 9 + q];
  float fsum = 0.f, fsq = 0.f;
  const int wid = blockIdx.x * 4 + w;
  for (int t = 0; t < 4; ++t) {
    const int b = wid * 4 + t;
    ((float4*)sx[w])[lane] = ((const float4*)x)[b * 64 + lane];
    __builtin_amdgcn_wave_barrier();
    for (int q = 0; q < 49; ++q) {
      int p = pg * 49 + q;
      int i = p / 14, j = p - i * 14;
      const float* r0 = &sx[w][i * 16 + j];
      float y = 0.f;
#pragma unroll
      for (int di = 0; di < 3; ++di)
#pragma unroll
        for (int dj = 0; dj < 3; ++dj)
          y += w1r[di * 3 + dj] * r0[di * 16 + dj];
      fsum += y; fsq += y * y;
    }
    __builtin_amdgcn_wave_barrier();
  }
  fsum += __shfl_xor(fsum, 16); fsum += __shfl_xor(fsum, 32);
  fsq  += __shfl_xor(fsq, 16);  fsq  += __shfl_xor(fsq, 32);
  if (lane < 16) { red[w][lane] = fsum; red[w][16 + lane] = fsq; }
  __syncthreads();
  if (tid < 32)
    ws[P1_OFF + blockIdx.x * 32 + tid] =
        red[0][tid] + red[1][tid] + red[2][tid] + red[3][tid];
}

// Stats finalize, one block per channel: sum 1024 partials in parallel,
// emit s=g*rsqrt(var+eps), t=b-mean*s.
__global__ __launch_bounds__(256) void k_stats2(
    const float* __restrict__ gamma, const float* __restrict__ beta,
    float* __restrict__ ws, int nch, int part_off, int st_off, float inv_n)
{
  const int c = blockIdx.x, tid = threadIdx.x;
  const int w = tid >> 6, lane = tid & 63;
  __shared__ float rs[4], rq[4];
  float s = 0.f, q = 0.f;
#pragma unroll 4
  for (int i = tid; i < NPART; i += 256) {
    s += ws[part_off + i * 2 * nch + c];
    q += ws[part_off + i * 2 * nch + nch + c];
  }
#pragma unroll
  for (int d = 1; d < 64; d <<= 1) {
    s += __shfl_xor(s, d);
    q += __shfl_xor(q, d);
  }
  if (lane == 0) { rs[w] = s; rq[w] = q; }
  __syncthreads();
  if (tid == 0) {
    float st = rs[0] + rs[1] + rs[2] + rs[3];
    float qt = rq[0] + rq[1] + rq[2] + rq[3];
    float mean = st * inv_n;
    float var  = qt * inv_n - mean * mean;
    float sv   = gamma[c] * rsqrtf(var + 1e-5f);
    ws[st_off + c]       = sv;
    ws[st_off + nch + c] = beta[c] - mean * sv;
  }
}

// K0: transpose+pack fc_w into ws as u32: fcT[i][jj][j(16)][p(33)] =
// bf16(w[jj][p][i][j]) | bf16(w[jj][p+32][i][j])<<16  (zeros for pads)
__global__ __launch_bounds__(256) void k0_fcT(
    const float* __restrict__ fcw, unsigned int* __restrict__ fcT)
{
  int e = blockIdx.x * 256 + threadIdx.x;
  if (e >= FCT_N) return;
  int i = e / 5280, rem = e - i * 5280;
  int jj = rem / 528, rem2 = rem - jj * 528;
  int j = rem2 / 33, p = rem2 - j * 33;
  unsigned int v = 0;
  if (p < 32 && j < 13) {
    float w0 = fcw[jj * 10816 + p * 169 + i * 13 + j];
    float w1v = fcw[jj * 10816 + (p + 32) * 169 + i * 13 + j];
    v = f2bf(w0) | (f2bf(w1v) << 16);
  }
  fcT[e] = v;
}

// Main MFMA pipeline. STAGE: 3 = conv2 stats, 5 = conv3 stats, 7 = final+FC.
// MFMA 16x16x32 bf16 layouts:
//   A: m=lane&15, k=8*(lane>>4)+j   B: n=lane&15, k=8*(lane>>4)+j
//   D: n=lane&15, m=4*(lane>>4)+reg
// M-tile = 13-pixel output row padded to 16 (garbage rows masked).
template <int STAGE>
__global__ __launch_bounds__(256) void k_pipe(
    const float* __restrict__ x, const float* __restrict__ w1,
    const float* __restrict__ w2, const float* __restrict__ w3,
    const float* __restrict__ fcb, float* __restrict__ ws,
    float* __restrict__ out)
{
  constexpr int NIW = (STAGE == 7) ? 2 : 4;    // images per wave
  constexpr int NWIN = (STAGE == 7) ? 2 : 1;   // live a1 windows per wave
  constexpr int NIB = NIW * 4;                 // images per block

  __shared__ float sx[NIB * 256];
  __shared__ alignas(16) short a1h[4 * NWIN * 512];  // [w][win][buf2][j16][k16]
  __shared__ alignas(16) short a2s[(STAGE >= 5) ? 4 * 640 : 8]; // [w][pix16][40]
  __shared__ unsigned int fcp[(STAGE == 7) ? 5280 : 1];         // [jj][j16][33]
  __shared__ float red[(STAGE == 3) ? 256 : ((STAGE == 5) ? 512 : 1)];

  const int tid = threadIdx.x, w = tid >> 6, lane = tid & 63;
  const int b = lane & 15, q = lane >> 4;

  // stage x (coalesced float4)
  {
    const float4* xs = (const float4*)(x + (size_t)blockIdx.x * (NIB * 256));
    float4* sd = (float4*)sx;
    for (int e = tid; e < NIB * 64; e += 256) sd[e] = xs[e];
  }

  // conv1 weights + bn1 (lane channel = b)
  float w1r[9];
#pragma unroll
  for (int t = 0; t < 9; ++t) w1r[t] = w1[b * 9 + t];
  const float rs1 = ws[ST1 + b], rt1 = ws[ST1 + 16 + b];

  // conv2 weight B-frags. K = ks*32 + dj*16 + kk (di=ks).
  bf16x8 b2h[4];
#pragma unroll
  for (int ks = 0; ks < 2; ++ks)
#pragma unroll
    for (int nt = 0; nt < 2; ++nt) {
      bf16x8 vh;
#pragma unroll
      for (int j = 0; j < 8; ++j) {
        int kk = 8 * (q & 1) + j, dj = q >> 1;
        vh[j] = (short)f2bf(w2[(nt * 16 + b) * 64 + kk * 4 + ks * 2 + dj]);
      }
      b2h[ks * 2 + nt] = vh;
    }

  bf16x8 b3h[4];
  float rs2v[2], rt2v[2], rs3v[4], rt3v[4];
  if constexpr (STAGE >= 5) {
#pragma unroll
    for (int nt = 0; nt < 4; ++nt) {
      bf16x8 vh;
#pragma unroll
      for (int j = 0; j < 8; ++j)
        vh[j] = (short)f2bf(w3[(nt * 16 + b) * 32 + 8 * q + j]);
      b3h[nt] = vh;
    }
#pragma unroll
    for (int nt = 0; nt < 2; ++nt) {
      rs2v[nt] = ws[ST2 + nt * 16 + b];
      rt2v[nt] = ws[ST2 + 32 + nt * 16 + b];
    }
  }
  if constexpr (STAGE == 7) {
#pragma unroll
    for (int nt = 0; nt < 4; ++nt) {
      rs3v[nt] = ws[ST3 + nt * 16 + b];
      rt3v[nt] = ws[ST3 + 64 + nt * 16 + b];
    }
  }

  // per-lane A-frag offsets (shorts). conv2: m=b pixel, col=min(b+dj,15).
  const int colA = b + (q >> 1);
  const int offA = (colA < 15 ? colA : 15) * 16 + 8 * (q & 1);
  const int offA3 = b * 40 + 8 * q;
  short* a2w = a2s + w * 640;

  __syncthreads();

  if constexpr (STAGE != 7) {
    float s2[2] = {0.f, 0.f}, q2[2] = {0.f, 0.f};
    float s3[4] = {0.f, 0.f, 0.f, 0.f}, q3[4] = {0.f, 0.f, 0.f, 0.f};
    short* ph = a1h + w * 512;
#pragma unroll 1
    for (int t = 0; t < NIW; ++t) {
      const float* sxi = sx + (w * NIW + t) * 256;
      conv1_row(sxi, ph, 0, b, q, w1r, rs1, rt1);
      __builtin_amdgcn_wave_barrier();
#pragma unroll 1
      for (int i = 0; i < 13; ++i) {
        conv1_row(sxi, ph, i + 1, b, q, w1r, rs1, rt1);
        __builtin_amdgcn_wave_barrier();
        f32x4 acc2[2] = {{0.f,0.f,0.f,0.f},{0.f,0.f,0.f,0.f}};
#pragma unroll
        for (int ks = 0; ks < 2; ++ks) {
          int par = (i + ks) & 1;
          bf16x8 ah = *(const bf16x8*)(ph + par * 256 + offA);
#pragma unroll
          for (int nt = 0; nt < 2; ++nt)
            acc2[nt] = __builtin_amdgcn_mfma_f32_16x16x32_bf16(ah, b2h[ks*2+nt], acc2[nt], 0, 0, 0);
        }
        if constexpr (STAGE == 3) {
#pragma unroll
          for (int nt = 0; nt < 2; ++nt)
#pragma unroll
            for (int r = 0; r < 4; ++r) {
              bool vd = (4 * q + r) < 13;
              float y = acc2[nt][r];
              s2[nt] += vd ? y : 0.f;
              q2[nt] += vd ? y * y : 0.f;
            }
        } else {
#pragma unroll
          for (int nt = 0; nt < 2; ++nt)
#pragma unroll
            for (int r = 0; r < 4; ++r) {
              float v = rs2v[nt] * acc2[nt][r] + rt2v[nt];
              v = v > 0.f ? v : 0.f;          // kills NaN garbage rows too
              a2w[(4 * q + r) * 40 + nt * 16 + b] = (short)f2bf(v);
            }
          __builtin_amdgcn_wave_barrier();
          bf16x8 a2f = *(const bf16x8*)(a2w + offA3);
#pragma unroll
          for (int nt = 0; nt < 4; ++nt) {
            f32x4 acc3 = {0.f, 0.f, 0.f, 0.f};
            acc3 = __builtin_amdgcn_mfma_f32_16x16x32_bf16(a2f, b3h[nt], acc3, 0, 0, 0);
#pragma unroll
            for (int r = 0; r < 4; ++r) {
              bool vd = (4 * q + r) < 13;
              float y = acc3[r];
              s3[nt] += vd ? y : 0.f;
              q3[nt] += vd ? y * y : 0.f;
            }
          }
        }
        __builtin_amdgcn_wave_barrier();
      }
    }
    if constexpr (STAGE == 3) {
#pragma unroll
      for (int nt = 0; nt < 2; ++nt) {
        s2[nt] += __shfl_xor(s2[nt], 16); s2[nt] += __shfl_xor(s2[nt], 32);
        q2[nt] += __shfl_xor(q2[nt], 16); q2[nt] += __shfl_xor(q2[nt], 32);
      }
      if (lane < 16) {
        red[w * 64 + b]      = s2[0];
        red[w * 64 + 16 + b] = s2[1];
        red[w * 64 + 32 + b] = q2[0];
        red[w * 64 + 48 + b] = q2[1];
      }
      __syncthreads();
      if (tid < 64)
        ws[P2_OFF + blockIdx.x * 64 + tid] =
            red[tid] + red[64 + tid] + red[128 + tid] + red[192 + tid];
    } else {
#pragma unroll
      for (int nt = 0; nt < 4; ++nt) {
        s3[nt] += __shfl_xor(s3[nt], 16); s3[nt] += __shfl_xor(s3[nt], 32);
        q3[nt] += __shfl_xor(q3[nt], 16); q3[nt] += __shfl_xor(q3[nt], 32);
      }
      if (lane < 16) {
#pragma unroll
        for (int nt = 0; nt < 4; ++nt) {
          red[w * 128 + nt * 16 + b]      = s3[nt];
          red[w * 128 + 64 + nt * 16 + b] = q3[nt];
        }
      }
      __syncthreads();
      if (tid < 128)
        ws[P3_OFF + blockIdx.x * 128 + tid] =
            red[tid] + red[128 + tid] + red[256 + tid] + red[384 + tid];
    }
  }

  if constexpr (STAGE == 7) {
    const unsigned int* fcT = (const unsigned int*)ws;
    float pacc[2][10];
#pragma unroll
    for (int t = 0; t < 2; ++t)
#pragma unroll
      for (int jj = 0; jj < 10; ++jj) pacc[t][jj] = 0.f;

#pragma unroll
    for (int t = 0; t < 2; ++t)
      conv1_row(sx + (w * 2 + t) * 256, a1h + (w * 2 + t) * 512,
                0, b, q, w1r, rs1, rt1);

#pragma unroll 1
    for (int i = 0; i < 13; ++i) {
      for (int e = tid; e < 5280; e += 256) fcp[e] = fcT[i * 5280 + e];
      __syncthreads();
#pragma unroll
      for (int t = 0; t < 2; ++t) {
        const float* sxi = sx + (w * 2 + t) * 256;
        short* ph = a1h + (w * 2 + t) * 512;
        conv1_row(sxi, ph, i + 1, b, q, w1r, rs1, rt1);
        __builtin_amdgcn_wave_barrier();
        f32x4 acc2[2] = {{0.f,0.f,0.f,0.f},{0.f,0.f,0.f,0.f}};
#pragma unroll
        for (int ks = 0; ks < 2; ++ks) {
          int par = (i + ks) & 1;
          bf16x8 ah = *(const bf16x8*)(ph + par * 256 + offA);
#pragma unroll
          for (int nt = 0; nt < 2; ++nt)
            acc2[nt] = __builtin_amdgcn_mfma_f32_16x16x32_bf16(ah, b2h[ks*2+nt], acc2[nt], 0, 0, 0);
        }
#pragma unroll
        for (int nt = 0; nt < 2; ++nt)
#pragma unroll
          for (int r = 0; r < 4; ++r) {
            float v = rs2v[nt] * acc2[nt][r] + rt2v[nt];
            v = v > 0.f ? v : 0.f;
            a2w[(4 * q + r) * 40 + nt * 16 + b] = (short)f2bf(v);
          }
        __builtin_amdgcn_wave_barrier();
        bf16x8 a2f = *(const bf16x8*)(a2w + offA3);
        float a3v[4][4];
#pragma unroll
        for (int nt = 0; nt < 4; ++nt) {
          f32x4 acc3 = {0.f, 0.f, 0.f, 0.f};
          acc3 = __builtin_amdgcn_mfma_f32_16x16x32_bf16(a2f, b3h[nt], acc3, 0, 0, 0);
#pragma unroll
          for (int r = 0; r < 4; ++r) {
            float v = rs3v[nt] * acc3[r] + rt3v[nt];
            v = v > 0.f ? v : 0.f;
            a3v[nt][r] = (4 * q + r) < 13 ? v : 0.f;
          }
        }
#pragma unroll
        for (int jj = 0; jj < 10; ++jj) {
          float s = 0.f;
#pragma unroll
          for (int r = 0; r < 4; ++r) {
            int jrow = 4 * q + r;
            unsigned u0 = fcp[(jj * 16 + jrow) * 33 + b];
            unsigned u1 = fcp[(jj * 16 + jrow) * 33 + b + 16];
            s += bf2f(u0 & 0xffffu) * a3v[0][r];
            s += __uint_as_float(u0 & 0xffff0000u) * a3v[2][r];
            s += bf2f(u1 & 0xffffu) * a3v[1][r];
            s += __uint_as_float(u1 & 0xffff0000u) * a3v[3][r];
          }
          pacc[t][jj] += s;
        }
        __builtin_amdgcn_wave_barrier();
      }
      __syncthreads();
    }

#pragma unroll
    for (int t = 0; t < 2; ++t) {
      const int bi = blockIdx.x * 8 + w * 2 + t;
      float res = 0.f;
#pragma unroll
      for (int jj = 0; jj < 10; ++jj) {
        float v = pacc[t][jj];
        v += __shfl_xor(v, 1);  v += __shfl_xor(v, 2);  v += __shfl_xor(v, 4);
        v += __shfl_xor(v, 8);  v += __shfl_xor(v, 16); v += __shfl_xor(v, 32);
        if (lane == jj) res = v;
      }
      if (lane < 10) out[bi * 10 + lane] = res + fcb[lane];
    }
  }
}

extern "C" void kernel_launch(void* const* d_in, const int* in_sizes, int n_in,
                              void* d_out, int out_size, void* d_ws, size_t ws_size,
                              hipStream_t stream) {
  (void)in_sizes; (void)n_in; (void)out_size; (void)ws_size;
  const float* x   = (const float*)d_in[0];
  const float* w1  = (const float*)d_in[1];
  const float* w2  = (const float*)d_in[2];
  const float* w3  = (const float*)d_in[3];
  const float* g1  = (const float*)d_in[4];
  const float* b1  = (const float*)d_in[5];
  const float* g2  = (const float*)d_in[6];
  const float* b2  = (const float*)d_in[7];
  const float* g3  = (const float*)d_in[8];
  const float* b3  = (const float*)d_in[9];
  const float* fcw = (const float*)d_in[10];
  const float* fcb = (const float*)d_in[11];
  float* out = (float*)d_out;
  float* ws  = (float*)d_ws;

  k1_conv1_stats<<<1024, 256, 0, stream>>>(x, w1, ws);
  k_stats2<<<16, 256, 0, stream>>>(g1, b1, ws, 16, P1_OFF, ST1,
                                   1.0f / (16384.0f * 196.0f));
  k_pipe<3><<<1024, 256, 0, stream>>>(x, w1, w2, w3, fcb, ws, out);
  k_stats2<<<32, 256, 0, stream>>>(g2, b2, ws, 32, P2_OFF, ST2,
                                   1.0f / (16384.0f * 169.0f));
  k_pipe<5><<<1024, 256, 0, stream>>>(x, w1, w2, w3, fcb, ws, out);
  k_stats2<<<64, 256, 0, stream>>>(g3, b3, ws, 64, P3_OFF, ST3,
                                   1.0f / (16384.0f * 169.0f));
  k0_fcT<<<(FCT_N + 255) / 256, 256, 0, stream>>>(fcw, (unsigned int*)ws);
  k_pipe<7><<<2048, 256, 0, stream>>>(x, w1, w2, w3, fcb, ws, out);
}

// Round 4
// 426.513 us; speedup vs baseline: 5.8560x; 1.4272x over previous
//
#include <hip/hip_runtime.h>

// ---------------------------------------------------------------------------
// LocallyConnectedNN: x[16384,256] -> conv3x3(1->16)+BN+ReLU -> conv2x2(16->32)
// +BN+ReLU -> conv1x1(32->64)+BN+ReLU -> FC(10816->10).
// Round 4: stage-7 FC moved to MFMA. Block = 16 images; per output row the
// block materializes a3 (channel-last, K=c*16+j zero-padded) in LDS and runs
// [16 img]x[16 jj] MFMA over K=1024, B-frags loaded straight from a
// prepacked global fcB (416KB in ws, L2-resident). This deletes the scalar
// FC dot (160 VALU FMA + 80 4-way-conflicted ds_read per image-row) that
// round-3 counters showed (VALUBusy 56%, 3.6e7 bank conflicts, MfmaUtil 3%).
// ---------------------------------------------------------------------------

#define NPART 1024
#define P1_OFF 0          // [1024][32]  (16 sums | 16 sumsq)
#define P2_OFF 32768      // [1024][64]
#define P3_OFF 98304      // [1024][128]
#define ST_OFF 229376     // s1[16] t1[16] s2[32] t2[32] s3[64] t3[64]
#define ST1 ST_OFF
#define ST2 (ST_OFF + 32)
#define ST3 (ST_OFF + 96)
// fcB: MFMA-fragment-ordered FC weights, u32 [13 i][32 mm][16 jj][4 q][4 u]
// at ws[0 .. 106496) u32 = 416KB. Overlaps P1/P2/P3 regions, which are all
// consumed (k_stats2) before k0_fcB runs. ST region is above it.
#define FCB_N (13 * 8192)

typedef __attribute__((ext_vector_type(8))) short bf16x8;
typedef __attribute__((ext_vector_type(4))) float f32x4;

__device__ __forceinline__ unsigned int f2bf(float f) {
  unsigned int u = __float_as_uint(f);
  return (u + 0x7fffu + ((u >> 16) & 1u)) >> 16;   // RTNE bf16 bits
}
__device__ __forceinline__ float bf2f(unsigned int hb) {
  return __uint_as_float(hb << 16);
}

// conv1 (3x3, 1->16) + bn1 + relu, one output row r, channel-last bf16.
// lane: b = lane&15 (channel), jg = lane>>4 (4-col group).
__device__ __forceinline__ void conv1_row(
    const float* __restrict__ sxi,   // [256] one 16x16 image
    short* ph_buf,                   // [2 bufs][16 j][16 k]
    int r, int b, int jg, const float* w1r, float rs1, float rt1)
{
  short* ph = ph_buf + (r & 1) * 256;
#pragma unroll
  for (int jq = 0; jq < 4; ++jq) {
    int j = jg * 4 + jq;
    if (j < 14) {
      float y = 0.f;
#pragma unroll
      for (int di = 0; di < 3; ++di)
#pragma unroll
        for (int dj = 0; dj < 3; ++dj)
          y += w1r[di * 3 + dj] * sxi[(r + di) * 16 + j + dj];
      y = rs1 * y + rt1;
      y = y > 0.f ? y : 0.f;
      ph[j * 16 + b] = (short)f2bf(y);
    }
  }
}

// K1: per-channel sum/sumsq of raw conv1 output.
__global__ __launch_bounds__(256) void k1_conv1_stats(
    const float* __restrict__ x, const float* __restrict__ w1,
    float* __restrict__ ws)
{
  __shared__ float sx[4][256];
  __shared__ float red[4][32];
  const int tid = threadIdx.x, w = tid >> 6, lane = tid & 63;
  const int k = lane & 15, pg = lane >> 4;
  float w1r[9];
#pragma unroll
  for (int q = 0; q < 9; ++q) w1r[q] = w1[k * 9 + q];
  float fsum = 0.f, fsq = 0.f;
  const int wid = blockIdx.x * 4 + w;
  for (int t = 0; t < 4; ++t) {
    const int b = wid * 4 + t;
    ((float4*)sx[w])[lane] = ((const float4*)x)[b * 64 + lane];
    __builtin_amdgcn_wave_barrier();
    for (int q = 0; q < 49; ++q) {
      int p = pg * 49 + q;
      int i = p / 14, j = p - i * 14;
      const float* r0 = &sx[w][i * 16 + j];
      float y = 0.f;
#pragma unroll
      for (int di = 0; di < 3; ++di)
#pragma unroll
        for (int dj = 0; dj < 3; ++dj)
          y += w1r[di * 3 + dj] * r0[di * 16 + dj];
      fsum += y; fsq += y * y;
    }
    __builtin_amdgcn_wave_barrier();
  }
  fsum += __shfl_xor(fsum, 16); fsum += __shfl_xor(fsum, 32);
  fsq  += __shfl_xor(fsq, 16);  fsq  += __shfl_xor(fsq, 32);
  if (lane < 16) { red[w][lane] = fsum; red[w][16 + lane] = fsq; }
  __syncthreads();
  if (tid < 32)
    ws[P1_OFF + blockIdx.x * 32 + tid] =
        red[0][tid] + red[1][tid] + red[2][tid] + red[3][tid];
}

// Stats finalize, one block per channel.
__global__ __launch_bounds__(256) void k_stats2(
    const float* __restrict__ gamma, const float* __restrict__ beta,
    float* __restrict__ ws, int nch, int part_off, int st_off, float inv_n)
{
  const int c = blockIdx.x, tid = threadIdx.x;
  const int w = tid >> 6, lane = tid & 63;
  __shared__ float rs[4], rq[4];
  float s = 0.f, q = 0.f;
#pragma unroll 4
  for (int i = tid; i < NPART; i += 256) {
    s += ws[part_off + i * 2 * nch + c];
    q += ws[part_off + i * 2 * nch + nch + c];
  }
#pragma unroll
  for (int d = 1; d < 64; d <<= 1) {
    s += __shfl_xor(s, d);
    q += __shfl_xor(q, d);
  }
  if (lane == 0) { rs[w] = s; rq[w] = q; }
  __syncthreads();
  if (tid == 0) {
    float st = rs[0] + rs[1] + rs[2] + rs[3];
    float qt = rq[0] + rq[1] + rq[2] + rq[3];
    float mean = st * inv_n;
    float var  = qt * inv_n - mean * mean;
    float sv   = gamma[c] * rsqrtf(var + 1e-5f);
    ws[st_off + c]       = sv;
    ws[st_off + nch + c] = beta[c] - mean * sv;
  }
}

// K0: pack fc_w into MFMA B-fragment order (bf16 pairs in u32).
// F = ((i*32+mm)*16+jj)*16 + q*4 + u; holds k = mm*32+8q+2u (lo), k+1 (hi);
// k = c*16 + j (j>=13 and jj>=10 are zero pads).
__global__ __launch_bounds__(256) void k0_fcB(
    const float* __restrict__ fcw, unsigned int* __restrict__ fcB)
{
  int F = blockIdx.x * 256 + threadIdx.x;
  if (F >= FCB_N) return;
  int u = F & 3, q = (F >> 2) & 3, jj = (F >> 4) & 15;
  int mm = (F >> 8) & 31, i = F >> 13;
  int k0 = mm * 32 + q * 8 + u * 2;
  unsigned lo = 0, hi = 0;
  if (jj < 10) {
    int c0 = k0 >> 4, j0 = k0 & 15;
    if (j0 < 13) lo = f2bf(fcw[jj * 10816 + c0 * 169 + i * 13 + j0]);
    int c1 = (k0 + 1) >> 4, j1 = (k0 + 1) & 15;
    if (j1 < 13) hi = f2bf(fcw[jj * 10816 + c1 * 169 + i * 13 + j1]);
  }
  fcB[F] = lo | (hi << 16);
}

// Main MFMA pipeline. STAGE: 3 = conv2 stats, 5 = conv3 stats, 7 = final+FC.
// MFMA 16x16x32 bf16 layouts:
//   A: m=lane&15, k=8*(lane>>4)+j   B: n=lane&15, k=8*(lane>>4)+j
//   D: n=lane&15, m=4*(lane>>4)+reg
template <int STAGE>
__global__ __launch_bounds__(256) void k_pipe(
    const float* __restrict__ x, const float* __restrict__ w1,
    const float* __restrict__ w2, const float* __restrict__ w3,
    const float* __restrict__ fcb, float* __restrict__ ws,
    float* __restrict__ out)
{
  constexpr int NIW = 4;                       // images per wave
  constexpr int NWIN = (STAGE == 7) ? 4 : 1;   // live a1 windows per wave
  constexpr int NIB = 16;                      // images per block
  constexpr int A3P = 1040;                    // a3buf img stride (shorts)

  __shared__ float sx[NIB * 256];                      // 16KB
  __shared__ alignas(16) short a1h[4 * NWIN * 512];    // 4 or 16KB
  __shared__ alignas(16) short a2s[4 * 640];           // 5KB  [w][pix16][40]
  __shared__ alignas(16) short a3buf[(STAGE == 7) ? 16 * A3P : 8]; // 33KB
  __shared__ float redf[(STAGE == 7) ? 1024 : ((STAGE == 3) ? 256 : 512)];

  const int tid = threadIdx.x, w = tid >> 6, lane = tid & 63;
  const int b = lane & 15, q = lane >> 4;

  // stage x (coalesced float4)
  {
    const float4* xs = (const float4*)(x + (size_t)blockIdx.x * (NIB * 256));
    float4* sd = (float4*)sx;
    for (int e = tid; e < NIB * 64; e += 256) sd[e] = xs[e];
  }

  // conv1 weights + bn1 (lane channel = b)
  float w1r[9];
#pragma unroll
  for (int t = 0; t < 9; ++t) w1r[t] = w1[b * 9 + t];
  const float rs1 = ws[ST1 + b], rt1 = ws[ST1 + 16 + b];

  // conv2 weight B-frags. K = ks*32 + dj*16 + kk (di=ks).
  bf16x8 b2h[4];
#pragma unroll
  for (int ks = 0; ks < 2; ++ks)
#pragma unroll
    for (int nt = 0; nt < 2; ++nt) {
      bf16x8 vh;
#pragma unroll
      for (int j = 0; j < 8; ++j) {
        int kk = 8 * (q & 1) + j, dj = q >> 1;
        vh[j] = (short)f2bf(w2[(nt * 16 + b) * 64 + kk * 4 + ks * 2 + dj]);
      }
      b2h[ks * 2 + nt] = vh;
    }

  bf16x8 b3h[4];
  float rs2v[2], rt2v[2], rs3v[4], rt3v[4];
  if constexpr (STAGE >= 5) {
#pragma unroll
    for (int nt = 0; nt < 4; ++nt) {
      bf16x8 vh;
#pragma unroll
      for (int j = 0; j < 8; ++j)
        vh[j] = (short)f2bf(w3[(nt * 16 + b) * 32 + 8 * q + j]);
      b3h[nt] = vh;
    }
#pragma unroll
    for (int nt = 0; nt < 2; ++nt) {
      rs2v[nt] = ws[ST2 + nt * 16 + b];
      rt2v[nt] = ws[ST2 + 32 + nt * 16 + b];
    }
  }
  if constexpr (STAGE == 7) {
#pragma unroll
    for (int nt = 0; nt < 4; ++nt) {
      rs3v[nt] = ws[ST3 + nt * 16 + b];
      rt3v[nt] = ws[ST3 + 64 + nt * 16 + b];
    }
  }

  // per-lane A-frag offsets (shorts). conv2: m=b pixel, col=min(b+dj,15).
  const int colA = b + (q >> 1);
  const int offA = (colA < 15 ? colA : 15) * 16 + 8 * (q & 1);
  const int offA3 = b * 40 + 8 * q;
  short* a2w = a2s + w * 640;

  __syncthreads();

  if constexpr (STAGE != 7) {
    float s2[2] = {0.f, 0.f}, q2[2] = {0.f, 0.f};
    float s3[4] = {0.f, 0.f, 0.f, 0.f}, q3[4] = {0.f, 0.f, 0.f, 0.f};
    float* red = redf;
    short* ph = a1h + w * 512;
#pragma unroll 1
    for (int t = 0; t < NIW; ++t) {
      const float* sxi = sx + (w * NIW + t) * 256;
      conv1_row(sxi, ph, 0, b, q, w1r, rs1, rt1);
      __builtin_amdgcn_wave_barrier();
#pragma unroll 1
      for (int i = 0; i < 13; ++i) {
        conv1_row(sxi, ph, i + 1, b, q, w1r, rs1, rt1);
        __builtin_amdgcn_wave_barrier();
        f32x4 acc2[2] = {{0.f,0.f,0.f,0.f},{0.f,0.f,0.f,0.f}};
#pragma unroll
        for (int ks = 0; ks < 2; ++ks) {
          int par = (i + ks) & 1;
          bf16x8 ah = *(const bf16x8*)(ph + par * 256 + offA);
#pragma unroll
          for (int nt = 0; nt < 2; ++nt)
            acc2[nt] = __builtin_amdgcn_mfma_f32_16x16x32_bf16(ah, b2h[ks*2+nt], acc2[nt], 0, 0, 0);
        }
        if constexpr (STAGE == 3) {
#pragma unroll
          for (int nt = 0; nt < 2; ++nt)
#pragma unroll
            for (int r = 0; r < 4; ++r) {
              bool vd = (4 * q + r) < 13;
              float y = acc2[nt][r];
              s2[nt] += vd ? y : 0.f;
              q2[nt] += vd ? y * y : 0.f;
            }
        } else {
#pragma unroll
          for (int nt = 0; nt < 2; ++nt)
#pragma unroll
            for (int r = 0; r < 4; ++r) {
              float v = rs2v[nt] * acc2[nt][r] + rt2v[nt];
              v = v > 0.f ? v : 0.f;          // kills NaN garbage rows too
              a2w[(4 * q + r) * 40 + nt * 16 + b] = (short)f2bf(v);
            }
          __builtin_amdgcn_wave_barrier();
          bf16x8 a2f = *(const bf16x8*)(a2w + offA3);
#pragma unroll
          for (int nt = 0; nt < 4; ++nt) {
            f32x4 acc3 = {0.f, 0.f, 0.f, 0.f};
            acc3 = __builtin_amdgcn_mfma_f32_16x16x32_bf16(a2f, b3h[nt], acc3, 0, 0, 0);
#pragma unroll
            for (int r = 0; r < 4; ++r) {
              bool vd = (4 * q + r) < 13;
              float y = acc3[r];
              s3[nt] += vd ? y : 0.f;
              q3[nt] += vd ? y * y : 0.f;
            }
          }
        }
        __builtin_amdgcn_wave_barrier();
      }
    }
    if constexpr (STAGE == 3) {
#pragma unroll
      for (int nt = 0; nt < 2; ++nt) {
        s2[nt] += __shfl_xor(s2[nt], 16); s2[nt] += __shfl_xor(s2[nt], 32);
        q2[nt] += __shfl_xor(q2[nt], 16); q2[nt] += __shfl_xor(q2[nt], 32);
      }
      if (lane < 16) {
        red[w * 64 + b]      = s2[0];
        red[w * 64 + 16 + b] = s2[1];
        red[w * 64 + 32 + b] = q2[0];
        red[w * 64 + 48 + b] = q2[1];
      }
      __syncthreads();
      if (tid < 64)
        ws[P2_OFF + blockIdx.x * 64 + tid] =
            red[tid] + red[64 + tid] + red[128 + tid] + red[192 + tid];
    } else {
#pragma unroll
      for (int nt = 0; nt < 4; ++nt) {
        s3[nt] += __shfl_xor(s3[nt], 16); s3[nt] += __shfl_xor(s3[nt], 32);
        q3[nt] += __shfl_xor(q3[nt], 16); q3[nt] += __shfl_xor(q3[nt], 32);
      }
      if (lane < 16) {
#pragma unroll
        for (int nt = 0; nt < 4; ++nt) {
          red[w * 128 + nt * 16 + b]      = s3[nt];
          red[w * 128 + 64 + nt * 16 + b] = q3[nt];
        }
      }
      __syncthreads();
      if (tid < 128)
        ws[P3_OFF + blockIdx.x * 128 + tid] =
            red[tid] + red[128 + tid] + red[256 + tid] + red[384 + tid];
    }
  }

  if constexpr (STAGE == 7) {
    const bf16x8* fcB = (const bf16x8*)ws;
    f32x4 accF = {0.f, 0.f, 0.f, 0.f};

#pragma unroll
    for (int t = 0; t < 4; ++t)
      conv1_row(sx + (w * 4 + t) * 256, a1h + (w * 4 + t) * 512,
                0, b, q, w1r, rs1, rt1);
    __builtin_amdgcn_wave_barrier();

#pragma unroll 1
    for (int i = 0; i < 13; ++i) {
#pragma unroll
      for (int t = 0; t < 4; ++t) {
        const int g = w * 4 + t;
        const float* sxi = sx + g * 256;
        short* ph = a1h + g * 512;
        conv1_row(sxi, ph, i + 1, b, q, w1r, rs1, rt1);
        __builtin_amdgcn_wave_barrier();
        f32x4 acc2[2] = {{0.f,0.f,0.f,0.f},{0.f,0.f,0.f,0.f}};
#pragma unroll
        for (int ks = 0; ks < 2; ++ks) {
          int par = (i + ks) & 1;
          bf16x8 ah = *(const bf16x8*)(ph + par * 256 + offA);
#pragma unroll
          for (int nt = 0; nt < 2; ++nt)
            acc2[nt] = __builtin_amdgcn_mfma_f32_16x16x32_bf16(ah, b2h[ks*2+nt], acc2[nt], 0, 0, 0);
        }
#pragma unroll
        for (int nt = 0; nt < 2; ++nt)
#pragma unroll
          for (int r = 0; r < 4; ++r) {
            float v = rs2v[nt] * acc2[nt][r] + rt2v[nt];
            v = v > 0.f ? v : 0.f;
            a2w[(4 * q + r) * 40 + nt * 16 + b] = (short)f2bf(v);
          }
        __builtin_amdgcn_wave_barrier();
        bf16x8 a2f = *(const bf16x8*)(a2w + offA3);
#pragma unroll
        for (int nt = 0; nt < 4; ++nt) {
          f32x4 acc3 = {0.f, 0.f, 0.f, 0.f};
          acc3 = __builtin_amdgcn_mfma_f32_16x16x32_bf16(a2f, b3h[nt], acc3, 0, 0, 0);
          short4 pk;
          {
            float v0 = rs3v[nt] * acc3[0] + rt3v[nt];
            float v1 = rs3v[nt] * acc3[1] + rt3v[nt];
            float v2 = rs3v[nt] * acc3[2] + rt3v[nt];
            float v3 = rs3v[nt] * acc3[3] + rt3v[nt];
            v0 = v0 > 0.f ? v0 : 0.f;  v1 = v1 > 0.f ? v1 : 0.f;
            v2 = v2 > 0.f ? v2 : 0.f;  v3 = v3 > 0.f ? v3 : 0.f;
            // j = 4q+r; zero pads j>=13
            pk.x = (short)((4 * q + 0) < 13 ? f2bf(v0) : 0);
            pk.y = (short)((4 * q + 1) < 13 ? f2bf(v1) : 0);
            pk.z = (short)((4 * q + 2) < 13 ? f2bf(v2) : 0);
            pk.w = (short)((4 * q + 3) < 13 ? f2bf(v3) : 0);
          }
          *(short4*)(a3buf + g * A3P + (nt * 16 + b) * 16 + 4 * q) = pk;
        }
        __builtin_amdgcn_wave_barrier();
      }
      __syncthreads();          // a3buf complete for all 16 images
      // FC: wave w handles K-chunk [w*256, w*256+256) of this row
#pragma unroll
      for (int mm = 0; mm < 8; ++mm) {
        bf16x8 af = *(const bf16x8*)(a3buf + b * A3P + w * 256 + mm * 32 + 8 * q);
        bf16x8 bw = fcB[((i * 32 + w * 8 + mm) * 16 + b) * 4 + q];
        accF = __builtin_amdgcn_mfma_f32_16x16x32_bf16(af, bw, accF, 0, 0, 0);
      }
      __syncthreads();          // before next row overwrites a3buf
    }

#pragma unroll
    for (int r = 0; r < 4; ++r)
      redf[w * 256 + (4 * q + r) * 16 + b] = accF[r];
    __syncthreads();
    if (tid < 160) {
      int img = tid / 10, jj = tid - img * 10;
      float s = redf[img * 16 + jj] + redf[256 + img * 16 + jj] +
                redf[512 + img * 16 + jj] + redf[768 + img * 16 + jj];
      out[(blockIdx.x * 16 + img) * 10 + jj] = s + fcb[jj];
    }
  }
}

extern "C" void kernel_launch(void* const* d_in, const int* in_sizes, int n_in,
                              void* d_out, int out_size, void* d_ws, size_t ws_size,
                              hipStream_t stream) {
  (void)in_sizes; (void)n_in; (void)out_size; (void)ws_size;
  const float* x   = (const float*)d_in[0];
  const float* w1  = (const float*)d_in[1];
  const float* w2  = (const float*)d_in[2];
  const float* w3  = (const float*)d_in[3];
  const float* g1  = (const float*)d_in[4];
  const float* b1  = (const float*)d_in[5];
  const float* g2  = (const float*)d_in[6];
  const float* b2  = (const float*)d_in[7];
  const float* g3  = (const float*)d_in[8];
  const float* b3  = (const float*)d_in[9];
  const float* fcw = (const float*)d_in[10];
  const float* fcb = (const float*)d_in[11];
  float* out = (float*)d_out;
  float* ws  = (float*)d_ws;

  k1_conv1_stats<<<1024, 256, 0, stream>>>(x, w1, ws);
  k_stats2<<<16, 256, 0, stream>>>(g1, b1, ws, 16, P1_OFF, ST1,
                                   1.0f / (16384.0f * 196.0f));
  k_pipe<3><<<1024, 256, 0, stream>>>(x, w1, w2, w3, fcb, ws, out);
  k_stats2<<<32, 256, 0, stream>>>(g2, b2, ws, 32, P2_OFF, ST2,
                                   1.0f / (16384.0f * 169.0f));
  k_pipe<5><<<1024, 256, 0, stream>>>(x, w1, w2, w3, fcb, ws, out);
  k_stats2<<<64, 256, 0, stream>>>(g3, b3, ws, 64, P3_OFF, ST3,
                                   1.0f / (16384.0f * 169.0f));
  k0_fcB<<<FCB_N / 256, 256, 0, stream>>>(fcw, (unsigned int*)ws);
  k_pipe<7><<<1024, 256, 0, stream>>>(x, w1, w2, w3, fcb, ws, out);
}

// Round 5
// 417.466 us; speedup vs baseline: 5.9829x; 1.0217x over previous
//
#include <hip/hip_runtime.h>

// ---------------------------------------------------------------------------
// LocallyConnectedNN: x[16384,256] -> conv3x3(1->16)+BN+ReLU -> conv2x2(16->32)
// +BN+ReLU -> conv1x1(32->64)+BN+ReLU -> FC(10816->10).
// Round 5: (1) hardware v_cvt_pk_bf16_f32 packing (guarded; round-4 showed
// ~35% of VALU was manual RTNE f2bf), (2) LDS paddings a1h stride 24 / a3buf
// stride 1048 to kill the 1.25e7 4-way bank conflicts, (3) k1 stats via the
// 9x9 patch-covariance trick (BN1 stats of a linear conv need only S=E[patch],
// C=E[patch patch^T]; per-channel mean/var = w^T S, w^T C w in the finalize).
// ---------------------------------------------------------------------------

#define NPART 1024
#define P1_OFF 0          // [512][54] x-patch S|C partials
#define P2_OFF 32768      // [1024][64]
#define P3_OFF 98304      // [1024][128]
#define ST_OFF 229376     // s1[16] t1[16] s2[32] t2[32] s3[64] t3[64]
#define ST1 ST_OFF
#define ST2 (ST_OFF + 32)
#define ST3 (ST_OFF + 96)
#define FCB_N (13 * 8192) // fcB u32 at ws[0..106496), overwrites P1-P3 after use
#define A1S 24            // a1h row stride (shorts): 48B keeps b128 align, 2-way banks
#define A1B 384           // one a1 buffer (16 rows x A1S)
#define A3P 1048          // a3buf image stride (shorts): 16B-aligned, 2-way banks

typedef __attribute__((ext_vector_type(8))) short bf16x8;
typedef __attribute__((ext_vector_type(4))) float f32x4;

__device__ __forceinline__ unsigned int f2bf(float f) {
  unsigned int u = __float_as_uint(f);
  return (u + 0x7fffu + ((u >> 16) & 1u)) >> 16;   // RTNE bf16 bits
}
__device__ __forceinline__ float bf2f(unsigned int hb) {
  return __uint_as_float(hb << 16);
}
// packed bf16 convert: 1 VALU on gfx950, fallback to manual RTNE
__device__ __forceinline__ unsigned int pkbf(float a, float b) {
#if __has_builtin(__builtin_amdgcn_cvt_pk_bf16_f32)
  auto r = __builtin_amdgcn_cvt_pk_bf16_f32(a, b);
  return __builtin_bit_cast(unsigned int, r);
#else
  return f2bf(a) | (f2bf(b) << 16);
#endif
}
__device__ __forceinline__ short cvtbf(float a) {
  return (short)(pkbf(a, 0.f) & 0xffffu);
}

// conv1 (3x3, 1->16) + bn1 + relu, one output row r, channel-last bf16.
// lane: b = lane&15 (channel), jg = lane>>4 (4-col group). j>=14 zeroed.
__device__ __forceinline__ void conv1_row(
    const float* __restrict__ sxi,   // [256] one 16x16 image
    short* ph_buf,                   // [2 bufs][16 j][A1S]
    int r, int b, int jg, const float* w1r, float rs1, float rt1)
{
  short* ph = ph_buf + (r & 1) * A1B;
#pragma unroll
  for (int jq = 0; jq < 4; ++jq) {
    int j = jg * 4 + jq;
    short val = 0;
    if (j < 14) {
      float y = 0.f;
#pragma unroll
      for (int di = 0; di < 3; ++di)
#pragma unroll
        for (int dj = 0; dj < 3; ++dj)
          y += w1r[di * 3 + dj] * sxi[(r + di) * 16 + j + dj];
      y = rs1 * y + rt1;
      y = y > 0.f ? y : 0.f;
      val = cvtbf(y);
    }
    ph[j * A1S + b] = val;
  }
}

// K1: x patch statistics. S[9] = sum of patch elements, C[45] = upper-tri sum
// of patch outer products, over all (batch, 14x14 positions). 32 img/block.
__global__ __launch_bounds__(256) void k1_xstats(
    const float* __restrict__ x, float* __restrict__ ws)
{
  __shared__ float sx[32 * 256];
  __shared__ float redl[4 * 56];
  const int tid = threadIdx.x, w = tid >> 6, lane = tid & 63;
  {
    const float4* xs = (const float4*)(x + (size_t)blockIdx.x * (32 * 256));
    float4* sd = (float4*)sx;
    for (int e = tid; e < 32 * 64; e += 256) sd[e] = xs[e];
  }
  __syncthreads();
  float S[9], C[45];
#pragma unroll
  for (int a = 0; a < 9; ++a) S[a] = 0.f;
#pragma unroll
  for (int a = 0; a < 45; ++a) C[a] = 0.f;
  for (int p = tid; p < 32 * 196; p += 256) {
    int img = p / 196, rem = p - img * 196;
    int i = rem / 14, j = rem - i * 14;
    const float* px = sx + img * 256 + i * 16 + j;
    float v[9];
    v[0] = px[0];  v[1] = px[1];  v[2] = px[2];
    v[3] = px[16]; v[4] = px[17]; v[5] = px[18];
    v[6] = px[32]; v[7] = px[33]; v[8] = px[34];
    int idx = 0;
#pragma unroll
    for (int a = 0; a < 9; ++a) {
      S[a] += v[a];
#pragma unroll
      for (int c = a; c < 9; ++c) { C[idx] += v[a] * v[c]; ++idx; }
    }
  }
#pragma unroll
  for (int a = 0; a < 9; ++a) {
    float v = S[a];
#pragma unroll
    for (int d = 1; d < 64; d <<= 1) v += __shfl_xor(v, d);
    if (lane == 0) redl[w * 56 + a] = v;
  }
#pragma unroll
  for (int a = 0; a < 45; ++a) {
    float v = C[a];
#pragma unroll
    for (int d = 1; d < 64; d <<= 1) v += __shfl_xor(v, d);
    if (lane == 0) redl[w * 56 + 9 + a] = v;
  }
  __syncthreads();
  if (tid < 54)
    ws[P1_OFF + blockIdx.x * 54 + tid] =
        redl[tid] + redl[56 + tid] + redl[112 + tid] + redl[168 + tid];
}

// BN1 finalize: fold S/C with w1 into per-channel scale/shift.
__global__ __launch_bounds__(256) void k_stats1(
    const float* __restrict__ w1, const float* __restrict__ gamma,
    const float* __restrict__ beta, float* __restrict__ ws)
{
  __shared__ float part[216];
  __shared__ float acc[54];
  const int tid = threadIdx.x;
  if (tid < 216) {
    int a = tid >> 2, seg = tid & 3;
    float s = 0.f;
    for (int i = seg * 128; i < seg * 128 + 128; ++i)
      s += ws[P1_OFF + i * 54 + a];
    part[tid] = s;
  }
  __syncthreads();
  if (tid < 54)
    acc[tid] = part[tid * 4] + part[tid * 4 + 1] +
               part[tid * 4 + 2] + part[tid * 4 + 3];
  __syncthreads();
  if (tid < 16) {
    float wr[9];
#pragma unroll
    for (int p = 0; p < 9; ++p) wr[p] = w1[tid * 9 + p];
    float msum = 0.f;
#pragma unroll
    for (int p = 0; p < 9; ++p) msum += wr[p] * acc[p];
    float e2 = 0.f;
    int idx = 9;
#pragma unroll
    for (int a = 0; a < 9; ++a)
#pragma unroll
      for (int c = a; c < 9; ++c) {
        float t = wr[a] * wr[c] * acc[idx];
        e2 += (c == a) ? t : 2.f * t;
        ++idx;
      }
    const float inv_n = 1.0f / (16384.0f * 196.0f);
    float mean = msum * inv_n;
    float var  = e2 * inv_n - mean * mean;
    float sv   = gamma[tid] * rsqrtf(var + 1e-5f);
    ws[ST1 + tid]      = sv;
    ws[ST1 + 16 + tid] = beta[tid] - mean * sv;
  }
}

// Stats finalize for BN2/BN3, one block per channel.
__global__ __launch_bounds__(256) void k_stats2(
    const float* __restrict__ gamma, const float* __restrict__ beta,
    float* __restrict__ ws, int nch, int part_off, int st_off, float inv_n)
{
  const int c = blockIdx.x, tid = threadIdx.x;
  const int w = tid >> 6, lane = tid & 63;
  __shared__ float rs[4], rq[4];
  float s = 0.f, q = 0.f;
#pragma unroll 4
  for (int i = tid; i < NPART; i += 256) {
    s += ws[part_off + i * 2 * nch + c];
    q += ws[part_off + i * 2 * nch + nch + c];
  }
#pragma unroll
  for (int d = 1; d < 64; d <<= 1) {
    s += __shfl_xor(s, d);
    q += __shfl_xor(q, d);
  }
  if (lane == 0) { rs[w] = s; rq[w] = q; }
  __syncthreads();
  if (tid == 0) {
    float st = rs[0] + rs[1] + rs[2] + rs[3];
    float qt = rq[0] + rq[1] + rq[2] + rq[3];
    float mean = st * inv_n;
    float var  = qt * inv_n - mean * mean;
    float sv   = gamma[c] * rsqrtf(var + 1e-5f);
    ws[st_off + c]       = sv;
    ws[st_off + nch + c] = beta[c] - mean * sv;
  }
}

// K0: pack fc_w into MFMA B-fragment order (bf16 pairs in u32).
__global__ __launch_bounds__(256) void k0_fcB(
    const float* __restrict__ fcw, unsigned int* __restrict__ fcB)
{
  int F = blockIdx.x * 256 + threadIdx.x;
  if (F >= FCB_N) return;
  int u = F & 3, q = (F >> 2) & 3, jj = (F >> 4) & 15;
  int mm = (F >> 8) & 31, i = F >> 13;
  int k0 = mm * 32 + q * 8 + u * 2;
  unsigned lo = 0, hi = 0;
  if (jj < 10) {
    int c0 = k0 >> 4, j0 = k0 & 15;
    if (j0 < 13) lo = f2bf(fcw[jj * 10816 + c0 * 169 + i * 13 + j0]);
    int c1 = (k0 + 1) >> 4, j1 = (k0 + 1) & 15;
    if (j1 < 13) hi = f2bf(fcw[jj * 10816 + c1 * 169 + i * 13 + j1]);
  }
  fcB[F] = lo | (hi << 16);
}

// Main MFMA pipeline. STAGE: 3 = conv2 stats, 5 = conv3 stats, 7 = final+FC.
// MFMA 16x16x32 bf16 layouts:
//   A: m=lane&15, k=8*(lane>>4)+j   B: n=lane&15, k=8*(lane>>4)+j
//   D: n=lane&15, m=4*(lane>>4)+reg
template <int STAGE>
__global__ __launch_bounds__(256) void k_pipe(
    const float* __restrict__ x, const float* __restrict__ w1,
    const float* __restrict__ w2, const float* __restrict__ w3,
    const float* __restrict__ fcb, float* __restrict__ ws,
    float* __restrict__ out)
{
  constexpr int NWIN = (STAGE == 7) ? 16 : 4;  // live a1 windows (block-wide)
  constexpr int NIB = 16;                      // images per block

  __shared__ float sx[NIB * 256];                       // 16KB
  __shared__ alignas(16) short a1h[NWIN * 2 * A1B];     // 6 or 24.6KB
  __shared__ alignas(16) short a2s[4 * 640];            // 5KB [w][pix16][40]
  __shared__ alignas(16) short a3buf[(STAGE == 7) ? 16 * A3P : 8]; // 33.5KB
  __shared__ float redf[(STAGE == 3) ? 256 : ((STAGE == 5) ? 512 : 1)];

  const int tid = threadIdx.x, w = tid >> 6, lane = tid & 63;
  const int b = lane & 15, q = lane >> 4;

  // stage x (coalesced float4)
  {
    const float4* xs = (const float4*)(x + (size_t)blockIdx.x * (NIB * 256));
    float4* sd = (float4*)sx;
    for (int e = tid; e < NIB * 64; e += 256) sd[e] = xs[e];
  }

  // conv1 weights + bn1 (lane channel = b)
  float w1r[9];
#pragma unroll
  for (int t = 0; t < 9; ++t) w1r[t] = w1[b * 9 + t];
  const float rs1 = ws[ST1 + b], rt1 = ws[ST1 + 16 + b];

  // conv2 weight B-frags. K = ks*32 + dj*16 + kk (di=ks).
  bf16x8 b2h[4];
#pragma unroll
  for (int ks = 0; ks < 2; ++ks)
#pragma unroll
    for (int nt = 0; nt < 2; ++nt) {
      bf16x8 vh;
#pragma unroll
      for (int j = 0; j < 8; ++j) {
        int kk = 8 * (q & 1) + j, dj = q >> 1;
        vh[j] = cvtbf(w2[(nt * 16 + b) * 64 + kk * 4 + ks * 2 + dj]);
      }
      b2h[ks * 2 + nt] = vh;
    }

  bf16x8 b3h[4];
  float rs2v[2], rt2v[2], rs3v[4], rt3v[4];
  if constexpr (STAGE >= 5) {
#pragma unroll
    for (int nt = 0; nt < 4; ++nt) {
      bf16x8 vh;
#pragma unroll
      for (int j = 0; j < 8; ++j)
        vh[j] = cvtbf(w3[(nt * 16 + b) * 32 + 8 * q + j]);
      b3h[nt] = vh;
    }
#pragma unroll
    for (int nt = 0; nt < 2; ++nt) {
      rs2v[nt] = ws[ST2 + nt * 16 + b];
      rt2v[nt] = ws[ST2 + 32 + nt * 16 + b];
    }
  }
  if constexpr (STAGE == 7) {
#pragma unroll
    for (int nt = 0; nt < 4; ++nt) {
      rs3v[nt] = ws[ST3 + nt * 16 + b];
      rt3v[nt] = ws[ST3 + 64 + nt * 16 + b];
    }
  }

  // pixel-validity weights (m = 4q+r valid if < 13)
  float wm[4];
#pragma unroll
  for (int r = 0; r < 4; ++r) wm[r] = (4 * q + r) < 13 ? 1.f : 0.f;
  const float m1 = (q < 3) ? 1.f : 0.f;

  // per-lane A-frag offsets (shorts). conv2: m=b pixel, col=min(b+dj,15).
  const int colA = b + (q >> 1);
  const int offA = (colA < 15 ? colA : 15) * A1S + 8 * (q & 1);
  const int offA3 = b * 40 + 8 * q;
  short* a2w = a2s + w * 640;

  __syncthreads();

  if constexpr (STAGE != 7) {
    float s2[2] = {0.f, 0.f}, q2[2] = {0.f, 0.f};
    float s3[4] = {0.f, 0.f, 0.f, 0.f}, q3[4] = {0.f, 0.f, 0.f, 0.f};
    float* red = redf;
    short* ph = a1h + w * (2 * A1B);
#pragma unroll 1
    for (int t = 0; t < 4; ++t) {
      const float* sxi = sx + (w * 4 + t) * 256;
      conv1_row(sxi, ph, 0, b, q, w1r, rs1, rt1);
      __builtin_amdgcn_wave_barrier();
#pragma unroll 1
      for (int i = 0; i < 13; ++i) {
        conv1_row(sxi, ph, i + 1, b, q, w1r, rs1, rt1);
        __builtin_amdgcn_wave_barrier();
        f32x4 acc2[2] = {{0.f,0.f,0.f,0.f},{0.f,0.f,0.f,0.f}};
#pragma unroll
        for (int ks = 0; ks < 2; ++ks) {
          int par = (i + ks) & 1;
          bf16x8 ah = *(const bf16x8*)(ph + par * A1B + offA);
#pragma unroll
          for (int nt = 0; nt < 2; ++nt)
            acc2[nt] = __builtin_amdgcn_mfma_f32_16x16x32_bf16(ah, b2h[ks*2+nt], acc2[nt], 0, 0, 0);
        }
        if constexpr (STAGE == 3) {
#pragma unroll
          for (int nt = 0; nt < 2; ++nt)
#pragma unroll
            for (int r = 0; r < 4; ++r) {
              float ym = acc2[nt][r] * wm[r];
              s2[nt] += ym;
              q2[nt] = fmaf(ym, acc2[nt][r], q2[nt]);
            }
        } else {
#pragma unroll
          for (int nt = 0; nt < 2; ++nt)
#pragma unroll
            for (int r = 0; r < 4; ++r) {
              float v = rs2v[nt] * acc2[nt][r] + rt2v[nt];
              v = v > 0.f ? v : 0.f;
              a2w[(4 * q + r) * 40 + nt * 16 + b] = cvtbf(v);
            }
          __builtin_amdgcn_wave_barrier();
          bf16x8 a2f = *(const bf16x8*)(a2w + offA3);
#pragma unroll
          for (int nt = 0; nt < 4; ++nt) {
            f32x4 acc3 = {0.f, 0.f, 0.f, 0.f};
            acc3 = __builtin_amdgcn_mfma_f32_16x16x32_bf16(a2f, b3h[nt], acc3, 0, 0, 0);
#pragma unroll
            for (int r = 0; r < 4; ++r) {
              float ym = acc3[r] * wm[r];
              s3[nt] += ym;
              q3[nt] = fmaf(ym, acc3[r], q3[nt]);
            }
          }
        }
        __builtin_amdgcn_wave_barrier();
      }
    }
    if constexpr (STAGE == 3) {
#pragma unroll
      for (int nt = 0; nt < 2; ++nt) {
        s2[nt] += __shfl_xor(s2[nt], 16); s2[nt] += __shfl_xor(s2[nt], 32);
        q2[nt] += __shfl_xor(q2[nt], 16); q2[nt] += __shfl_xor(q2[nt], 32);
      }
      if (lane < 16) {
        red[w * 64 + b]      = s2[0];
        red[w * 64 + 16 + b] = s2[1];
        red[w * 64 + 32 + b] = q2[0];
        red[w * 64 + 48 + b] = q2[1];
      }
      __syncthreads();
      if (tid < 64)
        ws[P2_OFF + blockIdx.x * 64 + tid] =
            red[tid] + red[64 + tid] + red[128 + tid] + red[192 + tid];
    } else {
#pragma unroll
      for (int nt = 0; nt < 4; ++nt) {
        s3[nt] += __shfl_xor(s3[nt], 16); s3[nt] += __shfl_xor(s3[nt], 32);
        q3[nt] += __shfl_xor(q3[nt], 16); q3[nt] += __shfl_xor(q3[nt], 32);
      }
      if (lane < 16) {
#pragma unroll
        for (int nt = 0; nt < 4; ++nt) {
          red[w * 128 + nt * 16 + b]      = s3[nt];
          red[w * 128 + 64 + nt * 16 + b] = q3[nt];
        }
      }
      __syncthreads();
      if (tid < 128)
        ws[P3_OFF + blockIdx.x * 128 + tid] =
            red[tid] + red[128 + tid] + red[256 + tid] + red[384 + tid];
    }
  }

  if constexpr (STAGE == 7) {
    const bf16x8* fcB = (const bf16x8*)ws;
    f32x4 accF = {0.f, 0.f, 0.f, 0.f};

#pragma unroll
    for (int t = 0; t < 4; ++t)
      conv1_row(sx + (w * 4 + t) * 256, a1h + (w * 4 + t) * (2 * A1B),
                0, b, q, w1r, rs1, rt1);
    __builtin_amdgcn_wave_barrier();

#pragma unroll 1
    for (int i = 0; i < 13; ++i) {
#pragma unroll
      for (int t = 0; t < 4; ++t) {
        const int g = w * 4 + t;
        const float* sxi = sx + g * 256;
        short* ph = a1h + g * (2 * A1B);
        conv1_row(sxi, ph, i + 1, b, q, w1r, rs1, rt1);
        __builtin_amdgcn_wave_barrier();
        f32x4 acc2[2] = {{0.f,0.f,0.f,0.f},{0.f,0.f,0.f,0.f}};
#pragma unroll
        for (int ks = 0; ks < 2; ++ks) {
          int par = (i + ks) & 1;
          bf16x8 ah = *(const bf16x8*)(ph + par * A1B + offA);
#pragma unroll
          for (int nt = 0; nt < 2; ++nt)
            acc2[nt] = __builtin_amdgcn_mfma_f32_16x16x32_bf16(ah, b2h[ks*2+nt], acc2[nt], 0, 0, 0);
        }
#pragma unroll
        for (int nt = 0; nt < 2; ++nt)
#pragma unroll
          for (int r = 0; r < 4; ++r) {
            float v = rs2v[nt] * acc2[nt][r] + rt2v[nt];
            v = v > 0.f ? v : 0.f;
            a2w[(4 * q + r) * 40 + nt * 16 + b] = cvtbf(v);
          }
        __builtin_amdgcn_wave_barrier();
        bf16x8 a2f = *(const bf16x8*)(a2w + offA3);
#pragma unroll
        for (int nt = 0; nt < 4; ++nt) {
          f32x4 acc3 = {0.f, 0.f, 0.f, 0.f};
          acc3 = __builtin_amdgcn_mfma_f32_16x16x32_bf16(a2f, b3h[nt], acc3, 0, 0, 0);
          float v0 = rs3v[nt] * acc3[0] + rt3v[nt];
          float v1 = rs3v[nt] * acc3[1] + rt3v[nt];
          float v2 = rs3v[nt] * acc3[2] + rt3v[nt];
          float v3 = rs3v[nt] * acc3[3] + rt3v[nt];
          v0 = v0 > 0.f ? v0 : 0.f;  v1 = (v1 > 0.f ? v1 : 0.f) * m1;
          v2 = (v2 > 0.f ? v2 : 0.f) * m1;  v3 = (v3 > 0.f ? v3 : 0.f) * m1;
          uint2 pk2;
          pk2.x = pkbf(v0, v1);
          pk2.y = pkbf(v2, v3);
          *(uint2*)(a3buf + g * A3P + (nt * 16 + b) * 16 + 4 * q) = pk2;
        }
        __builtin_amdgcn_wave_barrier();
      }
      __syncthreads();          // a3buf complete for all 16 images
      // FC: wave w handles K-chunk [w*256, w*256+256) of this row
#pragma unroll
      for (int mm = 0; mm < 8; ++mm) {
        bf16x8 af = *(const bf16x8*)(a3buf + b * A3P + w * 256 + mm * 32 + 8 * q);
        bf16x8 bw = fcB[((i * 32 + w * 8 + mm) * 16 + b) * 4 + q];
        accF = __builtin_amdgcn_mfma_f32_16x16x32_bf16(af, bw, accF, 0, 0, 0);
      }
      __syncthreads();          // before next row overwrites a3buf
    }

    float* redf7 = (float*)a3buf;   // a3buf is free after the loop
#pragma unroll
    for (int r = 0; r < 4; ++r)
      redf7[w * 256 + (4 * q + r) * 16 + b] = accF[r];
    __syncthreads();
    if (tid < 160) {
      int img = tid / 10, jj = tid - img * 10;
      float s = redf7[img * 16 + jj] + redf7[256 + img * 16 + jj] +
                redf7[512 + img * 16 + jj] + redf7[768 + img * 16 + jj];
      out[(blockIdx.x * 16 + img) * 10 + jj] = s + fcb[jj];
    }
  }
}

extern "C" void kernel_launch(void* const* d_in, const int* in_sizes, int n_in,
                              void* d_out, int out_size, void* d_ws, size_t ws_size,
                              hipStream_t stream) {
  (void)in_sizes; (void)n_in; (void)out_size; (void)ws_size;
  const float* x   = (const float*)d_in[0];
  const float* w1  = (const float*)d_in[1];
  const float* w2  = (const float*)d_in[2];
  const float* w3  = (const float*)d_in[3];
  const float* g1  = (const float*)d_in[4];
  const float* b1  = (const float*)d_in[5];
  const float* g2  = (const float*)d_in[6];
  const float* b2  = (const float*)d_in[7];
  const float* g3  = (const float*)d_in[8];
  const float* b3  = (const float*)d_in[9];
  const float* fcw = (const float*)d_in[10];
  const float* fcb = (const float*)d_in[11];
  float* out = (float*)d_out;
  float* ws  = (float*)d_ws;

  k1_xstats<<<512, 256, 0, stream>>>(x, ws);
  k_stats1<<<1, 256, 0, stream>>>(w1, g1, b1, ws);
  k_pipe<3><<<1024, 256, 0, stream>>>(x, w1, w2, w3, fcb, ws, out);
  k_stats2<<<32, 256, 0, stream>>>(g2, b2, ws, 32, P2_OFF, ST2,
                                   1.0f / (16384.0f * 169.0f));
  k_pipe<5><<<1024, 256, 0, stream>>>(x, w1, w2, w3, fcb, ws, out);
  k_stats2<<<64, 256, 0, stream>>>(g3, b3, ws, 64, P3_OFF, ST3,
                                   1.0f / (16384.0f * 169.0f));
  k0_fcB<<<FCB_N / 256, 256, 0, stream>>>(fcw, (unsigned int*)ws);
  k_pipe<7><<<1024, 256, 0, stream>>>(x, w1, w2, w3, fcb, ws, out);
}

// Round 6
// 351.845 us; speedup vs baseline: 7.0987x; 1.1865x over previous
//
#include <hip/hip_runtime.h>

// ---------------------------------------------------------------------------
// LocallyConnectedNN: x[16384,256] -> conv3x3(1->16)+BN+ReLU -> conv2x2(16->32)
// +BN+ReLU -> conv1x1(32->64)+BN+ReLU -> FC(10816->10).
// Round 6: activation caching in ws, tiered on ws_size (graph-safe: ws_size
// is constant). T3: k3 writes a1(117MB), k5 reads a1/writes a2(218MB), k7
// reads a2 (conv3+FC only, LDS 78->34KB => 4 blocks/CU). T2: a2 only.
// T1: a1 only. T0: full recompute (round-5 behavior). Round-5 counters:
// VALUBusy 58% / MfmaUtil 8.7% = recompute VALU chain dominates; conflicts
// (1.4e7) are only ~3% -- dropped that thread. Also: pkbf via v_perm_b32
// (3 inst guaranteed), pixel masks folded into pre-zeroed bn3 scale/shift,
// conv1 j<14 branch removed via zero-padded sx overrun.
// ---------------------------------------------------------------------------

#define NPART 1024
#define P1_OFF 0          // [512][54] x-patch S|C partials
#define P2_OFF 32768      // [1024][64]
#define P3_OFF 98304      // [1024][128]
#define ST_OFF 229376     // s1[16] t1[16] s2[32] t2[32] s3[64] t3[64]
#define ST1 ST_OFF
#define ST2 (ST_OFF + 32)
#define ST3 (ST_OFF + 96)
#define FCB_N (13 * 8192) // fcB u32 at ws[0..106496), overwrites P1-P3 after use
#define A1S 24            // a1h LDS row stride (shorts)
#define A1B 384           // one a1 LDS buffer (16 rows x A1S)
#define A3P 1048          // a3buf image stride (shorts)
// Global activation caches (byte offsets into ws; region below 1MiB holds
// partials/ST/fcB exactly as before).
#define AC_BASE (1ull << 20)
#define A1_BYTES 117440512ull   // [img][row14][col16][ch16] bf16
#define A2_BYTES 218103808ull   // [img][row13][pix16][ch32] bf16

typedef __attribute__((ext_vector_type(8))) short bf16x8;
typedef __attribute__((ext_vector_type(4))) float f32x4;

__device__ __forceinline__ unsigned int f2bf(float f) {
  unsigned int u = __float_as_uint(f);
  return (u + 0x7fffu + ((u >> 16) & 1u)) >> 16;   // RTNE bf16 bits
}
__device__ __forceinline__ float bf2f(unsigned int hb) {
  return __uint_as_float(hb << 16);
}
// pack two floats to bf16x2 (round-half-up): 2 adds + 1 v_perm_b32
__device__ __forceinline__ unsigned int pkbf(float a, float b) {
  unsigned ua = __float_as_uint(a) + 0x8000u;
  unsigned ub = __float_as_uint(b) + 0x8000u;
  return __builtin_amdgcn_perm(ub, ua, 0x07060302u);
}
__device__ __forceinline__ short cvtbf(float a) {
  return (short)((__float_as_uint(a) + 0x8000u) >> 16);
}

// conv1 (3x3, 1->16) + bn1 + relu, one output row r, channel-last bf16.
// lane: b = lane&15 (channel), jg = lane>>4 (4-col group). j=14,15 are
// garbage-but-finite (sx overrun is in-bounds + zero pad); consumers mask.
template <bool WG>
__device__ __forceinline__ void conv1_row(
    const float* __restrict__ sxi,   // [256] one 16x16 image (+pad after last)
    short* ph_buf,                   // [2 bufs][16 j][A1S]
    short* __restrict__ a1img,       // global a1 cache for this image (if WG)
    int r, int b, int jg, const float* w1r, float rs1, float rt1)
{
  short* ph = ph_buf + (r & 1) * A1B;
#pragma unroll
  for (int jq = 0; jq < 4; ++jq) {
    int j = jg * 4 + jq;
    float y = 0.f;
#pragma unroll
    for (int di = 0; di < 3; ++di)
#pragma unroll
      for (int dj = 0; dj < 3; ++dj)
        y += w1r[di * 3 + dj] * sxi[(r + di) * 16 + j + dj];
    y = rs1 * y + rt1;
    y = y > 0.f ? y : 0.f;
    short val = cvtbf(y);
    ph[j * A1S + b] = val;
    if constexpr (WG) a1img[r * 256 + j * 16 + b] = val;
  }
}

// K1: x patch statistics (S[9], upper-tri C[45]) -- BN1 via covariance trick.
__global__ __launch_bounds__(256) void k1_xstats(
    const float* __restrict__ x, float* __restrict__ ws)
{
  __shared__ float sx[32 * 256];
  __shared__ float redl[4 * 56];
  const int tid = threadIdx.x, w = tid >> 6, lane = tid & 63;
  {
    const float4* xs = (const float4*)(x + (size_t)blockIdx.x * (32 * 256));
    float4* sd = (float4*)sx;
    for (int e = tid; e < 32 * 64; e += 256) sd[e] = xs[e];
  }
  __syncthreads();
  float S[9], C[45];
#pragma unroll
  for (int a = 0; a < 9; ++a) S[a] = 0.f;
#pragma unroll
  for (int a = 0; a < 45; ++a) C[a] = 0.f;
  for (int p = tid; p < 32 * 196; p += 256) {
    int img = p / 196, rem = p - img * 196;
    int i = rem / 14, j = rem - i * 14;
    const float* px = sx + img * 256 + i * 16 + j;
    float v[9];
    v[0] = px[0];  v[1] = px[1];  v[2] = px[2];
    v[3] = px[16]; v[4] = px[17]; v[5] = px[18];
    v[6] = px[32]; v[7] = px[33]; v[8] = px[34];
    int idx = 0;
#pragma unroll
    for (int a = 0; a < 9; ++a) {
      S[a] += v[a];
#pragma unroll
      for (int c = a; c < 9; ++c) { C[idx] += v[a] * v[c]; ++idx; }
    }
  }
#pragma unroll
  for (int a = 0; a < 9; ++a) {
    float v = S[a];
#pragma unroll
    for (int d = 1; d < 64; d <<= 1) v += __shfl_xor(v, d);
    if (lane == 0) redl[w * 56 + a] = v;
  }
#pragma unroll
  for (int a = 0; a < 45; ++a) {
    float v = C[a];
#pragma unroll
    for (int d = 1; d < 64; d <<= 1) v += __shfl_xor(v, d);
    if (lane == 0) redl[w * 56 + 9 + a] = v;
  }
  __syncthreads();
  if (tid < 54)
    ws[P1_OFF + blockIdx.x * 54 + tid] =
        redl[tid] + redl[56 + tid] + redl[112 + tid] + redl[168 + tid];
}

// BN1 finalize: fold S/C with w1 into per-channel scale/shift.
__global__ __launch_bounds__(256) void k_stats1(
    const float* __restrict__ w1, const float* __restrict__ gamma,
    const float* __restrict__ beta, float* __restrict__ ws)
{
  __shared__ float part[216];
  __shared__ float acc[54];
  const int tid = threadIdx.x;
  if (tid < 216) {
    int a = tid >> 2, seg = tid & 3;
    float s = 0.f;
    for (int i = seg * 128; i < seg * 128 + 128; ++i)
      s += ws[P1_OFF + i * 54 + a];
    part[tid] = s;
  }
  __syncthreads();
  if (tid < 54)
    acc[tid] = part[tid * 4] + part[tid * 4 + 1] +
               part[tid * 4 + 2] + part[tid * 4 + 3];
  __syncthreads();
  if (tid < 16) {
    float wr[9];
#pragma unroll
    for (int p = 0; p < 9; ++p) wr[p] = w1[tid * 9 + p];
    float msum = 0.f;
#pragma unroll
    for (int p = 0; p < 9; ++p) msum += wr[p] * acc[p];
    float e2 = 0.f;
    int idx = 9;
#pragma unroll
    for (int a = 0; a < 9; ++a)
#pragma unroll
      for (int c = a; c < 9; ++c) {
        float t = wr[a] * wr[c] * acc[idx];
        e2 += (c == a) ? t : 2.f * t;
        ++idx;
      }
    const float inv_n = 1.0f / (16384.0f * 196.0f);
    float mean = msum * inv_n;
    float var  = e2 * inv_n - mean * mean;
    float sv   = gamma[tid] * rsqrtf(var + 1e-5f);
    ws[ST1 + tid]      = sv;
    ws[ST1 + 16 + tid] = beta[tid] - mean * sv;
  }
}

// Stats finalize for BN2/BN3, one block per channel.
__global__ __launch_bounds__(256) void k_stats2(
    const float* __restrict__ gamma, const float* __restrict__ beta,
    float* __restrict__ ws, int nch, int part_off, int st_off, float inv_n)
{
  const int c = blockIdx.x, tid = threadIdx.x;
  const int w = tid >> 6, lane = tid & 63;
  __shared__ float rs[4], rq[4];
  float s = 0.f, q = 0.f;
#pragma unroll 4
  for (int i = tid; i < NPART; i += 256) {
    s += ws[part_off + i * 2 * nch + c];
    q += ws[part_off + i * 2 * nch + nch + c];
  }
#pragma unroll
  for (int d = 1; d < 64; d <<= 1) {
    s += __shfl_xor(s, d);
    q += __shfl_xor(q, d);
  }
  if (lane == 0) { rs[w] = s; rq[w] = q; }
  __syncthreads();
  if (tid == 0) {
    float st = rs[0] + rs[1] + rs[2] + rs[3];
    float qt = rq[0] + rq[1] + rq[2] + rq[3];
    float mean = st * inv_n;
    float var  = qt * inv_n - mean * mean;
    float sv   = gamma[c] * rsqrtf(var + 1e-5f);
    ws[st_off + c]       = sv;
    ws[st_off + nch + c] = beta[c] - mean * sv;
  }
}

// K0: pack fc_w into MFMA B-fragment order (bf16 pairs in u32).
__global__ __launch_bounds__(256) void k0_fcB(
    const float* __restrict__ fcw, unsigned int* __restrict__ fcB)
{
  int F = blockIdx.x * 256 + threadIdx.x;
  if (F >= FCB_N) return;
  int u = F & 3, q = (F >> 2) & 3, jj = (F >> 4) & 15;
  int mm = (F >> 8) & 31, i = F >> 13;
  int k0 = mm * 32 + q * 8 + u * 2;
  unsigned lo = 0, hi = 0;
  if (jj < 10) {
    int c0 = k0 >> 4, j0 = k0 & 15;
    if (j0 < 13) lo = f2bf(fcw[jj * 10816 + c0 * 169 + i * 13 + j0]);
    int c1 = (k0 + 1) >> 4, j1 = (k0 + 1) & 15;
    if (j1 < 13) hi = f2bf(fcw[jj * 10816 + c1 * 169 + i * 13 + j1]);
  }
  fcB[F] = lo | (hi << 16);
}

// Main MFMA pipeline.
// STAGE 3: conv2 stats.   F1=1 -> also write a1 cache.
// STAGE 5: conv3 stats.   F1=1 -> read a1 (skip conv1). F2=1 -> write a2.
// STAGE 7: final+FC.      F1=0 full recompute, 1 read a1, 2 read a2.
// MFMA 16x16x32 bf16: A m=lane&15,k=8*(lane>>4)+j; D n=lane&15,m=4*(lane>>4)+r.
template <int STAGE, int F1, int F2>
__global__ __launch_bounds__(256) void k_pipe(
    const float* __restrict__ x, const float* __restrict__ w1,
    const float* __restrict__ w2, const float* __restrict__ w3,
    const float* __restrict__ fcb, float* __restrict__ ws,
    short* __restrict__ a1g, short* __restrict__ a2g,
    float* __restrict__ out)
{
  constexpr bool WA1 = (STAGE == 3 && F1 == 1);
  constexpr bool RA1 = (STAGE == 5 && F1 == 1) || (STAGE == 7 && F1 == 1);
  constexpr bool WA2 = (STAGE == 5 && F2 == 1);
  constexpr bool RA2 = (STAGE == 7 && F1 == 2);
  constexpr bool DO_C1 = !(RA1 || RA2);   // run conv1
  constexpr bool DO_C2 = !RA2;            // run conv2
  constexpr int NIB = 16;
  constexpr int NW1 = (STAGE == 7) ? 16 : 4;

  __shared__ float sx_s[DO_C1 ? (NIB * 256 + 16) : 16];
  __shared__ alignas(16) short a1h[DO_C1 ? (NW1 * 2 * A1B) : 8];
  __shared__ alignas(16) short a2s[(DO_C2 && STAGE >= 5) ? 4 * 640 : 8];
  __shared__ alignas(16) short a3buf[(STAGE == 7) ? 16 * A3P : 8];
  __shared__ float redf[(STAGE == 3) ? 256 : ((STAGE == 5) ? 512 : 1)];

  const int tid = threadIdx.x, w = tid >> 6, lane = tid & 63;
  const int b = lane & 15, q = lane >> 4;

  if constexpr (DO_C1) {
    const float4* xs = (const float4*)(x + (size_t)blockIdx.x * (NIB * 256));
    float4* sd = (float4*)sx_s;
    for (int e = tid; e < NIB * 64; e += 256) sd[e] = xs[e];
    if (tid < 16) sx_s[NIB * 256 + tid] = 0.f;   // finite overrun pad
  }

  float w1r[9];
  float rs1 = 0.f, rt1 = 0.f;
  if constexpr (DO_C1) {
#pragma unroll
    for (int t = 0; t < 9; ++t) w1r[t] = w1[b * 9 + t];
    rs1 = ws[ST1 + b]; rt1 = ws[ST1 + 16 + b];
  }

  bf16x8 b2h[4];
  float rs2v[2], rt2v[2];
  if constexpr (DO_C2) {
#pragma unroll
    for (int ks = 0; ks < 2; ++ks)
#pragma unroll
      for (int nt = 0; nt < 2; ++nt) {
        bf16x8 vh;
#pragma unroll
        for (int j = 0; j < 8; ++j) {
          int kk = 8 * (q & 1) + j, dj = q >> 1;
          vh[j] = (short)f2bf(w2[(nt * 16 + b) * 64 + kk * 4 + ks * 2 + dj]);
        }
        b2h[ks * 2 + nt] = vh;
      }
    if constexpr (STAGE >= 5) {
#pragma unroll
      for (int nt = 0; nt < 2; ++nt) {
        rs2v[nt] = ws[ST2 + nt * 16 + b];
        rt2v[nt] = ws[ST2 + 32 + nt * 16 + b];
      }
    }
  }

  bf16x8 b3h[4];
  float rs3v[4], rt3v[4], rs3z[4], rt3z[4];
  if constexpr (STAGE >= 5) {
#pragma unroll
    for (int nt = 0; nt < 4; ++nt) {
      bf16x8 vh;
#pragma unroll
      for (int j = 0; j < 8; ++j)
        vh[j] = (short)f2bf(w3[(nt * 16 + b) * 32 + 8 * q + j]);
      b3h[nt] = vh;
    }
  }
  if constexpr (STAGE == 7) {
#pragma unroll
    for (int nt = 0; nt < 4; ++nt) {
      rs3v[nt] = ws[ST3 + nt * 16 + b];
      rt3v[nt] = ws[ST3 + 64 + nt * 16 + b];
      rs3z[nt] = (q < 3) ? rs3v[nt] : 0.f;   // pixels 4q+r, r>=1 invalid at q==3
      rt3z[nt] = (q < 3) ? rt3v[nt] : 0.f;
    }
  }

  // validity weights for stats (pixel m = 4q+r)
  float wm[4];
#pragma unroll
  for (int r = 0; r < 4; ++r) wm[r] = (4 * q + r) < 13 ? 1.f : 0.f;

  // A-frag offsets: conv2 A col = min(b + dj, 15), dj = q>>1.
  const int colAr = (b + (q >> 1) < 15) ? (b + (q >> 1)) : 15;
  const int offAl = colAr * A1S + 8 * (q & 1);   // LDS a1h
  const int offAg = colAr * 16 + 8 * (q & 1);    // global a1g (within row)
  const int offA3 = b * 40 + 8 * q;              // LDS a2s
  short* a2w = a2s + w * 640;

  __syncthreads();

  if constexpr (STAGE != 7) {
    float s2[2] = {0.f, 0.f}, q2[2] = {0.f, 0.f};
    float s3[4] = {0.f, 0.f, 0.f, 0.f}, q3[4] = {0.f, 0.f, 0.f, 0.f};
    float* red = redf;
    short* ph = a1h + w * (2 * A1B);
#pragma unroll 1
    for (int t = 0; t < 4; ++t) {
      const int img = blockIdx.x * 16 + w * 4 + t;
      short* a1img = WA1 ? (a1g + (size_t)img * 3584) : (short*)nullptr;
      const short* a1imgR = RA1 ? (a1g + (size_t)img * 3584) : (const short*)nullptr;
      const float* sxi = sx_s + (w * 4 + t) * 256;
      bf16x8 ahP;
      if constexpr (DO_C1) {
        conv1_row<WA1>(sxi, ph, a1img, 0, b, q, w1r, rs1, rt1);
        __builtin_amdgcn_wave_barrier();
      } else {
        ahP = *(const bf16x8*)(a1imgR + offAg);
      }
#pragma unroll 1
      for (int i = 0; i < 13; ++i) {
        bf16x8 ah0, ah1;
        if constexpr (DO_C1) {
          conv1_row<WA1>(sxi, ph, a1img, i + 1, b, q, w1r, rs1, rt1);
          __builtin_amdgcn_wave_barrier();
          ah0 = *(const bf16x8*)(ph + (i & 1) * A1B + offAl);
          ah1 = *(const bf16x8*)(ph + ((i + 1) & 1) * A1B + offAl);
        } else {
          ah1 = *(const bf16x8*)(a1imgR + (i + 1) * 256 + offAg);
          ah0 = ahP;
        }
        f32x4 acc2[2] = {{0.f,0.f,0.f,0.f},{0.f,0.f,0.f,0.f}};
#pragma unroll
        for (int nt = 0; nt < 2; ++nt) {
          acc2[nt] = __builtin_amdgcn_mfma_f32_16x16x32_bf16(ah0, b2h[nt], acc2[nt], 0, 0, 0);
          acc2[nt] = __builtin_amdgcn_mfma_f32_16x16x32_bf16(ah1, b2h[2 + nt], acc2[nt], 0, 0, 0);
        }
        if constexpr (STAGE == 3) {
#pragma unroll
          for (int nt = 0; nt < 2; ++nt)
#pragma unroll
            for (int r = 0; r < 4; ++r) {
              float ym = acc2[nt][r] * wm[r];
              s2[nt] += ym;
              q2[nt] = fmaf(ym, acc2[nt][r], q2[nt]);
            }
        } else {
#pragma unroll
          for (int nt = 0; nt < 2; ++nt)
#pragma unroll
            for (int r = 0; r < 4; ++r) {
              float v = rs2v[nt] * acc2[nt][r] + rt2v[nt];
              v = v > 0.f ? v : 0.f;
              a2w[(4 * q + r) * 40 + nt * 16 + b] = cvtbf(v);
            }
          __builtin_amdgcn_wave_barrier();
          bf16x8 a2f = *(const bf16x8*)(a2w + offA3);
#pragma unroll
          for (int nt = 0; nt < 4; ++nt) {
            f32x4 acc3 = {0.f, 0.f, 0.f, 0.f};
            acc3 = __builtin_amdgcn_mfma_f32_16x16x32_bf16(a2f, b3h[nt], acc3, 0, 0, 0);
#pragma unroll
            for (int r = 0; r < 4; ++r) {
              float ym = acc3[r] * wm[r];
              s3[nt] += ym;
              q3[nt] = fmaf(ym, acc3[r], q3[nt]);
            }
          }
          if constexpr (WA2) {
            unsigned* a2g32 = (unsigned*)a2g;
            const unsigned* a2w32 = (const unsigned*)a2w;
            size_t dbase = (size_t)img * 3328 + (size_t)i * 256;
#pragma unroll
            for (int tt = 0; tt < 4; ++tt) {
              int f = tt * 64 + lane;
              a2g32[dbase + f] = a2w32[(f >> 4) * 20 + (f & 15)];
            }
          }
        }
        if constexpr (!DO_C1) ahP = ah1;
        __builtin_amdgcn_wave_barrier();
      }
    }
    if constexpr (STAGE == 3) {
#pragma unroll
      for (int nt = 0; nt < 2; ++nt) {
        s2[nt] += __shfl_xor(s2[nt], 16); s2[nt] += __shfl_xor(s2[nt], 32);
        q2[nt] += __shfl_xor(q2[nt], 16); q2[nt] += __shfl_xor(q2[nt], 32);
      }
      if (lane < 16) {
        red[w * 64 + b]      = s2[0];
        red[w * 64 + 16 + b] = s2[1];
        red[w * 64 + 32 + b] = q2[0];
        red[w * 64 + 48 + b] = q2[1];
      }
      __syncthreads();
      if (tid < 64)
        ws[P2_OFF + blockIdx.x * 64 + tid] =
            red[tid] + red[64 + tid] + red[128 + tid] + red[192 + tid];
    } else {
#pragma unroll
      for (int nt = 0; nt < 4; ++nt) {
        s3[nt] += __shfl_xor(s3[nt], 16); s3[nt] += __shfl_xor(s3[nt], 32);
        q3[nt] += __shfl_xor(q3[nt], 16); q3[nt] += __shfl_xor(q3[nt], 32);
      }
      if (lane < 16) {
#pragma unroll
        for (int nt = 0; nt < 4; ++nt) {
          red[w * 128 + nt * 16 + b]      = s3[nt];
          red[w * 128 + 64 + nt * 16 + b] = q3[nt];
        }
      }
      __syncthreads();
      if (tid < 128)
        ws[P3_OFF + blockIdx.x * 128 + tid] =
            red[tid] + red[128 + tid] + red[256 + tid] + red[384 + tid];
    }
  }

  if constexpr (STAGE == 7) {
    const bf16x8* fcB = (const bf16x8*)ws;
    f32x4 accF = {0.f, 0.f, 0.f, 0.f};
    bf16x8 ahP[4];

    if constexpr (DO_C1) {
#pragma unroll
      for (int t = 0; t < 4; ++t)
        conv1_row<false>(sx_s + (w * 4 + t) * 256, a1h + (w * 4 + t) * (2 * A1B),
                         nullptr, 0, b, q, w1r, rs1, rt1);
      __builtin_amdgcn_wave_barrier();
    } else if constexpr (RA1) {
#pragma unroll
      for (int t = 0; t < 4; ++t)
        ahP[t] = *(const bf16x8*)(a1g + (size_t)(blockIdx.x * 16 + w * 4 + t) * 3584 + offAg);
    }

#pragma unroll 1
    for (int i = 0; i < 13; ++i) {
#pragma unroll
      for (int t = 0; t < 4; ++t) {
        const int g = w * 4 + t;
        const int img = blockIdx.x * 16 + g;
        bf16x8 a2f;
        if constexpr (RA2) {
          a2f = *(const bf16x8*)(a2g + (size_t)img * 6656 + i * 512 + b * 32 + 8 * q);
        } else {
          bf16x8 ah0, ah1;
          if constexpr (DO_C1) {
            short* ph = a1h + g * (2 * A1B);
            conv1_row<false>(sx_s + g * 256, ph, nullptr, i + 1, b, q, w1r, rs1, rt1);
            __builtin_amdgcn_wave_barrier();
            ah0 = *(const bf16x8*)(ph + (i & 1) * A1B + offAl);
            ah1 = *(const bf16x8*)(ph + ((i + 1) & 1) * A1B + offAl);
          } else {
            ah0 = ahP[t];
            ah1 = *(const bf16x8*)(a1g + (size_t)img * 3584 + (i + 1) * 256 + offAg);
            ahP[t] = ah1;
          }
          f32x4 acc2[2] = {{0.f,0.f,0.f,0.f},{0.f,0.f,0.f,0.f}};
#pragma unroll
          for (int nt = 0; nt < 2; ++nt) {
            acc2[nt] = __builtin_amdgcn_mfma_f32_16x16x32_bf16(ah0, b2h[nt], acc2[nt], 0, 0, 0);
            acc2[nt] = __builtin_amdgcn_mfma_f32_16x16x32_bf16(ah1, b2h[2 + nt], acc2[nt], 0, 0, 0);
          }
#pragma unroll
          for (int nt = 0; nt < 2; ++nt)
#pragma unroll
            for (int r = 0; r < 4; ++r) {
              float v = rs2v[nt] * acc2[nt][r] + rt2v[nt];
              v = v > 0.f ? v : 0.f;
              a2w[(4 * q + r) * 40 + nt * 16 + b] = cvtbf(v);
            }
          __builtin_amdgcn_wave_barrier();
          a2f = *(const bf16x8*)(a2w + offA3);
        }
#pragma unroll
        for (int nt = 0; nt < 4; ++nt) {
          f32x4 acc3 = {0.f, 0.f, 0.f, 0.f};
          acc3 = __builtin_amdgcn_mfma_f32_16x16x32_bf16(a2f, b3h[nt], acc3, 0, 0, 0);
          float v0 = rs3v[nt] * acc3[0] + rt3v[nt];
          float v1 = rs3z[nt] * acc3[1] + rt3z[nt];
          float v2 = rs3z[nt] * acc3[2] + rt3z[nt];
          float v3 = rs3z[nt] * acc3[3] + rt3z[nt];
          v0 = v0 > 0.f ? v0 : 0.f;  v1 = v1 > 0.f ? v1 : 0.f;
          v2 = v2 > 0.f ? v2 : 0.f;  v3 = v3 > 0.f ? v3 : 0.f;
          uint2 pk2;
          pk2.x = pkbf(v0, v1);
          pk2.y = pkbf(v2, v3);
          *(uint2*)(a3buf + g * A3P + (nt * 16 + b) * 16 + 4 * q) = pk2;
        }
        __builtin_amdgcn_wave_barrier();
      }
      __syncthreads();          // a3buf complete for all 16 images
#pragma unroll
      for (int mm = 0; mm < 8; ++mm) {
        bf16x8 af = *(const bf16x8*)(a3buf + b * A3P + w * 256 + mm * 32 + 8 * q);
        bf16x8 bw = fcB[((i * 32 + w * 8 + mm) * 16 + b) * 4 + q];
        accF = __builtin_amdgcn_mfma_f32_16x16x32_bf16(af, bw, accF, 0, 0, 0);
      }
      __syncthreads();          // before next row overwrites a3buf
    }

    float* redf7 = (float*)a3buf;   // a3buf is free after the loop
#pragma unroll
    for (int r = 0; r < 4; ++r)
      redf7[w * 256 + (4 * q + r) * 16 + b] = accF[r];
    __syncthreads();
    if (tid < 160) {
      int img = tid / 10, jj = tid - img * 10;
      float s = redf7[img * 16 + jj] + redf7[256 + img * 16 + jj] +
                redf7[512 + img * 16 + jj] + redf7[768 + img * 16 + jj];
      out[(blockIdx.x * 16 + img) * 10 + jj] = s + fcb[jj];
    }
  }
}

extern "C" void kernel_launch(void* const* d_in, const int* in_sizes, int n_in,
                              void* d_out, int out_size, void* d_ws, size_t ws_size,
                              hipStream_t stream) {
  (void)in_sizes; (void)n_in; (void)out_size;
  const float* x   = (const float*)d_in[0];
  const float* w1  = (const float*)d_in[1];
  const float* w2  = (const float*)d_in[2];
  const float* w3  = (const float*)d_in[3];
  const float* g1  = (const float*)d_in[4];
  const float* b1  = (const float*)d_in[5];
  const float* g2  = (const float*)d_in[6];
  const float* b2  = (const float*)d_in[7];
  const float* g3  = (const float*)d_in[8];
  const float* b3  = (const float*)d_in[9];
  const float* fcw = (const float*)d_in[10];
  const float* fcb = (const float*)d_in[11];
  float* out = (float*)d_out;
  float* ws  = (float*)d_ws;
  char*  wsb = (char*)d_ws;

  // Tier selection: constant across calls (ws_size fixed) -> graph-safe.
  short* a1g = nullptr;
  short* a2g = nullptr;
  int tier = 0;
  if (ws_size >= AC_BASE + A1_BYTES + A2_BYTES) {
    tier = 3; a1g = (short*)(wsb + AC_BASE); a2g = (short*)(wsb + AC_BASE + A1_BYTES);
  } else if (ws_size >= AC_BASE + A2_BYTES) {
    tier = 2; a2g = (short*)(wsb + AC_BASE);
  } else if (ws_size >= AC_BASE + A1_BYTES) {
    tier = 1; a1g = (short*)(wsb + AC_BASE);
  }

  k1_xstats<<<512, 256, 0, stream>>>(x, ws);
  k_stats1<<<1, 256, 0, stream>>>(w1, g1, b1, ws);

  if (tier == 3 || tier == 1)
    k_pipe<3,1,0><<<1024, 256, 0, stream>>>(x, w1, w2, w3, fcb, ws, a1g, a2g, out);
  else
    k_pipe<3,0,0><<<1024, 256, 0, stream>>>(x, w1, w2, w3, fcb, ws, a1g, a2g, out);

  k_stats2<<<32, 256, 0, stream>>>(g2, b2, ws, 32, P2_OFF, ST2,
                                   1.0f / (16384.0f * 169.0f));

  if (tier == 3)
    k_pipe<5,1,1><<<1024, 256, 0, stream>>>(x, w1, w2, w3, fcb, ws, a1g, a2g, out);
  else if (tier == 2)
    k_pipe<5,0,1><<<1024, 256, 0, stream>>>(x, w1, w2, w3, fcb, ws, a1g, a2g, out);
  else if (tier == 1)
    k_pipe<5,1,0><<<1024, 256, 0, stream>>>(x, w1, w2, w3, fcb, ws, a1g, a2g, out);
  else
    k_pipe<5,0,0><<<1024, 256, 0, stream>>>(x, w1, w2, w3, fcb, ws, a1g, a2g, out);

  k_stats2<<<64, 256, 0, stream>>>(g3, b3, ws, 64, P3_OFF, ST3,
                                   1.0f / (16384.0f * 169.0f));
  k0_fcB<<<FCB_N / 256, 256, 0, stream>>>(fcw, (unsigned int*)ws);

  if (tier >= 2)
    k_pipe<7,2,0><<<1024, 256, 0, stream>>>(x, w1, w2, w3, fcb, ws, a1g, a2g, out);
  else if (tier == 1)
    k_pipe<7,1,0><<<1024, 256, 0, stream>>>(x, w1, w2, w3, fcb, ws, a1g, a2g, out);
  else
    k_pipe<7,0,0><<<1024, 256, 0, stream>>>(x, w1, w2, w3, fcb, ws, a1g, a2g, out);
}

// Round 7
// 296.532 us; speedup vs baseline: 8.4228x; 1.1865x over previous
//
#include <hip/hip_runtime.h>

// ---------------------------------------------------------------------------
// LocallyConnectedNN: x[16384,256] -> conv3x3(1->16)+BN+ReLU -> conv2x2(16->32)
// +BN+ReLU -> conv1x1(32->64)+BN+ReLU -> FC(10816->10).
// Round 7: (1) conv1 moved to MFMA (im2row from sx, zero-padded K), used in
// k3 and k5; (2) BN3 stats via second moments: S2=E[a2], C2=E[a2 a2^T] via
// MFMA syrk where A-frag==B-frag (conv3 never computed in the stats pass);
// (3) a2 cache packed to 13 pixels (177MB, ws need 182MB < proven 219MB);
// (4) k7 prefetches next row's a2 frags into registers.
// ws layout: [0,1MB): P1/P2 partials, ST params, C2R, fcB(416KB overwrites
// P1/P2 after consumption). [1MB,4.3MB): C2/S2 block partials. [5MB,182MB): a2.
// ---------------------------------------------------------------------------

#define NPART 1024
#define P1_OFF 0          // [512][54] x-patch S|C partials
#define P2_OFF 32768      // [1024][64] conv2 stats partials
#define ST_OFF 229376     // s1[16] t1[16] s2[32] t2[32] s3[64] t3[64]
#define ST1 ST_OFF
#define ST2 (ST_OFF + 32)
#define ST3 (ST_OFF + 96)
#define C2R_OFF 230400    // reduced [768 C2 tiles | 32 S2]
#define C2P_OFF 262144    // block partials [1024][800] floats (1MB..4.3MB)
#define A2G_BYTE 5242880ull // a2 cache: [img][13 i][13 pix][32 ch] bf16, 177MB
#define FCB_N (13 * 8192) // fcB u32 at ws[0..106496)
#define A1S 24            // a1h LDS row stride (shorts)
#define A1B 384           // one a1 LDS buffer (16 rows x A1S)
#define A3P 1048          // a3buf image stride (shorts)

typedef __attribute__((ext_vector_type(8))) short bf16x8;
typedef __attribute__((ext_vector_type(4))) float f32x4;

__device__ __forceinline__ unsigned int f2bf(float f) {
  unsigned int u = __float_as_uint(f);
  return (u + 0x7fffu + ((u >> 16) & 1u)) >> 16;   // RTNE bf16 bits
}
// pack two floats to bf16x2 (round-half-up): 2 adds + 1 v_perm_b32
__device__ __forceinline__ unsigned int pkbf(float a, float b) {
  unsigned ua = __float_as_uint(a) + 0x8000u;
  unsigned ub = __float_as_uint(b) + 0x8000u;
  return __builtin_amdgcn_perm(ub, ua, 0x07060302u);
}
__device__ __forceinline__ short cvtbf(float a) {
  return (short)((__float_as_uint(a) + 0x8000u) >> 16);
}

// conv1 (3x3,1->16)+bn1+relu for one output row r via MFMA.
// A-frag: m=col j (lane b), k=tap (8q+j', taps>=9 hit zero B). D: n=ch=b, m=j.
__device__ __forceinline__ void conv1_mfma(
    const float* __restrict__ sxi,   // [256] image (+finite pad after)
    short* ph_buf,                   // [2 bufs][16 j][A1S]
    int r, int b, int q, bf16x8 b1f, float rs1, float rt1)
{
  bf16x8 af = {0, 0, 0, 0, 0, 0, 0, 0};
  unsigned* au = (unsigned*)&af;
  if (q == 0) {
    au[0] = pkbf(sxi[r * 16 + b],        sxi[r * 16 + b + 1]);
    au[1] = pkbf(sxi[r * 16 + b + 2],    sxi[(r + 1) * 16 + b]);
    au[2] = pkbf(sxi[(r + 1) * 16 + b + 1], sxi[(r + 1) * 16 + b + 2]);
    au[3] = pkbf(sxi[(r + 2) * 16 + b],  sxi[(r + 2) * 16 + b + 1]);
  } else if (q == 1) {
    au[0] = pkbf(sxi[(r + 2) * 16 + b + 2], 0.f);
  }
  f32x4 acc = {0.f, 0.f, 0.f, 0.f};
  acc = __builtin_amdgcn_mfma_f32_16x16x32_bf16(af, b1f, acc, 0, 0, 0);
  short* ph = ph_buf + (r & 1) * A1B;
#pragma unroll
  for (int rr = 0; rr < 4; ++rr) {
    float v = rs1 * acc[rr] + rt1;
    v = v > 0.f ? v : 0.f;
    ph[(4 * q + rr) * A1S + b] = cvtbf(v);
  }
}

// conv1 weight B-frag: n=ch=b, k=tap 8q+j (zeros for tap>=9).
__device__ __forceinline__ bf16x8 conv1_bfrag(const float* w1, int b, int q) {
  bf16x8 v;
#pragma unroll
  for (int j = 0; j < 8; ++j) {
    int tap = 8 * q + j;
    v[j] = (tap < 9) ? (short)f2bf(w1[b * 9 + tap]) : (short)0;
  }
  return v;
}

// K1: x patch statistics (S[9], upper-tri C[45]) -- BN1 via covariance trick.
__global__ __launch_bounds__(256) void k1_xstats(
    const float* __restrict__ x, float* __restrict__ ws)
{
  __shared__ float sx[32 * 256];
  __shared__ float redl[4 * 56];
  const int tid = threadIdx.x, w = tid >> 6, lane = tid & 63;
  {
    const float4* xs = (const float4*)(x + (size_t)blockIdx.x * (32 * 256));
    float4* sd = (float4*)sx;
    for (int e = tid; e < 32 * 64; e += 256) sd[e] = xs[e];
  }
  __syncthreads();
  float S[9], C[45];
#pragma unroll
  for (int a = 0; a < 9; ++a) S[a] = 0.f;
#pragma unroll
  for (int a = 0; a < 45; ++a) C[a] = 0.f;
  for (int p = tid; p < 32 * 196; p += 256) {
    int img = p / 196, rem = p - img * 196;
    int i = rem / 14, j = rem - i * 14;
    const float* px = sx + img * 256 + i * 16 + j;
    float v[9];
    v[0] = px[0];  v[1] = px[1];  v[2] = px[2];
    v[3] = px[16]; v[4] = px[17]; v[5] = px[18];
    v[6] = px[32]; v[7] = px[33]; v[8] = px[34];
    int idx = 0;
#pragma unroll
    for (int a = 0; a < 9; ++a) {
      S[a] += v[a];
#pragma unroll
      for (int c = a; c < 9; ++c) { C[idx] += v[a] * v[c]; ++idx; }
    }
  }
#pragma unroll
  for (int a = 0; a < 9; ++a) {
    float v = S[a];
#pragma unroll
    for (int d = 1; d < 64; d <<= 1) v += __shfl_xor(v, d);
    if (lane == 0) redl[w * 56 + a] = v;
  }
#pragma unroll
  for (int a = 0; a < 45; ++a) {
    float v = C[a];
#pragma unroll
    for (int d = 1; d < 64; d <<= 1) v += __shfl_xor(v, d);
    if (lane == 0) redl[w * 56 + 9 + a] = v;
  }
  __syncthreads();
  if (tid < 54)
    ws[P1_OFF + blockIdx.x * 54 + tid] =
        redl[tid] + redl[56 + tid] + redl[112 + tid] + redl[168 + tid];
}

// BN1 finalize: fold S/C with w1 into per-channel scale/shift.
__global__ __launch_bounds__(256) void k_stats1(
    const float* __restrict__ w1, const float* __restrict__ gamma,
    const float* __restrict__ beta, float* __restrict__ ws)
{
  __shared__ float part[216];
  __shared__ float acc[54];
  const int tid = threadIdx.x;
  if (tid < 216) {
    int a = tid >> 2, seg = tid & 3;
    float s = 0.f;
    for (int i = seg * 128; i < seg * 128 + 128; ++i)
      s += ws[P1_OFF + i * 54 + a];
    part[tid] = s;
  }
  __syncthreads();
  if (tid < 54)
    acc[tid] = part[tid * 4] + part[tid * 4 + 1] +
               part[tid * 4 + 2] + part[tid * 4 + 3];
  __syncthreads();
  if (tid < 16) {
    float wr[9];
#pragma unroll
    for (int p = 0; p < 9; ++p) wr[p] = w1[tid * 9 + p];
    float msum = 0.f;
#pragma unroll
    for (int p = 0; p < 9; ++p) msum += wr[p] * acc[p];
    float e2 = 0.f;
    int idx = 9;
#pragma unroll
    for (int a = 0; a < 9; ++a)
#pragma unroll
      for (int c = a; c < 9; ++c) {
        float t = wr[a] * wr[c] * acc[idx];
        e2 += (c == a) ? t : 2.f * t;
        ++idx;
      }
    const float inv_n = 1.0f / (16384.0f * 196.0f);
    float mean = msum * inv_n;
    float var  = e2 * inv_n - mean * mean;
    float sv   = gamma[tid] * rsqrtf(var + 1e-5f);
    ws[ST1 + tid]      = sv;
    ws[ST1 + 16 + tid] = beta[tid] - mean * sv;
  }
}

// BN2 finalize, one block per channel (reduces P2 [1024][64]).
__global__ __launch_bounds__(256) void k_stats2(
    const float* __restrict__ gamma, const float* __restrict__ beta,
    float* __restrict__ ws, int nch, int part_off, int st_off, float inv_n)
{
  const int c = blockIdx.x, tid = threadIdx.x;
  const int w = tid >> 6, lane = tid & 63;
  __shared__ float rs[4], rq[4];
  float s = 0.f, q = 0.f;
#pragma unroll 4
  for (int i = tid; i < NPART; i += 256) {
    s += ws[part_off + i * 2 * nch + c];
    q += ws[part_off + i * 2 * nch + nch + c];
  }
#pragma unroll
  for (int d = 1; d < 64; d <<= 1) {
    s += __shfl_xor(s, d);
    q += __shfl_xor(q, d);
  }
  if (lane == 0) { rs[w] = s; rq[w] = q; }
  __syncthreads();
  if (tid == 0) {
    float st = rs[0] + rs[1] + rs[2] + rs[3];
    float qt = rq[0] + rq[1] + rq[2] + rq[3];
    float mean = st * inv_n;
    float var  = qt * inv_n - mean * mean;
    float sv   = gamma[c] * rsqrtf(var + 1e-5f);
    ws[st_off + c]       = sv;
    ws[st_off + nch + c] = beta[c] - mean * sv;
  }
}

// K3: conv1(MFMA) + conv2 raw stats.
__global__ __launch_bounds__(256) void k3_conv2_stats(
    const float* __restrict__ x, const float* __restrict__ w1,
    const float* __restrict__ w2, float* __restrict__ ws)
{
  __shared__ float sx_s[16 * 256 + 16];
  __shared__ alignas(16) short a1h[4 * 2 * A1B];
  __shared__ float redf[256];
  const int tid = threadIdx.x, w = tid >> 6, lane = tid & 63;
  const int b = lane & 15, q = lane >> 4;
  {
    const float4* xs = (const float4*)(x + (size_t)blockIdx.x * (16 * 256));
    float4* sd = (float4*)sx_s;
    for (int e = tid; e < 16 * 64; e += 256) sd[e] = xs[e];
    if (tid < 16) sx_s[16 * 256 + tid] = 0.f;
  }
  bf16x8 b1f = conv1_bfrag(w1, b, q);
  const float rs1 = ws[ST1 + b], rt1 = ws[ST1 + 16 + b];
  bf16x8 b2h[4];
#pragma unroll
  for (int ks = 0; ks < 2; ++ks)
#pragma unroll
    for (int nt = 0; nt < 2; ++nt) {
      bf16x8 vh;
#pragma unroll
      for (int j = 0; j < 8; ++j) {
        int kk = 8 * (q & 1) + j, dj = q >> 1;
        vh[j] = (short)f2bf(w2[(nt * 16 + b) * 64 + kk * 4 + ks * 2 + dj]);
      }
      b2h[ks * 2 + nt] = vh;
    }
  float wm[4];
#pragma unroll
  for (int r = 0; r < 4; ++r) wm[r] = (4 * q + r) < 13 ? 1.f : 0.f;
  const int colAr = (b + (q >> 1) < 15) ? (b + (q >> 1)) : 15;
  const int offAl = colAr * A1S + 8 * (q & 1);
  __syncthreads();

  float s2[2] = {0.f, 0.f}, q2[2] = {0.f, 0.f};
  short* ph = a1h + w * (2 * A1B);
#pragma unroll 1
  for (int t = 0; t < 4; ++t) {
    const float* sxi = sx_s + (w * 4 + t) * 256;
    conv1_mfma(sxi, ph, 0, b, q, b1f, rs1, rt1);
    __builtin_amdgcn_wave_barrier();
#pragma unroll 1
    for (int i = 0; i < 13; ++i) {
      conv1_mfma(sxi, ph, i + 1, b, q, b1f, rs1, rt1);
      __builtin_amdgcn_wave_barrier();
      bf16x8 ah0 = *(const bf16x8*)(ph + (i & 1) * A1B + offAl);
      bf16x8 ah1 = *(const bf16x8*)(ph + ((i + 1) & 1) * A1B + offAl);
      f32x4 acc2[2] = {{0.f,0.f,0.f,0.f},{0.f,0.f,0.f,0.f}};
#pragma unroll
      for (int nt = 0; nt < 2; ++nt) {
        acc2[nt] = __builtin_amdgcn_mfma_f32_16x16x32_bf16(ah0, b2h[nt], acc2[nt], 0, 0, 0);
        acc2[nt] = __builtin_amdgcn_mfma_f32_16x16x32_bf16(ah1, b2h[2 + nt], acc2[nt], 0, 0, 0);
      }
#pragma unroll
      for (int nt = 0; nt < 2; ++nt)
#pragma unroll
        for (int r = 0; r < 4; ++r) {
          float ym = acc2[nt][r] * wm[r];
          s2[nt] += ym;
          q2[nt] = fmaf(ym, acc2[nt][r], q2[nt]);
        }
      __builtin_amdgcn_wave_barrier();
    }
  }
#pragma unroll
  for (int nt = 0; nt < 2; ++nt) {
    s2[nt] += __shfl_xor(s2[nt], 16); s2[nt] += __shfl_xor(s2[nt], 32);
    q2[nt] += __shfl_xor(q2[nt], 16); q2[nt] += __shfl_xor(q2[nt], 32);
  }
  if (lane < 16) {
    redf[w * 64 + b]      = s2[0];
    redf[w * 64 + 16 + b] = s2[1];
    redf[w * 64 + 32 + b] = q2[0];
    redf[w * 64 + 48 + b] = q2[1];
  }
  __syncthreads();
  if (tid < 64)
    ws[P2_OFF + blockIdx.x * 64 + tid] =
        redf[tid] + redf[64 + tid] + redf[128 + tid] + redf[192 + tid];
}

// K5: conv1(MFMA)+conv2+bn2+relu -> packed a2 cache + S2/C2 syrk (BN3 stats).
// Xt LDS [32 ch][32 pos + pad8]; syrk tiles T00,T01,T11 with A-frag==B-frag.
__global__ __launch_bounds__(256) void k5_a2(
    const float* __restrict__ x, const float* __restrict__ w1,
    const float* __restrict__ w2, float* __restrict__ ws,
    short* __restrict__ a2g, float* __restrict__ parts)
{
  __shared__ float sx_s[16 * 256 + 16];          // reused as redc at the end
  __shared__ alignas(16) short a1h[4 * 2 * A1B];
  __shared__ alignas(16) short a2w4[4 * 640];    // [w][pix16][40]
  __shared__ alignas(16) short xt4[4 * 32 * 40]; // [w][ch32][pos32+pad8]
  __shared__ float s2red[4 * 32];
  const int tid = threadIdx.x, w = tid >> 6, lane = tid & 63;
  const int b = lane & 15, q = lane >> 4;
  {
    const float4* xs = (const float4*)(x + (size_t)blockIdx.x * (16 * 256));
    float4* sd = (float4*)sx_s;
    for (int e = tid; e < 16 * 64; e += 256) sd[e] = xs[e];
    if (tid < 16) sx_s[16 * 256 + tid] = 0.f;
  }
  bf16x8 b1f = conv1_bfrag(w1, b, q);
  const float rs1 = ws[ST1 + b], rt1 = ws[ST1 + 16 + b];
  bf16x8 b2h[4];
#pragma unroll
  for (int ks = 0; ks < 2; ++ks)
#pragma unroll
    for (int nt = 0; nt < 2; ++nt) {
      bf16x8 vh;
#pragma unroll
      for (int j = 0; j < 8; ++j) {
        int kk = 8 * (q & 1) + j, dj = q >> 1;
        vh[j] = (short)f2bf(w2[(nt * 16 + b) * 64 + kk * 4 + ks * 2 + dj]);
      }
      b2h[ks * 2 + nt] = vh;
    }
  float rs2v[2], rt2v[2];
#pragma unroll
  for (int nt = 0; nt < 2; ++nt) {
    rs2v[nt] = ws[ST2 + nt * 16 + b];
    rt2v[nt] = ws[ST2 + 32 + nt * 16 + b];
  }
  float wm[4];
#pragma unroll
  for (int r = 0; r < 4; ++r) wm[r] = (4 * q + r) < 13 ? 1.f : 0.f;
  const int colAr = (b + (q >> 1) < 15) ? (b + (q >> 1)) : 15;
  const int offAl = colAr * A1S + 8 * (q & 1);
  short* a2w = a2w4 + w * 640;
  short* xt  = xt4 + w * 1280;
  __syncthreads();

  f32x4 accT0 = {0.f,0.f,0.f,0.f}, accT1 = {0.f,0.f,0.f,0.f},
        accT2 = {0.f,0.f,0.f,0.f};
  float s2a[2] = {0.f, 0.f};
  short* ph = a1h + w * (2 * A1B);
#pragma unroll 1
  for (int t = 0; t < 4; ++t) {
    const int img = blockIdx.x * 16 + w * 4 + t;
    const float* sxi = sx_s + (w * 4 + t) * 256;
    conv1_mfma(sxi, ph, 0, b, q, b1f, rs1, rt1);
    __builtin_amdgcn_wave_barrier();
#pragma unroll 1
    for (int i = 0; i < 13; ++i) {
      conv1_mfma(sxi, ph, i + 1, b, q, b1f, rs1, rt1);
      __builtin_amdgcn_wave_barrier();
      bf16x8 ah0 = *(const bf16x8*)(ph + (i & 1) * A1B + offAl);
      bf16x8 ah1 = *(const bf16x8*)(ph + ((i + 1) & 1) * A1B + offAl);
      f32x4 acc2[2] = {{0.f,0.f,0.f,0.f},{0.f,0.f,0.f,0.f}};
#pragma unroll
      for (int nt = 0; nt < 2; ++nt) {
        acc2[nt] = __builtin_amdgcn_mfma_f32_16x16x32_bf16(ah0, b2h[nt], acc2[nt], 0, 0, 0);
        acc2[nt] = __builtin_amdgcn_mfma_f32_16x16x32_bf16(ah1, b2h[2 + nt], acc2[nt], 0, 0, 0);
      }
#pragma unroll
      for (int nt = 0; nt < 2; ++nt) {
        float vm[4];
#pragma unroll
        for (int r = 0; r < 4; ++r) {
          float v = rs2v[nt] * acc2[nt][r] + rt2v[nt];
          v = v > 0.f ? v : 0.f;
          vm[r] = v * wm[r];
          a2w[(4 * q + r) * 40 + nt * 16 + b] = cvtbf(vm[r]);
        }
        uint2 pk2;
        pk2.x = pkbf(vm[0], vm[1]);
        pk2.y = pkbf(vm[2], vm[3]);
        *(uint2*)(xt + (nt * 16 + b) * 40 + (i & 1) * 16 + 4 * q) = pk2;
        s2a[nt] += (vm[0] + vm[1]) + (vm[2] + vm[3]);
      }
      __builtin_amdgcn_wave_barrier();
      // packed global a2 write: [img][i][13 pix][32 ch]
      {
        const unsigned* a2w32 = (const unsigned*)a2w;
        unsigned* a2g32 = (unsigned*)a2g;
        size_t dbase = (size_t)img * 2704 + (size_t)i * 208;
#pragma unroll
        for (int tt = 0; tt < 4; ++tt) {
          int f = tt * 64 + lane;
          if (f < 208) a2g32[dbase + f] = a2w32[(f >> 4) * 20 + (f & 15)];
        }
      }
      if (i & 1) {   // syrk over position pair (i-1, i)
        bf16x8 xf0 = *(const bf16x8*)(xt + b * 40 + 8 * q);
        bf16x8 xf1 = *(const bf16x8*)(xt + (16 + b) * 40 + 8 * q);
        accT0 = __builtin_amdgcn_mfma_f32_16x16x32_bf16(xf0, xf0, accT0, 0, 0, 0);
        accT1 = __builtin_amdgcn_mfma_f32_16x16x32_bf16(xf0, xf1, accT1, 0, 0, 0);
        accT2 = __builtin_amdgcn_mfma_f32_16x16x32_bf16(xf1, xf1, accT2, 0, 0, 0);
      }
      __builtin_amdgcn_wave_barrier();
    }
    // leftover row 12 (parity 0): zero parity-1 halves, final syrk
    {
      uint2 z; z.x = 0u; z.y = 0u;
      *(uint2*)(xt + b * 40 + 16 + 4 * q) = z;
      *(uint2*)(xt + (16 + b) * 40 + 16 + 4 * q) = z;
      __builtin_amdgcn_wave_barrier();
      bf16x8 xf0 = *(const bf16x8*)(xt + b * 40 + 8 * q);
      bf16x8 xf1 = *(const bf16x8*)(xt + (16 + b) * 40 + 8 * q);
      accT0 = __builtin_amdgcn_mfma_f32_16x16x32_bf16(xf0, xf0, accT0, 0, 0, 0);
      accT1 = __builtin_amdgcn_mfma_f32_16x16x32_bf16(xf0, xf1, accT1, 0, 0, 0);
      accT2 = __builtin_amdgcn_mfma_f32_16x16x32_bf16(xf1, xf1, accT2, 0, 0, 0);
      __builtin_amdgcn_wave_barrier();
    }
  }
  // reductions: S2 over q, C2 tiles into redc (reuse own sx quarter)
#pragma unroll
  for (int nt = 0; nt < 2; ++nt) {
    s2a[nt] += __shfl_xor(s2a[nt], 16);
    s2a[nt] += __shfl_xor(s2a[nt], 32);
  }
  if (lane < 16) { s2red[w * 32 + b] = s2a[0]; s2red[w * 32 + 16 + b] = s2a[1]; }
  float* redc = sx_s;   // wave w writes only into its own sx quarter
#pragma unroll
  for (int rr = 0; rr < 4; ++rr) {
    int m = 4 * q + rr;
    redc[w * 1024 + 0   + m * 16 + b] = accT0[rr];
    redc[w * 1024 + 256 + m * 16 + b] = accT1[rr];
    redc[w * 1024 + 512 + m * 16 + b] = accT2[rr];
  }
  __syncthreads();
  for (int e = tid; e < 768; e += 256)
    parts[blockIdx.x * 800 + e] =
        redc[e] + redc[1024 + e] + redc[2048 + e] + redc[3072 + e];
  if (tid < 32)
    parts[blockIdx.x * 800 + 768 + tid] =
        s2red[tid] + s2red[32 + tid] + s2red[64 + tid] + s2red[96 + tid];
}

// Reduce C2/S2 block partials: one block per entry e in [0,800).
__global__ __launch_bounds__(256) void k_statsC(
    const float* __restrict__ parts, float* __restrict__ ws)
{
  const int e = blockIdx.x, tid = threadIdx.x;
  const int w = tid >> 6, lane = tid & 63;
  __shared__ float rs[4];
  float s = 0.f;
#pragma unroll 4
  for (int i = tid; i < 1024; i += 256) s += parts[i * 800 + e];
#pragma unroll
  for (int d = 1; d < 64; d <<= 1) s += __shfl_xor(s, d);
  if (lane == 0) rs[w] = s;
  __syncthreads();
  if (tid == 0) ws[C2R_OFF + e] = rs[0] + rs[1] + rs[2] + rs[3];
}

// BN3 finalize from S2/C2: mean=w3^T S2/N, E[y3^2]=w3^T C2 w3 /N.
__global__ __launch_bounds__(64) void k_stats3n(
    const float* __restrict__ w3, const float* __restrict__ gamma,
    const float* __restrict__ beta, float* __restrict__ ws)
{
  const int c3 = threadIdx.x;
  if (c3 >= 64) return;
  const float* C2R = ws + C2R_OFF;
  float wr[32];
#pragma unroll
  for (int k = 0; k < 32; ++k) wr[k] = w3[c3 * 32 + k];
  const float inv_n = 1.0f / (16384.0f * 169.0f);
  float msum = 0.f;
#pragma unroll
  for (int k = 0; k < 32; ++k) msum += wr[k] * C2R[768 + k];
  float e2 = 0.f;
  for (int a = 0; a < 16; ++a)
#pragma unroll
    for (int bb = 0; bb < 16; ++bb) {
      e2 += wr[a] * wr[bb] * C2R[a * 16 + bb];              // T00
      e2 += wr[16 + a] * wr[16 + bb] * C2R[512 + a * 16 + bb]; // T11
      e2 += 2.f * wr[a] * wr[16 + bb] * C2R[256 + a * 16 + bb]; // T01 (+mirror)
    }
  float mean = msum * inv_n;
  float var  = e2 * inv_n - mean * mean;
  float sv   = gamma[c3] * rsqrtf(var + 1e-5f);
  ws[ST3 + c3]      = sv;
  ws[ST3 + 64 + c3] = beta[c3] - mean * sv;
}

// K0: pack fc_w into MFMA B-fragment order (bf16 pairs in u32).
__global__ __launch_bounds__(256) void k0_fcB(
    const float* __restrict__ fcw, unsigned int* __restrict__ fcB)
{
  int F = blockIdx.x * 256 + threadIdx.x;
  if (F >= FCB_N) return;
  int u = F & 3, q = (F >> 2) & 3, jj = (F >> 4) & 15;
  int mm = (F >> 8) & 31, i = F >> 13;
  int k0 = mm * 32 + q * 8 + u * 2;
  unsigned lo = 0, hi = 0;
  if (jj < 10) {
    int c0 = k0 >> 4, j0 = k0 & 15;
    if (j0 < 13) lo = f2bf(fcw[jj * 10816 + c0 * 169 + i * 13 + j0]);
    int c1 = (k0 + 1) >> 4, j1 = (k0 + 1) & 15;
    if (j1 < 13) hi = f2bf(fcw[jj * 10816 + c1 * 169 + i * 13 + j1]);
  }
  fcB[F] = lo | (hi << 16);
}

// K7: read packed a2 -> conv3+bn3+relu (MFMA) -> FC (MFMA), a2 prefetched.
__global__ __launch_bounds__(256) void k7_fc(
    const short* __restrict__ a2g, const float* __restrict__ w3,
    const float* __restrict__ fcb, const float* __restrict__ ws,
    float* __restrict__ out)
{
  __shared__ alignas(16) short a3buf[16 * A3P];
  const int tid = threadIdx.x, w = tid >> 6, lane = tid & 63;
  const int b = lane & 15, q = lane >> 4;
  bf16x8 b3h[4];
#pragma unroll
  for (int nt = 0; nt < 4; ++nt) {
    bf16x8 vh;
#pragma unroll
    for (int j = 0; j < 8; ++j)
      vh[j] = (short)f2bf(w3[(nt * 16 + b) * 32 + 8 * q + j]);
    b3h[nt] = vh;
  }
  float rs3v[4], rt3v[4], rs3z[4], rt3z[4];
#pragma unroll
  for (int nt = 0; nt < 4; ++nt) {
    rs3v[nt] = ws[ST3 + nt * 16 + b];
    rt3v[nt] = ws[ST3 + 64 + nt * 16 + b];
    rs3z[nt] = (q < 3) ? rs3v[nt] : 0.f;
    rt3z[nt] = (q < 3) ? rt3v[nt] : 0.f;
  }
  const bf16x8* fcB = (const bf16x8*)ws;
  f32x4 accF = {0.f, 0.f, 0.f, 0.f};
  const int pixc = (b < 12) ? b : 12;   // clamp pad rows (masked by rs3z)
  size_t ib[4];
#pragma unroll
  for (int t = 0; t < 4; ++t)
    ib[t] = (size_t)(blockIdx.x * 16 + w * 4 + t) * 5408;
  bf16x8 a2pre[4];
#pragma unroll
  for (int t = 0; t < 4; ++t)
    a2pre[t] = *(const bf16x8*)(a2g + ib[t] + pixc * 32 + 8 * q);

#pragma unroll 1
  for (int i = 0; i < 13; ++i) {
    bf16x8 a2cur[4];
#pragma unroll
    for (int t = 0; t < 4; ++t) a2cur[t] = a2pre[t];
    if (i < 12) {
#pragma unroll
      for (int t = 0; t < 4; ++t)
        a2pre[t] = *(const bf16x8*)(a2g + ib[t] +
                                    (size_t)((i + 1) * 13 + pixc) * 32 + 8 * q);
    }
#pragma unroll
    for (int t = 0; t < 4; ++t) {
      const int g = w * 4 + t;
#pragma unroll
      for (int nt = 0; nt < 4; ++nt) {
        f32x4 acc3 = {0.f, 0.f, 0.f, 0.f};
        acc3 = __builtin_amdgcn_mfma_f32_16x16x32_bf16(a2cur[t], b3h[nt], acc3, 0, 0, 0);
        float v0 = rs3v[nt] * acc3[0] + rt3v[nt];
        float v1 = rs3z[nt] * acc3[1] + rt3z[nt];
        float v2 = rs3z[nt] * acc3[2] + rt3z[nt];
        float v3 = rs3z[nt] * acc3[3] + rt3z[nt];
        v0 = v0 > 0.f ? v0 : 0.f;  v1 = v1 > 0.f ? v1 : 0.f;
        v2 = v2 > 0.f ? v2 : 0.f;  v3 = v3 > 0.f ? v3 : 0.f;
        uint2 pk2;
        pk2.x = pkbf(v0, v1);
        pk2.y = pkbf(v2, v3);
        *(uint2*)(a3buf + g * A3P + (nt * 16 + b) * 16 + 4 * q) = pk2;
      }
    }
    __syncthreads();          // a3buf complete for all 16 images
#pragma unroll
    for (int mm = 0; mm < 8; ++mm) {
      bf16x8 af = *(const bf16x8*)(a3buf + b * A3P + w * 256 + mm * 32 + 8 * q);
      bf16x8 bw = fcB[((i * 32 + w * 8 + mm) * 16 + b) * 4 + q];
      accF = __builtin_amdgcn_mfma_f32_16x16x32_bf16(af, bw, accF, 0, 0, 0);
    }
    __syncthreads();          // before next row overwrites a3buf
  }

  float* redf7 = (float*)a3buf;
#pragma unroll
  for (int r = 0; r < 4; ++r)
    redf7[w * 256 + (4 * q + r) * 16 + b] = accF[r];
  __syncthreads();
  if (tid < 160) {
    int img = tid / 10, jj = tid - img * 10;
    float s = redf7[img * 16 + jj] + redf7[256 + img * 16 + jj] +
              redf7[512 + img * 16 + jj] + redf7[768 + img * 16 + jj];
    out[(blockIdx.x * 16 + img) * 10 + jj] = s + fcb[jj];
  }
}

extern "C" void kernel_launch(void* const* d_in, const int* in_sizes, int n_in,
                              void* d_out, int out_size, void* d_ws, size_t ws_size,
                              hipStream_t stream) {
  (void)in_sizes; (void)n_in; (void)out_size; (void)ws_size;
  const float* x   = (const float*)d_in[0];
  const float* w1  = (const float*)d_in[1];
  const float* w2  = (const float*)d_in[2];
  const float* w3  = (const float*)d_in[3];
  const float* g1  = (const float*)d_in[4];
  const float* b1  = (const float*)d_in[5];
  const float* g2  = (const float*)d_in[6];
  const float* b2  = (const float*)d_in[7];
  const float* g3  = (const float*)d_in[8];
  const float* b3  = (const float*)d_in[9];
  const float* fcw = (const float*)d_in[10];
  const float* fcb = (const float*)d_in[11];
  float* out = (float*)d_out;
  float* ws  = (float*)d_ws;
  short* a2g = (short*)((char*)d_ws + A2G_BYTE);
  float* parts = ws + C2P_OFF;

  k1_xstats<<<512, 256, 0, stream>>>(x, ws);
  k_stats1<<<1, 256, 0, stream>>>(w1, g1, b1, ws);
  k3_conv2_stats<<<1024, 256, 0, stream>>>(x, w1, w2, ws);
  k_stats2<<<32, 256, 0, stream>>>(g2, b2, ws, 32, P2_OFF, ST2,
                                   1.0f / (16384.0f * 169.0f));
  k5_a2<<<1024, 256, 0, stream>>>(x, w1, w2, ws, a2g, parts);
  k_statsC<<<800, 256, 0, stream>>>(parts, ws);
  k_stats3n<<<1, 64, 0, stream>>>(w3, g3, b3, ws);
  k0_fcB<<<FCB_N / 256, 256, 0, stream>>>(fcw, (unsigned int*)ws);
  k7_fc<<<1024, 256, 0, stream>>>(a2g, w3, fcb, ws, out);
}

// Round 8
// 278.939 us; speedup vs baseline: 8.9541x; 1.0631x over previous
//
#include <hip/hip_runtime.h>

// ---------------------------------------------------------------------------
// LocallyConnectedNN: x[16384,256] -> conv3x3(1->16)+BN+ReLU -> conv2x2(16->32)
// +BN+ReLU -> conv1x1(32->64)+BN+ReLU -> FC(10816->10).
// Round 8: (1) BN folds into MFMA everywhere: weight frags pre-scaled by s,
// accumulator C initialized to t (invalid pixels: -1e30 -> relu -> 0, mask
// free); (2) conv1 operand-swapped (A=w1s,B=im2row) -> ph write is 1
// ds_write_b64; (3) conv2 in k5 operand-swapped -> lane holds 4 contiguous
// ch at fixed pix -> a2 stored DIRECTLY to global as uint2 (a2w staging
// buffer deleted); (4) k1 patch-covariance via MFMA syrk with register-built
// fragments (tap<->m, col<->k match the lane layout exactly; constant-1.0
// tap row makes C[9][t]=S[t]); 1 MFMA per image-row-pair.
// ---------------------------------------------------------------------------

#define NPART 1024
#define P2_OFF 32768      // [1024][64] conv2 stats partials
#define ST_OFF 229376     // s1[16] t1[16] s2[32] t2[32] s3[64] t3[64]
#define ST1 ST_OFF
#define ST2 (ST_OFF + 32)
#define ST3 (ST_OFF + 96)
#define C2R_OFF 230400    // reduced [768 C2 tiles | 32 S2]
#define C1R_OFF 231424    // reduced x-patch Cext [16x16]
#define C2P_OFF 262144    // block partials (1MB..): k1 [1024][256], k5 [1024][800]
#define A2G_BYTE 5242880ull // a2 cache: [img][13 i][13 pix][32 ch] bf16, 177MB
#define FCB_N (13 * 8192) // fcB u32 at ws[0..106496)
#define A1S 24            // a1h LDS row stride (shorts)
#define A1B 384           // one a1 LDS buffer (16 rows x A1S)
#define A3P 1048          // a3buf image stride (shorts)

typedef __attribute__((ext_vector_type(8))) short bf16x8;
typedef __attribute__((ext_vector_type(4))) float f32x4;

__device__ __forceinline__ unsigned int f2bf(float f) {
  unsigned int u = __float_as_uint(f);
  return (u + 0x7fffu + ((u >> 16) & 1u)) >> 16;   // RTNE bf16 bits
}
// pack two floats to bf16x2 (round-half-up): 2 adds + 1 v_perm_b32
__device__ __forceinline__ unsigned int pkbf(float a, float b) {
  unsigned ua = __float_as_uint(a) + 0x8000u;
  unsigned ub = __float_as_uint(b) + 0x8000u;
  return __builtin_amdgcn_perm(ub, ua, 0x07060302u);
}
__device__ __forceinline__ short cvtbf(float a) {
  return (short)((__float_as_uint(a) + 0x8000u) >> 16);
}

// conv1 (3x3,1->16)+bn1(folded)+relu for output row r, swapped operands:
// A = w1*rs1 (m=ch), B = im2row (n=col j), C-init = rt1.
// D: col(lane&15)=j, row(4q+r)=ch -> ph[j][ch] write = 1 ds_write_b64.
__device__ __forceinline__ void conv1_mfma(
    const float* __restrict__ sxi,   // [256] image (+finite pad after)
    short* ph_buf,                   // [2 bufs][16 j][A1S ch]
    int r, int b, int q, bf16x8 a1f, f32x4 c1i)
{
  bf16x8 bf = {0, 0, 0, 0, 0, 0, 0, 0};
  unsigned* bu = (unsigned*)&bf;
  if (q == 0) {
    bu[0] = pkbf(sxi[r * 16 + b],           sxi[r * 16 + b + 1]);
    bu[1] = pkbf(sxi[r * 16 + b + 2],       sxi[(r + 1) * 16 + b]);
    bu[2] = pkbf(sxi[(r + 1) * 16 + b + 1], sxi[(r + 1) * 16 + b + 2]);
    bu[3] = pkbf(sxi[(r + 2) * 16 + b],     sxi[(r + 2) * 16 + b + 1]);
  } else if (q == 1) {
    bu[0] = pkbf(sxi[(r + 2) * 16 + b + 2], 0.f);
  }
  f32x4 acc = c1i;
  acc = __builtin_amdgcn_mfma_f32_16x16x32_bf16(a1f, bf, acc, 0, 0, 0);
  float v0 = acc[0] > 0.f ? acc[0] : 0.f;
  float v1 = acc[1] > 0.f ? acc[1] : 0.f;
  float v2 = acc[2] > 0.f ? acc[2] : 0.f;
  float v3 = acc[3] > 0.f ? acc[3] : 0.f;
  uint2 pk;
  pk.x = pkbf(v0, v1);
  pk.y = pkbf(v2, v3);
  *(uint2*)(ph_buf + (r & 1) * A1B + b * A1S + 4 * q) = pk;
}

// conv1 A-frag: m=ch=b, k=tap 8q+j (zeros for tap>=9), scaled by rs1[b].
__device__ __forceinline__ bf16x8 conv1_afrag(const float* w1, float rs1b,
                                              int b, int q) {
  bf16x8 v;
#pragma unroll
  for (int j = 0; j < 8; ++j) {
    int tap = 8 * q + j;
    v[j] = (tap < 9) ? (short)f2bf(w1[b * 9 + tap] * rs1b) : (short)0;
  }
  return v;
}

// K1: x patch-covariance via MFMA syrk. Fragment built in registers:
// lane (b=tap,q=col-chunk) holds taps b of cols 8q..8q+7 -- exactly the
// A/B frag layout. Tap 9 = 1.0 (so C[9][t] = S[t]); taps 10..15 = 0.
__global__ __launch_bounds__(256) void k1_xsyrk(
    const float* __restrict__ x, float* __restrict__ parts)
{
  __shared__ float sx[16 * 256];
  const int tid = threadIdx.x, w = tid >> 6, lane = tid & 63;
  const int b = lane & 15, q = lane >> 4;
  {
    const float4* xs = (const float4*)(x + (size_t)blockIdx.x * (16 * 256));
    float4* sd = (float4*)sx;
    for (int e = tid; e < 16 * 64; e += 256) sd[e] = xs[e];
  }
  __syncthreads();
  const int di = (b < 9) ? (b / 3) : 0;
  const int dj = (b < 9) ? (b - di * 3) : 0;
  const int h = q >> 1, jb = (q & 1) * 8;
  f32x4 acc = {0.f, 0.f, 0.f, 0.f};
#pragma unroll 1
  for (int t = 0; t < 4; ++t) {
    const float* sxi = sx + (w * 4 + t) * 256;
#pragma unroll 1
    for (int s = 0; s < 7; ++s) {
      bf16x8 af;
      unsigned* au = (unsigned*)&af;
      if (b < 9) {
        const float* srow = sxi + (2 * s + h + di) * 16 + dj;
#pragma unroll
        for (int cc = 0; cc < 4; ++cc) {
          float v0 = (jb + 2 * cc     < 14) ? srow[jb + 2 * cc]     : 0.f;
          float v1 = (jb + 2 * cc + 1 < 14) ? srow[jb + 2 * cc + 1] : 0.f;
          au[cc] = pkbf(v0, v1);
        }
      } else if (b == 9) {
#pragma unroll
        for (int cc = 0; cc < 4; ++cc) {
          unsigned lo = (jb + 2 * cc     < 14) ? 0x3F80u : 0u;
          unsigned hi = (jb + 2 * cc + 1 < 14) ? 0x3F800000u : 0u;
          au[cc] = lo | hi;
        }
      } else {
#pragma unroll
        for (int cc = 0; cc < 4; ++cc) au[cc] = 0u;
      }
      acc = __builtin_amdgcn_mfma_f32_16x16x32_bf16(af, af, acc, 0, 0, 0);
    }
  }
  __syncthreads();                 // done reading sx; reuse as reduce buffer
  float* redc = sx;
#pragma unroll
  for (int rr = 0; rr < 4; ++rr)
    redc[w * 256 + (4 * q + rr) * 16 + b] = acc[rr];
  __syncthreads();
  parts[blockIdx.x * 256 + tid] =
      redc[tid] + redc[256 + tid] + redc[512 + tid] + redc[768 + tid];
}

// Reduce k1 partials [1024][256] -> Cext[256].
__global__ __launch_bounds__(256) void k_stats1a(
    const float* __restrict__ parts, float* __restrict__ ws)
{
  const int e = blockIdx.x, tid = threadIdx.x;
  const int w = tid >> 6, lane = tid & 63;
  __shared__ float rs[4];
  float s = 0.f;
#pragma unroll 4
  for (int i = tid; i < 1024; i += 256) s += parts[i * 256 + e];
#pragma unroll
  for (int d = 1; d < 64; d <<= 1) s += __shfl_xor(s, d);
  if (lane == 0) rs[w] = s;
  __syncthreads();
  if (tid == 0) ws[C1R_OFF + e] = rs[0] + rs[1] + rs[2] + rs[3];
}

// BN1 finalize from Cext: mean = w^T S /N, E[y^2] = w^T C w /N.
__global__ __launch_bounds__(64) void k_stats1b(
    const float* __restrict__ w1, const float* __restrict__ gamma,
    const float* __restrict__ beta, float* __restrict__ ws)
{
  const int c = threadIdx.x;
  if (c >= 16) return;
  const float* C = ws + C1R_OFF;
  float wr[9];
#pragma unroll
  for (int p = 0; p < 9; ++p) wr[p] = w1[c * 9 + p];
  float msum = 0.f;
#pragma unroll
  for (int p = 0; p < 9; ++p) msum += wr[p] * C[9 * 16 + p];
  float e2 = 0.f;
#pragma unroll
  for (int a = 0; a < 9; ++a)
#pragma unroll
    for (int bb = 0; bb < 9; ++bb)
      e2 += wr[a] * wr[bb] * C[a * 16 + bb];
  const float inv_n = 1.0f / (16384.0f * 196.0f);
  float mean = msum * inv_n;
  float var  = e2 * inv_n - mean * mean;
  float sv   = gamma[c] * rsqrtf(var + 1e-5f);
  ws[ST1 + c]      = sv;
  ws[ST1 + 16 + c] = beta[c] - mean * sv;
}

// BN2 finalize, one block per channel (reduces P2 [1024][64]).
__global__ __launch_bounds__(256) void k_stats2(
    const float* __restrict__ gamma, const float* __restrict__ beta,
    float* __restrict__ ws, int nch, int part_off, int st_off, float inv_n)
{
  const int c = blockIdx.x, tid = threadIdx.x;
  const int w = tid >> 6, lane = tid & 63;
  __shared__ float rs[4], rq[4];
  float s = 0.f, q = 0.f;
#pragma unroll 4
  for (int i = tid; i < NPART; i += 256) {
    s += ws[part_off + i * 2 * nch + c];
    q += ws[part_off + i * 2 * nch + nch + c];
  }
#pragma unroll
  for (int d = 1; d < 64; d <<= 1) {
    s += __shfl_xor(s, d);
    q += __shfl_xor(q, d);
  }
  if (lane == 0) { rs[w] = s; rq[w] = q; }
  __syncthreads();
  if (tid == 0) {
    float st = rs[0] + rs[1] + rs[2] + rs[3];
    float qt = rq[0] + rq[1] + rq[2] + rq[3];
    float mean = st * inv_n;
    float var  = qt * inv_n - mean * mean;
    float sv   = gamma[c] * rsqrtf(var + 1e-5f);
    ws[st_off + c]       = sv;
    ws[st_off + nch + c] = beta[c] - mean * sv;
  }
}

// K3: conv1(MFMA,folded) + conv2(swapped, raw) stats.
// conv2 D: col(b)=pix, row(4q+r)=ch(nt half).
__global__ __launch_bounds__(256) void k3_conv2_stats(
    const float* __restrict__ x, const float* __restrict__ w1,
    const float* __restrict__ w2, float* __restrict__ ws)
{
  __shared__ float sx_s[16 * 256 + 16];
  __shared__ alignas(16) short a1h[4 * 2 * A1B];
  __shared__ float redf[256];
  const int tid = threadIdx.x, w = tid >> 6, lane = tid & 63;
  const int b = lane & 15, q = lane >> 4;
  {
    const float4* xs = (const float4*)(x + (size_t)blockIdx.x * (16 * 256));
    float4* sd = (float4*)sx_s;
    for (int e = tid; e < 16 * 64; e += 256) sd[e] = xs[e];
    if (tid < 16) sx_s[16 * 256 + tid] = 0.f;
  }
  bf16x8 a1f = conv1_afrag(w1, ws[ST1 + b], b, q);
  f32x4 c1i;
#pragma unroll
  for (int r = 0; r < 4; ++r) c1i[r] = ws[ST1 + 16 + 4 * q + r];
  bf16x8 b2h[4];   // A-side now: [ks][nt], m=ch=b, raw
#pragma unroll
  for (int ks = 0; ks < 2; ++ks)
#pragma unroll
    for (int nt = 0; nt < 2; ++nt) {
      bf16x8 vh;
#pragma unroll
      for (int j = 0; j < 8; ++j) {
        int kk = 8 * (q & 1) + j, dj = q >> 1;
        vh[j] = (short)f2bf(w2[(nt * 16 + b) * 64 + kk * 4 + ks * 2 + dj]);
      }
      b2h[ks * 2 + nt] = vh;
    }
  const float vb = (b < 13) ? 1.f : 0.f;
  const int colAr = (b + (q >> 1) < 15) ? (b + (q >> 1)) : 15;
  const int offAl = colAr * A1S + 8 * (q & 1);
  __syncthreads();

  float s2r[2][4] = {{0.f,0.f,0.f,0.f},{0.f,0.f,0.f,0.f}};
  float q2r[2][4] = {{0.f,0.f,0.f,0.f},{0.f,0.f,0.f,0.f}};
  short* ph = a1h + w * (2 * A1B);
#pragma unroll 1
  for (int t = 0; t < 4; ++t) {
    const float* sxi = sx_s + (w * 4 + t) * 256;
    conv1_mfma(sxi, ph, 0, b, q, a1f, c1i);
    __builtin_amdgcn_wave_barrier();
#pragma unroll 1
    for (int i = 0; i < 13; ++i) {
      conv1_mfma(sxi, ph, i + 1, b, q, a1f, c1i);
      __builtin_amdgcn_wave_barrier();
      bf16x8 ah0 = *(const bf16x8*)(ph + (i & 1) * A1B + offAl);
      bf16x8 ah1 = *(const bf16x8*)(ph + ((i + 1) & 1) * A1B + offAl);
      f32x4 acc2[2] = {{0.f,0.f,0.f,0.f},{0.f,0.f,0.f,0.f}};
#pragma unroll
      for (int nt = 0; nt < 2; ++nt) {
        acc2[nt] = __builtin_amdgcn_mfma_f32_16x16x32_bf16(b2h[nt], ah0, acc2[nt], 0, 0, 0);
        acc2[nt] = __builtin_amdgcn_mfma_f32_16x16x32_bf16(b2h[2 + nt], ah1, acc2[nt], 0, 0, 0);
      }
#pragma unroll
      for (int nt = 0; nt < 2; ++nt)
#pragma unroll
        for (int r = 0; r < 4; ++r) {
          float ym = acc2[nt][r] * vb;
          s2r[nt][r] += ym;
          q2r[nt][r] = fmaf(ym, acc2[nt][r], q2r[nt][r]);
        }
      __builtin_amdgcn_wave_barrier();
    }
  }
  // reduce over the 16 pix-lanes (b); lane b==0 holds ch = nt*16+4q+r
#pragma unroll
  for (int nt = 0; nt < 2; ++nt)
#pragma unroll
    for (int r = 0; r < 4; ++r) {
      float sv = s2r[nt][r], qv = q2r[nt][r];
      sv += __shfl_xor(sv, 1); sv += __shfl_xor(sv, 2);
      sv += __shfl_xor(sv, 4); sv += __shfl_xor(sv, 8);
      qv += __shfl_xor(qv, 1); qv += __shfl_xor(qv, 2);
      qv += __shfl_xor(qv, 4); qv += __shfl_xor(qv, 8);
      if (b == 0) {
        redf[w * 64 + nt * 16 + 4 * q + r]      = sv;
        redf[w * 64 + 32 + nt * 16 + 4 * q + r] = qv;
      }
    }
  __syncthreads();
  if (tid < 64)
    ws[P2_OFF + blockIdx.x * 64 + tid] =
        redf[tid] + redf[64 + tid] + redf[128 + tid] + redf[192 + tid];
}

// K5: conv1(MFMA,folded) + conv2(swapped, bn2-folded) -> a2 DIRECT global
// uint2 stores + xt syrk (BN3 stats). conv2 D: col(b)=pix, row=ch ->
// lane holds 4 contiguous ch of a2[pix][ch].
__global__ __launch_bounds__(256) void k5_a2(
    const float* __restrict__ x, const float* __restrict__ w1,
    const float* __restrict__ w2, float* __restrict__ ws,
    short* __restrict__ a2g, float* __restrict__ parts)
{
  __shared__ float sx_s[16 * 256 + 16];          // reused as redc at the end
  __shared__ alignas(16) short a1h[4 * 2 * A1B];
  __shared__ alignas(16) short xt4[4 * 32 * 40]; // [w][ch32][pos32+pad8]
  __shared__ float s2red[4 * 32];
  const int tid = threadIdx.x, w = tid >> 6, lane = tid & 63;
  const int b = lane & 15, q = lane >> 4;
  {
    const float4* xs = (const float4*)(x + (size_t)blockIdx.x * (16 * 256));
    float4* sd = (float4*)sx_s;
    for (int e = tid; e < 16 * 64; e += 256) sd[e] = xs[e];
    if (tid < 16) sx_s[16 * 256 + tid] = 0.f;
  }
  bf16x8 a1f = conv1_afrag(w1, ws[ST1 + b], b, q);
  f32x4 c1i;
#pragma unroll
  for (int r = 0; r < 4; ++r) c1i[r] = ws[ST1 + 16 + 4 * q + r];
  bf16x8 b2h[4];   // A-side: [ks][nt], m=ch=b, scaled by s2[nt*16+b]
#pragma unroll
  for (int ks = 0; ks < 2; ++ks)
#pragma unroll
    for (int nt = 0; nt < 2; ++nt) {
      float rs2b = ws[ST2 + nt * 16 + b];
      bf16x8 vh;
#pragma unroll
      for (int j = 0; j < 8; ++j) {
        int kk = 8 * (q & 1) + j, dj = q >> 1;
        vh[j] = (short)f2bf(w2[(nt * 16 + b) * 64 + kk * 4 + ks * 2 + dj] * rs2b);
      }
      b2h[ks * 2 + nt] = vh;
    }
  f32x4 c2i[2];
#pragma unroll
  for (int nt = 0; nt < 2; ++nt)
#pragma unroll
    for (int r = 0; r < 4; ++r)
      c2i[nt][r] = (b < 13) ? ws[ST2 + 32 + nt * 16 + 4 * q + r] : -1e30f;
  const int colAr = (b + (q >> 1) < 15) ? (b + (q >> 1)) : 15;
  const int offAl = colAr * A1S + 8 * (q & 1);
  short* xt = xt4 + w * 1280;
  __syncthreads();

  f32x4 accT0 = {0.f,0.f,0.f,0.f}, accT1 = {0.f,0.f,0.f,0.f},
        accT2 = {0.f,0.f,0.f,0.f};
  float s2aR[2][4] = {{0.f,0.f,0.f,0.f},{0.f,0.f,0.f,0.f}};
  short* ph = a1h + w * (2 * A1B);
#pragma unroll 1
  for (int t = 0; t < 4; ++t) {
    const int img = blockIdx.x * 16 + w * 4 + t;
    const float* sxi = sx_s + (w * 4 + t) * 256;
    conv1_mfma(sxi, ph, 0, b, q, a1f, c1i);
    __builtin_amdgcn_wave_barrier();
#pragma unroll 1
    for (int i = 0; i < 13; ++i) {
      conv1_mfma(sxi, ph, i + 1, b, q, a1f, c1i);
      __builtin_amdgcn_wave_barrier();
      bf16x8 ah0 = *(const bf16x8*)(ph + (i & 1) * A1B + offAl);
      bf16x8 ah1 = *(const bf16x8*)(ph + ((i + 1) & 1) * A1B + offAl);
#pragma unroll
      for (int nt = 0; nt < 2; ++nt) {
        f32x4 acc2 = c2i[nt];
        acc2 = __builtin_amdgcn_mfma_f32_16x16x32_bf16(b2h[nt], ah0, acc2, 0, 0, 0);
        acc2 = __builtin_amdgcn_mfma_f32_16x16x32_bf16(b2h[2 + nt], ah1, acc2, 0, 0, 0);
        float vm[4];
#pragma unroll
        for (int r = 0; r < 4; ++r) {
          vm[r] = acc2[r] > 0.f ? acc2[r] : 0.f;
          s2aR[nt][r] += vm[r];
          xt[(nt * 16 + 4 * q + r) * 40 + (i & 1) * 16 + b] = cvtbf(vm[r]);
        }
        if (b < 13) {
          uint2 pk;
          pk.x = pkbf(vm[0], vm[1]);
          pk.y = pkbf(vm[2], vm[3]);
          *(uint2*)(a2g + (size_t)img * 5408 + (size_t)(i * 13 + b) * 32 +
                    nt * 16 + 4 * q) = pk;
        }
      }
      __builtin_amdgcn_wave_barrier();
      if (i & 1) {   // syrk over position pair (i-1, i)
        bf16x8 xf0 = *(const bf16x8*)(xt + b * 40 + 8 * q);
        bf16x8 xf1 = *(const bf16x8*)(xt + (16 + b) * 40 + 8 * q);
        accT0 = __builtin_amdgcn_mfma_f32_16x16x32_bf16(xf0, xf0, accT0, 0, 0, 0);
        accT1 = __builtin_amdgcn_mfma_f32_16x16x32_bf16(xf0, xf1, accT1, 0, 0, 0);
        accT2 = __builtin_amdgcn_mfma_f32_16x16x32_bf16(xf1, xf1, accT2, 0, 0, 0);
      }
      __builtin_amdgcn_wave_barrier();
    }
    // leftover row 12 (parity 0): zero parity-1 halves, final syrk
    {
      uint2 z; z.x = 0u; z.y = 0u;
      *(uint2*)(xt + b * 40 + 16 + 4 * q) = z;
      *(uint2*)(xt + (16 + b) * 40 + 16 + 4 * q) = z;
      __builtin_amdgcn_wave_barrier();
      bf16x8 xf0 = *(const bf16x8*)(xt + b * 40 + 8 * q);
      bf16x8 xf1 = *(const bf16x8*)(xt + (16 + b) * 40 + 8 * q);
      accT0 = __builtin_amdgcn_mfma_f32_16x16x32_bf16(xf0, xf0, accT0, 0, 0, 0);
      accT1 = __builtin_amdgcn_mfma_f32_16x16x32_bf16(xf0, xf1, accT1, 0, 0, 0);
      accT2 = __builtin_amdgcn_mfma_f32_16x16x32_bf16(xf1, xf1, accT2, 0, 0, 0);
      __builtin_amdgcn_wave_barrier();
    }
  }
  // S2: reduce over pix-lanes b; lane b==0 holds ch = nt*16+4q+r
#pragma unroll
  for (int nt = 0; nt < 2; ++nt)
#pragma unroll
    for (int r = 0; r < 4; ++r) {
      float sv = s2aR[nt][r];
      sv += __shfl_xor(sv, 1); sv += __shfl_xor(sv, 2);
      sv += __shfl_xor(sv, 4); sv += __shfl_xor(sv, 8);
      if (b == 0) s2red[w * 32 + nt * 16 + 4 * q + r] = sv;
    }
  float* redc = sx_s;   // wave w writes only into its own sx quarter
#pragma unroll
  for (int rr = 0; rr < 4; ++rr) {
    int m = 4 * q + rr;
    redc[w * 1024 + 0   + m * 16 + b] = accT0[rr];
    redc[w * 1024 + 256 + m * 16 + b] = accT1[rr];
    redc[w * 1024 + 512 + m * 16 + b] = accT2[rr];
  }
  __syncthreads();
  for (int e = tid; e < 768; e += 256)
    parts[blockIdx.x * 800 + e] =
        redc[e] + redc[1024 + e] + redc[2048 + e] + redc[3072 + e];
  if (tid < 32)
    parts[blockIdx.x * 800 + 768 + tid] =
        s2red[tid] + s2red[32 + tid] + s2red[64 + tid] + s2red[96 + tid];
}

// Reduce C2/S2 block partials: one block per entry e in [0,800).
__global__ __launch_bounds__(256) void k_statsC(
    const float* __restrict__ parts, float* __restrict__ ws)
{
  const int e = blockIdx.x, tid = threadIdx.x;
  const int w = tid >> 6, lane = tid & 63;
  __shared__ float rs[4];
  float s = 0.f;
#pragma unroll 4
  for (int i = tid; i < 1024; i += 256) s += parts[i * 800 + e];
#pragma unroll
  for (int d = 1; d < 64; d <<= 1) s += __shfl_xor(s, d);
  if (lane == 0) rs[w] = s;
  __syncthreads();
  if (tid == 0) ws[C2R_OFF + e] = rs[0] + rs[1] + rs[2] + rs[3];
}

// BN3 finalize from S2/C2: mean=w3^T S2/N, E[y3^2]=w3^T C2 w3 /N.
__global__ __launch_bounds__(64) void k_stats3n(
    const float* __restrict__ w3, const float* __restrict__ gamma,
    const float* __restrict__ beta, float* __restrict__ ws)
{
  const int c3 = threadIdx.x;
  if (c3 >= 64) return;
  const float* C2R = ws + C2R_OFF;
  float wr[32];
#pragma unroll
  for (int k = 0; k < 32; ++k) wr[k] = w3[c3 * 32 + k];
  const float inv_n = 1.0f / (16384.0f * 169.0f);
  float msum = 0.f;
#pragma unroll
  for (int k = 0; k < 32; ++k) msum += wr[k] * C2R[768 + k];
  float e2 = 0.f;
  for (int a = 0; a < 16; ++a)
#pragma unroll
    for (int bb = 0; bb < 16; ++bb) {
      e2 += wr[a] * wr[bb] * C2R[a * 16 + bb];                  // T00
      e2 += wr[16 + a] * wr[16 + bb] * C2R[512 + a * 16 + bb];  // T11
      e2 += 2.f * wr[a] * wr[16 + bb] * C2R[256 + a * 16 + bb]; // T01
    }
  float mean = msum * inv_n;
  float var  = e2 * inv_n - mean * mean;
  float sv   = gamma[c3] * rsqrtf(var + 1e-5f);
  ws[ST3 + c3]      = sv;
  ws[ST3 + 64 + c3] = beta[c3] - mean * sv;
}

// K0: pack fc_w into MFMA B-fragment order (bf16 pairs in u32).
__global__ __launch_bounds__(256) void k0_fcB(
    const float* __restrict__ fcw, unsigned int* __restrict__ fcB)
{
  int F = blockIdx.x * 256 + threadIdx.x;
  if (F >= FCB_N) return;
  int u = F & 3, q = (F >> 2) & 3, jj = (F >> 4) & 15;
  int mm = (F >> 8) & 31, i = F >> 13;
  int k0 = mm * 32 + q * 8 + u * 2;
  unsigned lo = 0, hi = 0;
  if (jj < 10) {
    int c0 = k0 >> 4, j0 = k0 & 15;
    if (j0 < 13) lo = f2bf(fcw[jj * 10816 + c0 * 169 + i * 13 + j0]);
    int c1 = (k0 + 1) >> 4, j1 = (k0 + 1) & 15;
    if (j1 < 13) hi = f2bf(fcw[jj * 10816 + c1 * 169 + i * 13 + j1]);
  }
  fcB[F] = lo | (hi << 16);
}

// K7: read packed a2 -> conv3(bn3-folded)+relu (MFMA) -> FC (MFMA).
__global__ __launch_bounds__(256) void k7_fc(
    const short* __restrict__ a2g, const float* __restrict__ w3,
    const float* __restrict__ fcb, const float* __restrict__ ws,
    float* __restrict__ out)
{
  __shared__ alignas(16) short a3buf[16 * A3P];
  const int tid = threadIdx.x, w = tid >> 6, lane = tid & 63;
  const int b = lane & 15, q = lane >> 4;
  bf16x8 b3h[4];     // B-side: n=ch=nt*16+b, scaled by s3
  f32x4 c3i[4];
#pragma unroll
  for (int nt = 0; nt < 4; ++nt) {
    float s3 = ws[ST3 + nt * 16 + b];
    float t3 = ws[ST3 + 64 + nt * 16 + b];
    bf16x8 vh;
#pragma unroll
    for (int j = 0; j < 8; ++j)
      vh[j] = (short)f2bf(w3[(nt * 16 + b) * 32 + 8 * q + j] * s3);
    b3h[nt] = vh;
    c3i[nt][0] = t3;                          // pix = 4q valid always
#pragma unroll
    for (int r = 1; r < 4; ++r)
      c3i[nt][r] = (q < 3) ? t3 : -1e30f;     // pix 4q+r invalid at q==3
  }
  const bf16x8* fcB = (const bf16x8*)ws;
  f32x4 accF = {0.f, 0.f, 0.f, 0.f};
  const int pixc = (b < 12) ? b : 12;   // clamp pad rows (relu(-1e30)=0 masks)
  size_t ib[4];
#pragma unroll
  for (int t = 0; t < 4; ++t)
    ib[t] = (size_t)(blockIdx.x * 16 + w * 4 + t) * 5408;
  bf16x8 a2pre[4];
#pragma unroll
  for (int t = 0; t < 4; ++t)
    a2pre[t] = *(const bf16x8*)(a2g + ib[t] + pixc * 32 + 8 * q);

#pragma unroll 1
  for (int i = 0; i < 13; ++i) {
    bf16x8 a2cur[4];
#pragma unroll
    for (int t = 0; t < 4; ++t) a2cur[t] = a2pre[t];
    if (i < 12) {
#pragma unroll
      for (int t = 0; t < 4; ++t)
        a2pre[t] = *(const bf16x8*)(a2g + ib[t] +
                                    (size_t)((i + 1) * 13 + pixc) * 32 + 8 * q);
    }
#pragma unroll
    for (int t = 0; t < 4; ++t) {
      const int g = w * 4 + t;
#pragma unroll
      for (int nt = 0; nt < 4; ++nt) {
        f32x4 acc3 = c3i[nt];
        acc3 = __builtin_amdgcn_mfma_f32_16x16x32_bf16(a2cur[t], b3h[nt], acc3, 0, 0, 0);
        float v0 = acc3[0] > 0.f ? acc3[0] : 0.f;
        float v1 = acc3[1] > 0.f ? acc3[1] : 0.f;
        float v2 = acc3[2] > 0.f ? acc3[2] : 0.f;
        float v3 = acc3[3] > 0.f ? acc3[3] : 0.f;
        uint2 pk2;
        pk2.x = pkbf(v0, v1);
        pk2.y = pkbf(v2, v3);
        *(uint2*)(a3buf + g * A3P + (nt * 16 + b) * 16 + 4 * q) = pk2;
      }
    }
    __syncthreads();          // a3buf complete for all 16 images
#pragma unroll
    for (int mm = 0; mm < 8; ++mm) {
      bf16x8 af = *(const bf16x8*)(a3buf + b * A3P + w * 256 + mm * 32 + 8 * q);
      bf16x8 bw = fcB[((i * 32 + w * 8 + mm) * 16 + b) * 4 + q];
      accF = __builtin_amdgcn_mfma_f32_16x16x32_bf16(af, bw, accF, 0, 0, 0);
    }
    __syncthreads();          // before next row overwrites a3buf
  }

  float* redf7 = (float*)a3buf;
#pragma unroll
  for (int r = 0; r < 4; ++r)
    redf7[w * 256 + (4 * q + r) * 16 + b] = accF[r];
  __syncthreads();
  if (tid < 160) {
    int img = tid / 10, jj = tid - img * 10;
    float s = redf7[img * 16 + jj] + redf7[256 + img * 16 + jj] +
              redf7[512 + img * 16 + jj] + redf7[768 + img * 16 + jj];
    out[(blockIdx.x * 16 + img) * 10 + jj] = s + fcb[jj];
  }
}

extern "C" void kernel_launch(void* const* d_in, const int* in_sizes, int n_in,
                              void* d_out, int out_size, void* d_ws, size_t ws_size,
                              hipStream_t stream) {
  (void)in_sizes; (void)n_in; (void)out_size; (void)ws_size;
  const float* x   = (const float*)d_in[0];
  const float* w1  = (const float*)d_in[1];
  const float* w2  = (const float*)d_in[2];
  const float* w3  = (const float*)d_in[3];
  const float* g1  = (const float*)d_in[4];
  const float* b1  = (const float*)d_in[5];
  const float* g2  = (const float*)d_in[6];
  const float* b2  = (const float*)d_in[7];
  const float* g3  = (const float*)d_in[8];
  const float* b3  = (const float*)d_in[9];
  const float* fcw = (const float*)d_in[10];
  const float* fcb = (const float*)d_in[11];
  float* out = (float*)d_out;
  float* ws  = (float*)d_ws;
  short* a2g = (short*)((char*)d_ws + A2G_BYTE);
  float* parts = ws + C2P_OFF;

  k1_xsyrk<<<1024, 256, 0, stream>>>(x, parts);
  k_stats1a<<<256, 256, 0, stream>>>(parts, ws);
  k_stats1b<<<1, 64, 0, stream>>>(w1, g1, b1, ws);
  k3_conv2_stats<<<1024, 256, 0, stream>>>(x, w1, w2, ws);
  k_stats2<<<32, 256, 0, stream>>>(g2, b2, ws, 32, P2_OFF, ST2,
                                   1.0f / (16384.0f * 169.0f));
  k5_a2<<<1024, 256, 0, stream>>>(x, w1, w2, ws, a2g, parts);
  k_statsC<<<800, 256, 0, stream>>>(parts, ws);
  k_stats3n<<<1, 64, 0, stream>>>(w3, g3, b3, ws);
  k0_fcB<<<FCB_N / 256, 256, 0, stream>>>(fcw, (unsigned int*)ws);
  k7_fc<<<1024, 256, 0, stream>>>(a2g, w3, fcb, ws, out);
}